// Round 1
// baseline (653.937 us; speedup 1.0000x reference)
//
#include <hip/hip_runtime.h>
#include <hip/hip_bf16.h>
#include <math.h>

#define NB 2
#define NTOK 16384      // tokens per batch (128x128)
#define TOTT 32768      // total tokens
#define EPSF 1e-5f

__device__ __forceinline__ float bf2f(unsigned short u) {
    union { unsigned int i; float f; } x; x.i = ((unsigned int)u) << 16; return x.f;
}

// ---------------- K1: depthwise 3x3 conv + bias ----------------
__global__ __launch_bounds__(256) void k_dwconv(
    const float* __restrict__ xC, const float* __restrict__ dwW,
    const float* __restrict__ dwB, float* __restrict__ xdw)
{
    int idx = blockIdx.x * 256 + threadIdx.x;   // over TOTT*128
    int c = idx & 127;
    int t = idx >> 7;
    int b = t >> 14, n = t & 16383;
    int row = n >> 7, col = n & 127;
    float acc = dwB[c];
    const float* wp = dwW + c * 9;
    #pragma unroll
    for (int ky = 0; ky < 3; ++ky) {
        int r = row + ky - 1;
        if ((unsigned)r < 128u) {
            #pragma unroll
            for (int kx = 0; kx < 3; ++kx) {
                int cl = col + kx - 1;
                if ((unsigned)cl < 128u)
                    acc = fmaf(wp[ky * 3 + kx],
                               xC[((size_t)(b << 14) + (r << 7) + cl) * 128 + c], acc);
            }
        }
    }
    xdw[idx] = acc;
}

// ---------------- K2: pointwise conv + BN + ReLU + residual + enc + pos ----------------
__global__ __launch_bounds__(256) void k_pw_enc(
    const float* __restrict__ xdw, const float* __restrict__ xC,
    const float* __restrict__ pw, const float* __restrict__ pwb,
    const float* __restrict__ gam, const float* __restrict__ bet,
    const float* __restrict__ mean, const float* __restrict__ var,
    const float* __restrict__ encW, const float* __restrict__ encb,
    const float* __restrict__ pos, float* __restrict__ xpoi)
{
    __shared__ float s_weff[128 * 129];
    __shared__ float s_encW[128 * 64];
    __shared__ float s_dw[16 * 128];
    __shared__ float s_x1[16 * 128];
    __shared__ float s_scale[128];
    __shared__ float s_beff[128];
    int tid = threadIdx.x;
    int T0 = blockIdx.x * 16;
    if (tid < 128) {
        float sc = gam[tid] * rsqrtf(var[tid] + EPSF);
        s_scale[tid] = sc;
        s_beff[tid] = (pwb[tid] - mean[tid]) * sc + bet[tid];
    }
    for (int i = tid; i < 128 * 64; i += 256) s_encW[i] = encW[i];
    for (int i = tid; i < 16 * 128; i += 256) s_dw[i] = xdw[(size_t)T0 * 128 + i];
    __syncthreads();
    for (int i = tid; i < 128 * 128; i += 256) {
        int co = i >> 7, ci = i & 127;
        s_weff[co * 129 + ci] = pw[i] * s_scale[co];
    }
    __syncthreads();
    {   // pointwise + BN + relu + residual
        int co = tid & 127, half = tid >> 7;
        float acc[8];
        #pragma unroll
        for (int t = 0; t < 8; ++t) acc[t] = s_beff[co];
        for (int ci = 0; ci < 128; ++ci) {
            float w = s_weff[co * 129 + ci];
            #pragma unroll
            for (int t = 0; t < 8; ++t)
                acc[t] = fmaf(s_dw[(half * 8 + t) * 128 + ci], w, acc[t]);
        }
        #pragma unroll
        for (int t = 0; t < 8; ++t) {
            int tt = half * 8 + t;
            float x1 = fmaxf(acc[t], 0.f) + xC[(size_t)(T0 + tt) * 128 + co];
            s_x1[tt * 128 + co] = x1;
        }
    }
    __syncthreads();
    {   // enc + pos
        int c2 = tid & 63, q = tid >> 6;
        float acc[4] = {0.f, 0.f, 0.f, 0.f};
        for (int ci = 0; ci < 128; ++ci) {
            float e = s_encW[ci * 64 + c2];
            #pragma unroll
            for (int k = 0; k < 4; ++k)
                acc[k] = fmaf(s_x1[(q * 4 + k) * 128 + ci], e, acc[k]);
        }
        #pragma unroll
        for (int k = 0; k < 4; ++k) {
            int t = T0 + q * 4 + k;
            int n = t & 16383;
            xpoi[(size_t)t * 64 + c2] = acc[k] + encb[c2] + pos[(size_t)n * 64 + c2];
        }
    }
}

// ---------------- K3: y-stream relu(x)+x -> enc + pos ----------------
__global__ __launch_bounds__(256) void k_yenc(
    const float* __restrict__ xT, const float* __restrict__ encW,
    const float* __restrict__ encb, const float* __restrict__ pos,
    float* __restrict__ ypoi)
{
    __shared__ float s_y[32 * 128];
    __shared__ float s_encW[128 * 64];
    int tid = threadIdx.x;
    int T0 = blockIdx.x * 32;
    for (int i = tid; i < 128 * 64; i += 256) s_encW[i] = encW[i];
    for (int i = tid; i < 32 * 128; i += 256) {
        float v = xT[(size_t)T0 * 128 + i];
        s_y[i] = v > 0.f ? 2.f * v : v;
    }
    __syncthreads();
    int c2 = tid & 63, q = tid >> 6;
    float acc[8] = {};
    for (int ci = 0; ci < 128; ++ci) {
        float e = s_encW[ci * 64 + c2];
        #pragma unroll
        for (int k = 0; k < 8; ++k)
            acc[k] = fmaf(s_y[(q * 8 + k) * 128 + ci], e, acc[k]);
    }
    #pragma unroll
    for (int k = 0; k < 8; ++k) {
        int t = T0 + q * 8 + k;
        int n = t & 16383;
        ypoi[(size_t)t * 64 + c2] = acc[k] + encb[c2] + pos[(size_t)n * 64 + c2];
    }
}

// ---------------- K4: LN + qkv GEMM, store bf16 window-major ----------------
// layout: qkv[((s*2+b)*8+head)*64+wid]*256+p)*24 + {0..7 q, 8..15 k, 16..23 v}
__global__ __launch_bounds__(256) void k_qkv(
    const float* __restrict__ xpoi, const float* __restrict__ ypoi,
    const float* __restrict__ qkvW, const float* __restrict__ lng,
    const float* __restrict__ lnb, __hip_bfloat16* __restrict__ qkv)
{
    __shared__ float s_qW[64 * 192];
    __shared__ float s_w[32 * 64];
    int tid = threadIdx.x;
    int T0 = blockIdx.x * 32;
    int wv = tid >> 6, lane = tid & 63;
    for (int i = tid; i < 64 * 192; i += 256) s_qW[i] = qkvW[i];
    float g = lng[lane], be = lnb[lane];
    for (int s = 0; s < 2; ++s) {
        const float* src = s ? ypoi : xpoi;
        for (int it = 0; it < 8; ++it) {   // LN: one wave per token
            int tt = wv * 8 + it;
            float v = src[(size_t)(T0 + tt) * 64 + lane];
            float sm = v, sq = v * v;
            #pragma unroll
            for (int o = 32; o > 0; o >>= 1) { sm += __shfl_xor(sm, o); sq += __shfl_xor(sq, o); }
            float m = sm * (1.f / 64.f);
            float vr = sq * (1.f / 64.f) - m * m;
            s_w[tt * 64 + lane] = (v - m) * rsqrtf(vr + EPSF) * g + be;
        }
        __syncthreads();
        int head = lane >> 3, d = lane & 7;
        for (int it = 0; it < 8; ++it) {
            int tt = it * 4 + wv;
            float a0 = 0.f, a1 = 0.f, a2 = 0.f;
            for (int c = 0; c < 64; ++c) {
                float wvv = s_w[tt * 64 + c];
                a0 = fmaf(wvv, s_qW[c * 192 + lane], a0);
                a1 = fmaf(wvv, s_qW[c * 192 + 64 + lane], a1);
                a2 = fmaf(wvv, s_qW[c * 192 + 128 + lane], a2);
            }
            int t = T0 + tt;
            int b = t >> 14, n = t & 16383;
            int row = n >> 7, col = n & 127;
            int wid = (row >> 4) * 8 + (col >> 4);
            int p = (row & 15) * 16 + (col & 15);
            size_t base = (((((size_t)s * 2 + b) * 8 + head) * 64 + wid) * 256 + p) * 24;
            qkv[base + d]      = __float2bfloat16(a0);
            qkv[base + 8 + d]  = __float2bfloat16(a1);
            qkv[base + 16 + d] = __float2bfloat16(a2);
        }
        __syncthreads();
    }
}

// ---------------- K5: dual-stream windowed attention (cross values) ----------------
__global__ __launch_bounds__(256) void k_attn(
    const __hip_bfloat16* __restrict__ qkv,
    float* __restrict__ ox, float* __restrict__ oy)
{
    __shared__ float s_kx[256 * 8];
    __shared__ float s_vx[256 * 8];
    __shared__ float s_ky[256 * 8];
    __shared__ float s_vy[256 * 8];
    int i = threadIdx.x;                       // query token in window
    int widg = blockIdx.x >> 3, head = blockIdx.x & 7;
    int b = widg >> 6, wid = widg & 63;
    size_t basex = ((((size_t)0 * 2 + b) * 8 + head) * 64 + wid) * 256;
    size_t basey = ((((size_t)1 * 2 + b) * 8 + head) * 64 + wid) * 256;
    const unsigned short* px = (const unsigned short*)(qkv + (basex + i) * 24);
    const unsigned short* py = (const unsigned short*)(qkv + (basey + i) * 24);
    union U8 { uint4 v; unsigned short u[8]; };
    U8 xq, xk, xv, yq, yk, yv;
    xq.v = ((const uint4*)px)[0]; xk.v = ((const uint4*)px)[1]; xv.v = ((const uint4*)px)[2];
    yq.v = ((const uint4*)py)[0]; yk.v = ((const uint4*)py)[1]; yv.v = ((const uint4*)py)[2];
    const float scale = 0.35355339059327373f;
    float qx[8], qy[8];
    #pragma unroll
    for (int d = 0; d < 8; ++d) {
        qx[d] = bf2f(xq.u[d]) * scale;
        qy[d] = bf2f(yq.u[d]) * scale;
        s_kx[i * 8 + d] = bf2f(xk.u[d]);
        s_vx[i * 8 + d] = bf2f(xv.u[d]);
        s_ky[i * 8 + d] = bf2f(yk.u[d]);
        s_vy[i * 8 + d] = bf2f(yv.u[d]);
    }
    __syncthreads();
    float ax[8] = {}, ay[8] = {};
    float sx = 0.f, sy = 0.f;
    for (int j = 0; j < 256; ++j) {
        float lx = 0.f, ly = 0.f;
        #pragma unroll
        for (int d = 0; d < 8; ++d) {
            lx = fmaf(qx[d], s_kx[j * 8 + d], lx);
            ly = fmaf(qy[d], s_ky[j * 8 + d], ly);
        }
        float ex = __expf(lx), ey = __expf(ly);
        sx += ex; sy += ey;
        #pragma unroll
        for (int d = 0; d < 8; ++d) {
            ax[d] = fmaf(ex, s_vy[j * 8 + d], ax[d]);   // cross: x uses v from y
            ay[d] = fmaf(ey, s_vx[j * 8 + d], ay[d]);
        }
    }
    int row = (wid >> 3) * 16 + (i >> 4);
    int col = (wid & 7) * 16 + (i & 15);
    int t = b * 16384 + row * 128 + col;
    float ix = 1.f / sx, iy = 1.f / sy;
    #pragma unroll
    for (int d = 0; d < 8; ++d) {
        ox[(size_t)t * 64 + head * 8 + d] = ax[d] * ix;
        oy[(size_t)t * 64 + head * 8 + d] = ay[d] * iy;
    }
}

// ---------------- K6: proj + residual + FFN + dec (both streams fused) ----------------
__global__ __launch_bounds__(256) void k_final(
    const float* __restrict__ ox, const float* __restrict__ oy,
    const float* __restrict__ xpoi, const float* __restrict__ ypoi,
    const float* __restrict__ projW, const float* __restrict__ projb,
    const float* __restrict__ W1, const float* __restrict__ b1,
    const float* __restrict__ W2, const float* __restrict__ b2,
    const float* __restrict__ decW, const float* __restrict__ decb,
    const float* __restrict__ lng, const float* __restrict__ lnb,
    float* __restrict__ out)
{
    __shared__ float s_proj[64 * 64];
    __shared__ float s_W1[64 * 64];
    __shared__ float s_W2[64 * 64];
    __shared__ float s_dec[64 * 128];
    __shared__ float s_a[4][64];
    __shared__ float s_h[4][64];
    int tid = threadIdx.x;
    for (int i = tid; i < 4096; i += 256) { s_proj[i] = projW[i]; s_W1[i] = W1[i]; s_W2[i] = W2[i]; }
    for (int i = tid; i < 8192; i += 256) s_dec[i] = decW[i];
    __syncthreads();
    int wv = tid >> 6, l = tid & 63;
    float g = lng[l], be = lnb[l];
    float pb = projb[l], fb1 = b1[l], fb2 = b2[l];
    float db0 = 2.f * decb[l], db1 = 2.f * decb[64 + l];
    for (int it = 0; it < 16; ++it) {
        int t = blockIdx.x * 64 + wv * 16 + it;
        float z = 0.f;
        #pragma unroll 1
        for (int s = 0; s < 2; ++s) {
            const float* o = s ? oy : ox;
            const float* p = s ? ypoi : xpoi;
            // wx = LN(poi)
            float v = p[(size_t)t * 64 + l];
            float sm = v, sq = v * v;
            #pragma unroll
            for (int off = 32; off > 0; off >>= 1) { sm += __shfl_xor(sm, off); sq += __shfl_xor(sq, off); }
            float m = sm * (1.f / 64.f), vr = sq * (1.f / 64.f) - m * m;
            float wx = (v - m) * rsqrtf(vr + EPSF) * g + be;
            // xmid = o @ proj + pb + wx
            s_a[wv][l] = o[(size_t)t * 64 + l];
            float xm = pb + wx;
            for (int c = 0; c < 64; ++c) xm = fmaf(s_a[wv][c], s_proj[c * 64 + l], xm);
            // u = LN(xmid)
            sm = xm; sq = xm * xm;
            #pragma unroll
            for (int off = 32; off > 0; off >>= 1) { sm += __shfl_xor(sm, off); sq += __shfl_xor(sq, off); }
            m = sm * (1.f / 64.f); vr = sq * (1.f / 64.f) - m * m;
            float u = (xm - m) * rsqrtf(vr + EPSF) * g + be;
            s_a[wv][l] = u;                     // wave-lockstep: prior reads complete
            float h = fb1;
            for (int c = 0; c < 64; ++c) h = fmaf(s_a[wv][c], s_W1[c * 64 + l], h);
            h = fmaxf(h, 0.f);
            s_h[wv][l] = h;
            float xf = xm + fb2;
            for (int c = 0; c < 64; ++c) xf = fmaf(s_h[wv][c], s_W2[c * 64 + l], xf);
            z += xf;
        }
        s_a[wv][l] = z;
        float o0 = db0, o1 = db1;
        for (int c = 0; c < 64; ++c) {
            float zc = s_a[wv][c];
            o0 = fmaf(zc, s_dec[c * 128 + l], o0);
            o1 = fmaf(zc, s_dec[c * 128 + 64 + l], o1);
        }
        out[(size_t)t * 128 + l] = o0;
        out[(size_t)t * 128 + 64 + l] = o1;
    }
}

extern "C" void kernel_launch(void* const* d_in, const int* in_sizes, int n_in,
                              void* d_out, int out_size, void* d_ws, size_t ws_size,
                              hipStream_t stream) {
    const float* x_C   = (const float*)d_in[0];
    const float* x_T   = (const float*)d_in[1];
    const float* dwW   = (const float*)d_in[2];
    const float* dwB   = (const float*)d_in[3];
    const float* pw    = (const float*)d_in[4];
    const float* pwb   = (const float*)d_in[5];
    const float* gam   = (const float*)d_in[6];
    const float* bet   = (const float*)d_in[7];
    const float* mean  = (const float*)d_in[8];
    const float* var   = (const float*)d_in[9];
    const float* encW  = (const float*)d_in[10];
    const float* encb  = (const float*)d_in[11];
    const float* pos   = (const float*)d_in[12];
    const float* lng   = (const float*)d_in[13];
    const float* lnb   = (const float*)d_in[14];
    const float* qkvW  = (const float*)d_in[15];
    const float* projW = (const float*)d_in[16];
    const float* projb = (const float*)d_in[17];
    const float* W1    = (const float*)d_in[18];
    const float* b1    = (const float*)d_in[19];
    const float* W2    = (const float*)d_in[20];
    const float* b2    = (const float*)d_in[21];
    const float* decW  = (const float*)d_in[22];
    const float* decb  = (const float*)d_in[23];
    float* out = (float*)d_out;

    float* ws   = (float*)d_ws;
    float* xpoi = ws;                       // 2,097,152 f
    float* ypoi = ws + 2097152;             // 2,097,152 f
    float* xdw  = ws + 4194304;             // 4,194,304 f (dead after k_pw_enc)
    float* ox   = xdw;                      // reuse: 2,097,152 f
    float* oy   = xdw + 2097152;            // reuse: 2,097,152 f
    __hip_bfloat16* qkv = (__hip_bfloat16*)(ws + 8388608);  // 12,582,912 bf16

    k_dwconv<<<16384, 256, 0, stream>>>(x_C, dwW, dwB, xdw);
    k_pw_enc<<<2048, 256, 0, stream>>>(xdw, x_C, pw, pwb, gam, bet, mean, var,
                                       encW, encb, pos, xpoi);
    k_yenc<<<1024, 256, 0, stream>>>(x_T, encW, encb, pos, ypoi);
    k_qkv<<<1024, 256, 0, stream>>>(xpoi, ypoi, qkvW, lng, lnb, qkv);
    k_attn<<<1024, 256, 0, stream>>>(qkv, ox, oy);
    k_final<<<512, 256, 0, stream>>>(ox, oy, xpoi, ypoi, projW, projb,
                                     W1, b1, W2, b2, decW, decb, lng, lnb, out);
}

// Round 2
// 246.372 us; speedup vs baseline: 2.6543x; 2.6543x over previous
//
#include <hip/hip_runtime.h>
#include <hip/hip_bf16.h>
#include <math.h>

#define EPSF 1e-5f

__device__ __forceinline__ float bf2f(unsigned short u) {
    union { unsigned int i; float f; } x; x.i = ((unsigned int)u) << 16; return x.f;
}
__device__ __forceinline__ unsigned short f2bf(float f) {
    union { float f; unsigned int i; } u; u.f = f;
    unsigned int r = u.i + 0x7FFFu + ((u.i >> 16) & 1u);
    return (unsigned short)(r >> 16);
}

// ---------------- K1: depthwise 3x3 conv + bias (4 ch x 4 px per thread) ----------------
__global__ __launch_bounds__(256) void k_dwconv(
    const float* __restrict__ xC, const float* __restrict__ dwW,
    const float* __restrict__ dwB, float* __restrict__ xdw)
{
    __shared__ float s_w[128 * 9];
    __shared__ float s_bias[128];
    int tid = threadIdx.x;
    for (int i = tid; i < 128 * 9; i += 256) s_w[i] = dwW[i];
    if (tid < 128) s_bias[tid] = dwB[tid];
    __syncthreads();
    int idx = blockIdx.x * 256 + tid;        // over 8192 pixel-groups * 32 ch-quads
    int c4 = (idx & 31) * 4;
    int pg = idx >> 5;
    int t0 = pg * 4;
    int b = t0 >> 14, n = t0 & 16383;
    int row = n >> 7, col0 = n & 127;
    float vb[3][6][4];
    #pragma unroll
    for (int ky = 0; ky < 3; ++ky) {
        int r = row + ky - 1;
        #pragma unroll
        for (int cx = 0; cx < 6; ++cx) {
            int cl = col0 + cx - 1;
            if ((unsigned)r < 128u && (unsigned)cl < 128u) {
                *(float4*)&vb[ky][cx][0] =
                    *(const float4*)&xC[((size_t)(b << 14) + (r << 7) + cl) * 128 + c4];
            } else {
                vb[ky][cx][0] = 0.f; vb[ky][cx][1] = 0.f; vb[ky][cx][2] = 0.f; vb[ky][cx][3] = 0.f;
            }
        }
    }
    float acc[4][4];
    #pragma unroll
    for (int p = 0; p < 4; ++p)
        #pragma unroll
        for (int j = 0; j < 4; ++j) acc[p][j] = s_bias[c4 + j];
    #pragma unroll
    for (int ky = 0; ky < 3; ++ky)
        #pragma unroll
        for (int kx = 0; kx < 3; ++kx)
            #pragma unroll
            for (int j = 0; j < 4; ++j) {
                float w = s_w[(c4 + j) * 9 + ky * 3 + kx];
                #pragma unroll
                for (int p = 0; p < 4; ++p)
                    acc[p][j] = fmaf(w, vb[ky][p + kx][j], acc[p][j]);
            }
    #pragma unroll
    for (int p = 0; p < 4; ++p) {
        float4 o; o.x = acc[p][0]; o.y = acc[p][1]; o.z = acc[p][2]; o.w = acc[p][3];
        *(float4*)&xdw[((size_t)t0 + p) * 128 + c4] = o;
    }
}

// ---------------- K2: pointwise conv + BN + ReLU + residual (in-place on xbuf) ----------------
__global__ __launch_bounds__(512) void k_pw(
    float* xbuf,                             // in: dwconv out; out: x1  (same buffer)
    const float* __restrict__ xC, const float* __restrict__ pw,
    const float* __restrict__ pwb, const float* __restrict__ gam,
    const float* __restrict__ bet, const float* __restrict__ mean,
    const float* __restrict__ var)
{
    __shared__ float s_in[64 * 128];
    __shared__ float s_wT[128 * 130];
    __shared__ float s_scale[128];
    __shared__ float s_beff[128];
    int tid = threadIdx.x;
    int T0 = blockIdx.x * 64;
    if (tid < 128) {
        float sc = gam[tid] * rsqrtf(var[tid] + EPSF);
        s_scale[tid] = sc;
        s_beff[tid] = (pwb[tid] - mean[tid]) * sc + bet[tid];
    }
    for (int i = tid; i < 2048; i += 512)
        ((float4*)s_in)[i] = ((const float4*)(xbuf + (size_t)T0 * 128))[i];
    __syncthreads();
    for (int i = tid; i < 4096; i += 512) {
        float4 w = ((const float4*)pw)[i];
        int co = i >> 5;
        int ci0 = (i & 31) * 4;
        float sc = s_scale[co];
        s_wT[(ci0 + 0) * 130 + co] = w.x * sc;
        s_wT[(ci0 + 1) * 130 + co] = w.y * sc;
        s_wT[(ci0 + 2) * 130 + co] = w.z * sc;
        s_wT[(ci0 + 3) * 130 + co] = w.w * sc;
    }
    __syncthreads();
    int q = tid & 31, co4 = q * 4;
    int tg = tid >> 5;                        // 16 groups x 4 tokens
    float acc[4][4];
    #pragma unroll
    for (int i = 0; i < 4; ++i)
        #pragma unroll
        for (int j = 0; j < 4; ++j) acc[i][j] = s_beff[co4 + j];
    for (int ci = 0; ci < 128; ++ci) {
        float4 w = *(const float4*)&s_wT[ci * 130 + co4];
        #pragma unroll
        for (int i = 0; i < 4; ++i) {
            float xin = s_in[(tg * 4 + i) * 128 + ci];
            acc[i][0] = fmaf(xin, w.x, acc[i][0]);
            acc[i][1] = fmaf(xin, w.y, acc[i][1]);
            acc[i][2] = fmaf(xin, w.z, acc[i][2]);
            acc[i][3] = fmaf(xin, w.w, acc[i][3]);
        }
    }
    #pragma unroll
    for (int i = 0; i < 4; ++i) {
        size_t t = T0 + tg * 4 + i;
        float4 r = *(const float4*)&xC[t * 128 + co4];
        float4 o;
        o.x = fmaxf(acc[i][0], 0.f) + r.x;
        o.y = fmaxf(acc[i][1], 0.f) + r.y;
        o.z = fmaxf(acc[i][2], 0.f) + r.z;
        o.w = fmaxf(acc[i][3], 0.f) + r.w;
        *(float4*)&xbuf[t * 128 + co4] = o;
    }
}

// ---------------- K3: enc + pos + LayerNorm -> wx / wy ----------------
__global__ __launch_bounds__(512) void k_encln(
    const float* __restrict__ x1, const float* __restrict__ xT,
    const float* __restrict__ encW, const float* __restrict__ encb,
    const float* __restrict__ pos, const float* __restrict__ lng,
    const float* __restrict__ lnb, float* __restrict__ wx, float* __restrict__ wy)
{
    __shared__ float s_in[64 * 128];
    __shared__ float s_w[128 * 64];
    int tid = threadIdx.x;
    int T0 = blockIdx.x * 64;
    int stream = blockIdx.y;
    for (int i = tid; i < 2048; i += 512) ((float4*)s_w)[i] = ((const float4*)encW)[i];
    if (stream == 0) {
        for (int i = tid; i < 2048; i += 512)
            ((float4*)s_in)[i] = ((const float4*)(x1 + (size_t)T0 * 128))[i];
    } else {
        for (int i = tid; i < 2048; i += 512) {
            float4 v = ((const float4*)(xT + (size_t)T0 * 128))[i];
            float4 o;
            o.x = v.x > 0.f ? 2.f * v.x : v.x;
            o.y = v.y > 0.f ? 2.f * v.y : v.y;
            o.z = v.z > 0.f ? 2.f * v.z : v.z;
            o.w = v.w > 0.f ? 2.f * v.w : v.w;
            ((float4*)s_in)[i] = o;
        }
    }
    __syncthreads();
    int q = tid & 15, o4 = q * 4;
    int tg = tid >> 4;                        // 32 groups x 2 tokens
    float acc[2][4] = {};
    for (int ci = 0; ci < 128; ++ci) {
        float4 w = *(const float4*)&s_w[ci * 64 + o4];
        #pragma unroll
        for (int i = 0; i < 2; ++i) {
            float xin = s_in[(tg * 2 + i) * 128 + ci];
            acc[i][0] = fmaf(xin, w.x, acc[i][0]);
            acc[i][1] = fmaf(xin, w.y, acc[i][1]);
            acc[i][2] = fmaf(xin, w.z, acc[i][2]);
            acc[i][3] = fmaf(xin, w.w, acc[i][3]);
        }
    }
    float4 eb = *(const float4*)&encb[o4];
    float4 g  = *(const float4*)&lng[o4];
    float4 bb = *(const float4*)&lnb[o4];
    float* dst = stream == 0 ? wx : wy;
    #pragma unroll
    for (int i = 0; i < 2; ++i) {
        int t = T0 + tg * 2 + i;
        int n = t & 16383;
        float4 pv = *(const float4*)&pos[(size_t)n * 64 + o4];
        float v0 = acc[i][0] + eb.x + pv.x;
        float v1 = acc[i][1] + eb.y + pv.y;
        float v2 = acc[i][2] + eb.z + pv.z;
        float v3 = acc[i][3] + eb.w + pv.w;
        float sm = v0 + v1 + v2 + v3;
        float sq = v0 * v0 + v1 * v1 + v2 * v2 + v3 * v3;
        #pragma unroll
        for (int off = 1; off < 16; off <<= 1) {
            sm += __shfl_xor(sm, off);
            sq += __shfl_xor(sq, off);
        }
        float m = sm * (1.f / 64.f);
        float vr = sq * (1.f / 64.f) - m * m;
        float rs = rsqrtf(vr + EPSF);
        float4 o;
        o.x = (v0 - m) * rs * g.x + bb.x;
        o.y = (v1 - m) * rs * g.y + bb.y;
        o.z = (v2 - m) * rs * g.z + bb.z;
        o.w = (v3 - m) * rs * g.w + bb.w;
        *(float4*)&dst[(size_t)t * 64 + o4] = o;
    }
}

// ---------------- K4: qkv GEMM (64 -> 192), bf16 window-major output ----------------
// layout: ((((s*2+b)*8+head)*64+wid)*256+p)*24 + {0..7 q, 8..15 k, 16..23 v}
__global__ __launch_bounds__(256) void k_qkv(
    const float* __restrict__ wx, const float* __restrict__ wy,
    const float* __restrict__ qkvW, unsigned short* __restrict__ qkv)
{
    __shared__ float s_in[64 * 64];
    __shared__ float s_qW[64 * 192];
    int tid = threadIdx.x;
    int T0 = blockIdx.x * 64;
    int s = blockIdx.y;
    const float* src = s == 0 ? wx : wy;
    for (int i = tid; i < 1024; i += 256)
        ((float4*)s_in)[i] = ((const float4*)(src + (size_t)T0 * 64))[i];
    for (int i = tid; i < 3072; i += 256)
        ((float4*)s_qW)[i] = ((const float4*)qkvW)[i];
    __syncthreads();
    int q = tid & 15, o4 = q * 4;
    int tg = tid >> 4;                        // 16 groups x 4 tokens
    float acc[3][4][4] = {};
    for (int c = 0; c < 64; ++c) {
        float4 w0 = *(const float4*)&s_qW[c * 192 + o4];
        float4 w1 = *(const float4*)&s_qW[c * 192 + 64 + o4];
        float4 w2 = *(const float4*)&s_qW[c * 192 + 128 + o4];
        #pragma unroll
        for (int i = 0; i < 4; ++i) {
            float xin = s_in[(tg * 4 + i) * 64 + c];
            acc[0][i][0] = fmaf(xin, w0.x, acc[0][i][0]);
            acc[0][i][1] = fmaf(xin, w0.y, acc[0][i][1]);
            acc[0][i][2] = fmaf(xin, w0.z, acc[0][i][2]);
            acc[0][i][3] = fmaf(xin, w0.w, acc[0][i][3]);
            acc[1][i][0] = fmaf(xin, w1.x, acc[1][i][0]);
            acc[1][i][1] = fmaf(xin, w1.y, acc[1][i][1]);
            acc[1][i][2] = fmaf(xin, w1.z, acc[1][i][2]);
            acc[1][i][3] = fmaf(xin, w1.w, acc[1][i][3]);
            acc[2][i][0] = fmaf(xin, w2.x, acc[2][i][0]);
            acc[2][i][1] = fmaf(xin, w2.y, acc[2][i][1]);
            acc[2][i][2] = fmaf(xin, w2.z, acc[2][i][2]);
            acc[2][i][3] = fmaf(xin, w2.w, acc[2][i][3]);
        }
    }
    int head = o4 >> 3, dpos = o4 & 7;
    #pragma unroll
    for (int i = 0; i < 4; ++i) {
        int t = T0 + tg * 4 + i;
        int b = t >> 14, n = t & 16383;
        int row = n >> 7, cp = n & 127;
        int wid = (row >> 4) * 8 + (cp >> 4);
        int p = (row & 15) * 16 + (cp & 15);
        size_t base = ((((size_t)(s * 2 + b) * 8 + head) * 64 + wid) * 256 + p) * 24 + dpos;
        #pragma unroll
        for (int sec = 0; sec < 3; ++sec) {
            uint2 val;
            val.x = (unsigned)f2bf(acc[sec][i][0]) | ((unsigned)f2bf(acc[sec][i][1]) << 16);
            val.y = (unsigned)f2bf(acc[sec][i][2]) | ((unsigned)f2bf(acc[sec][i][3]) << 16);
            *(uint2*)(qkv + base + sec * 8) = val;
        }
    }
}

// ---------------- K5: dual-stream windowed attention (cross values) ----------------
__global__ __launch_bounds__(256) void k_attn(
    const unsigned short* __restrict__ qkv,
    float* __restrict__ ox, float* __restrict__ oy)
{
    __shared__ float s_kx[256 * 8];
    __shared__ float s_vx[256 * 8];
    __shared__ float s_ky[256 * 8];
    __shared__ float s_vy[256 * 8];
    int i = threadIdx.x;
    int widg = blockIdx.x >> 3, head = blockIdx.x & 7;
    int b = widg >> 6, wid = widg & 63;
    size_t basex = (((size_t)(0 + b) * 8 + head) * 64 + wid) * 256;
    size_t basey = (((size_t)(2 + b) * 8 + head) * 64 + wid) * 256;
    const unsigned short* px = qkv + (basex + i) * 24;
    const unsigned short* py = qkv + (basey + i) * 24;
    union U8 { uint4 v; unsigned short u[8]; };
    U8 xq, xk, xv, yq, yk, yv;
    xq.v = ((const uint4*)px)[0]; xk.v = ((const uint4*)px)[1]; xv.v = ((const uint4*)px)[2];
    yq.v = ((const uint4*)py)[0]; yk.v = ((const uint4*)py)[1]; yv.v = ((const uint4*)py)[2];
    const float scale = 0.35355339059327373f * 1.4426950408889634f;  // *log2(e), use exp2
    float qx[8], qy[8];
    #pragma unroll
    for (int d = 0; d < 8; ++d) {
        qx[d] = bf2f(xq.u[d]) * scale;
        qy[d] = bf2f(yq.u[d]) * scale;
        s_kx[i * 8 + d] = bf2f(xk.u[d]);
        s_vx[i * 8 + d] = bf2f(xv.u[d]);
        s_ky[i * 8 + d] = bf2f(yk.u[d]);
        s_vy[i * 8 + d] = bf2f(yv.u[d]);
    }
    __syncthreads();
    float ax0[4] = {}, ax1[4] = {}, ay0[4] = {}, ay1[4] = {};
    float sx = 0.f, sy = 0.f;
    for (int j = 0; j < 256; ++j) {
        float4 ka = ((const float4*)s_kx)[j * 2], kb = ((const float4*)s_kx)[j * 2 + 1];
        float4 la = ((const float4*)s_ky)[j * 2], lb = ((const float4*)s_ky)[j * 2 + 1];
        float lx = qx[0] * ka.x + qx[1] * ka.y + qx[2] * ka.z + qx[3] * ka.w
                 + qx[4] * kb.x + qx[5] * kb.y + qx[6] * kb.z + qx[7] * kb.w;
        float ly = qy[0] * la.x + qy[1] * la.y + qy[2] * la.z + qy[3] * la.w
                 + qy[4] * lb.x + qy[5] * lb.y + qy[6] * lb.z + qy[7] * lb.w;
        float ex = exp2f(lx), ey = exp2f(ly);
        sx += ex; sy += ey;
        float4 va = ((const float4*)s_vy)[j * 2], vvb = ((const float4*)s_vy)[j * 2 + 1];
        float4 ua = ((const float4*)s_vx)[j * 2], ub = ((const float4*)s_vx)[j * 2 + 1];
        ax0[0] = fmaf(ex, va.x, ax0[0]); ax0[1] = fmaf(ex, va.y, ax0[1]);
        ax0[2] = fmaf(ex, va.z, ax0[2]); ax0[3] = fmaf(ex, va.w, ax0[3]);
        ax1[0] = fmaf(ex, vvb.x, ax1[0]); ax1[1] = fmaf(ex, vvb.y, ax1[1]);
        ax1[2] = fmaf(ex, vvb.z, ax1[2]); ax1[3] = fmaf(ex, vvb.w, ax1[3]);
        ay0[0] = fmaf(ey, ua.x, ay0[0]); ay0[1] = fmaf(ey, ua.y, ay0[1]);
        ay0[2] = fmaf(ey, ua.z, ay0[2]); ay0[3] = fmaf(ey, ua.w, ay0[3]);
        ay1[0] = fmaf(ey, ub.x, ay1[0]); ay1[1] = fmaf(ey, ub.y, ay1[1]);
        ay1[2] = fmaf(ey, ub.z, ay1[2]); ay1[3] = fmaf(ey, ub.w, ay1[3]);
    }
    int row = (wid >> 3) * 16 + (i >> 4);
    int col = (wid & 7) * 16 + (i & 15);
    size_t t = (size_t)b * 16384 + row * 128 + col;
    float ix = 1.f / sx, iy = 1.f / sy;
    float4 o;
    o.x = ax0[0] * ix; o.y = ax0[1] * ix; o.z = ax0[2] * ix; o.w = ax0[3] * ix;
    *(float4*)&ox[t * 64 + head * 8] = o;
    o.x = ax1[0] * ix; o.y = ax1[1] * ix; o.z = ax1[2] * ix; o.w = ax1[3] * ix;
    *(float4*)&ox[t * 64 + head * 8 + 4] = o;
    o.x = ay0[0] * iy; o.y = ay0[1] * iy; o.z = ay0[2] * iy; o.w = ay0[3] * iy;
    *(float4*)&oy[t * 64 + head * 8] = o;
    o.x = ay1[0] * iy; o.y = ay1[1] * iy; o.z = ay1[2] * iy; o.w = ay1[3] * iy;
    *(float4*)&oy[t * 64 + head * 8 + 4] = o;
}

// ---------------- K6: proj + residual + FFN (both streams) -> z = xf_x + xf_y ----------------
__global__ __launch_bounds__(256) void k_fuse(
    const float* __restrict__ ox, const float* __restrict__ oy,
    const float* __restrict__ wx, const float* __restrict__ wy,
    const float* __restrict__ projW, const float* __restrict__ projb,
    const float* __restrict__ W1, const float* __restrict__ b1,
    const float* __restrict__ W2, const float* __restrict__ b2,
    const float* __restrict__ lng, const float* __restrict__ lnb,
    float* __restrict__ z)
{
    __shared__ float s_proj[4096];
    __shared__ float s_W1[4096];
    __shared__ float s_W2[4096];
    __shared__ float s_a[4096];
    __shared__ float s_b[4096];
    int tid = threadIdx.x;
    int T0 = blockIdx.x * 64;
    for (int i = tid; i < 1024; i += 256) {
        ((float4*)s_proj)[i] = ((const float4*)projW)[i];
        ((float4*)s_W1)[i]   = ((const float4*)W1)[i];
        ((float4*)s_W2)[i]   = ((const float4*)W2)[i];
    }
    int q = tid & 15, o4 = q * 4;
    int tg = tid >> 4;                         // 16 groups x 4 tokens
    float4 pbv = *(const float4*)&projb[o4];
    float4 b1v = *(const float4*)&b1[o4];
    float4 b2v = *(const float4*)&b2[o4];
    float4 gv  = *(const float4*)&lng[o4];
    float4 bv  = *(const float4*)&lnb[o4];
    float zacc[4][4] = {};
    for (int s = 0; s < 2; ++s) {
        const float* osrc = s == 0 ? ox : oy;
        const float* wsrc = s == 0 ? wx : wy;
        __syncthreads();
        for (int i = tid; i < 1024; i += 256)
            ((float4*)s_a)[i] = ((const float4*)(osrc + (size_t)T0 * 64))[i];
        __syncthreads();
        // GEMM1: xm = o @ proj + pb + w
        float xm[4][4];
        #pragma unroll
        for (int i = 0; i < 4; ++i) {
            xm[i][0] = pbv.x; xm[i][1] = pbv.y; xm[i][2] = pbv.z; xm[i][3] = pbv.w;
        }
        for (int c = 0; c < 64; ++c) {
            float4 w = *(const float4*)&s_proj[c * 64 + o4];
            #pragma unroll
            for (int i = 0; i < 4; ++i) {
                float a = s_a[(tg * 4 + i) * 64 + c];
                xm[i][0] = fmaf(a, w.x, xm[i][0]);
                xm[i][1] = fmaf(a, w.y, xm[i][1]);
                xm[i][2] = fmaf(a, w.z, xm[i][2]);
                xm[i][3] = fmaf(a, w.w, xm[i][3]);
            }
        }
        #pragma unroll
        for (int i = 0; i < 4; ++i) {
            size_t t = T0 + tg * 4 + i;
            float4 wv = *(const float4*)&wsrc[t * 64 + o4];
            xm[i][0] += wv.x; xm[i][1] += wv.y; xm[i][2] += wv.z; xm[i][3] += wv.w;
        }
        // LN(xm) -> u  (in s_b)
        #pragma unroll
        for (int i = 0; i < 4; ++i) {
            float sm = xm[i][0] + xm[i][1] + xm[i][2] + xm[i][3];
            float sq = xm[i][0] * xm[i][0] + xm[i][1] * xm[i][1]
                     + xm[i][2] * xm[i][2] + xm[i][3] * xm[i][3];
            #pragma unroll
            for (int off = 1; off < 16; off <<= 1) {
                sm += __shfl_xor(sm, off);
                sq += __shfl_xor(sq, off);
            }
            float m = sm * (1.f / 64.f);
            float vr = sq * (1.f / 64.f) - m * m;
            float rs = rsqrtf(vr + EPSF);
            float4 u;
            u.x = (xm[i][0] - m) * rs * gv.x + bv.x;
            u.y = (xm[i][1] - m) * rs * gv.y + bv.y;
            u.z = (xm[i][2] - m) * rs * gv.z + bv.z;
            u.w = (xm[i][3] - m) * rs * gv.w + bv.w;
            *(float4*)&s_b[(tg * 4 + i) * 64 + o4] = u;
        }
        __syncthreads();
        // GEMM2: h = relu(u @ W1 + b1) -> s_a
        float h[4][4];
        #pragma unroll
        for (int i = 0; i < 4; ++i) {
            h[i][0] = b1v.x; h[i][1] = b1v.y; h[i][2] = b1v.z; h[i][3] = b1v.w;
        }
        for (int c = 0; c < 64; ++c) {
            float4 w = *(const float4*)&s_W1[c * 64 + o4];
            #pragma unroll
            for (int i = 0; i < 4; ++i) {
                float a = s_b[(tg * 4 + i) * 64 + c];
                h[i][0] = fmaf(a, w.x, h[i][0]);
                h[i][1] = fmaf(a, w.y, h[i][1]);
                h[i][2] = fmaf(a, w.z, h[i][2]);
                h[i][3] = fmaf(a, w.w, h[i][3]);
            }
        }
        #pragma unroll
        for (int i = 0; i < 4; ++i) {
            float4 u;
            u.x = fmaxf(h[i][0], 0.f); u.y = fmaxf(h[i][1], 0.f);
            u.z = fmaxf(h[i][2], 0.f); u.w = fmaxf(h[i][3], 0.f);
            *(float4*)&s_a[(tg * 4 + i) * 64 + o4] = u;
        }
        __syncthreads();
        // GEMM3: xf = xm + h @ W2 + b2 ; z += xf
        float xf[4][4];
        #pragma unroll
        for (int i = 0; i < 4; ++i) {
            xf[i][0] = xm[i][0] + b2v.x; xf[i][1] = xm[i][1] + b2v.y;
            xf[i][2] = xm[i][2] + b2v.z; xf[i][3] = xm[i][3] + b2v.w;
        }
        for (int c = 0; c < 64; ++c) {
            float4 w = *(const float4*)&s_W2[c * 64 + o4];
            #pragma unroll
            for (int i = 0; i < 4; ++i) {
                float a = s_a[(tg * 4 + i) * 64 + c];
                xf[i][0] = fmaf(a, w.x, xf[i][0]);
                xf[i][1] = fmaf(a, w.y, xf[i][1]);
                xf[i][2] = fmaf(a, w.z, xf[i][2]);
                xf[i][3] = fmaf(a, w.w, xf[i][3]);
            }
        }
        #pragma unroll
        for (int i = 0; i < 4; ++i) {
            zacc[i][0] += xf[i][0]; zacc[i][1] += xf[i][1];
            zacc[i][2] += xf[i][2]; zacc[i][3] += xf[i][3];
        }
    }
    #pragma unroll
    for (int i = 0; i < 4; ++i) {
        size_t t = T0 + tg * 4 + i;
        float4 o; o.x = zacc[i][0]; o.y = zacc[i][1]; o.z = zacc[i][2]; o.w = zacc[i][3];
        *(float4*)&z[t * 64 + o4] = o;
    }
}

// ---------------- K7: dec GEMM (64 -> 128) + 2*decb ----------------
__global__ __launch_bounds__(256) void k_dec(
    const float* __restrict__ z, const float* __restrict__ decW,
    const float* __restrict__ decb, float* __restrict__ out)
{
    __shared__ float s_z[4096];
    __shared__ float s_dec[8192];
    int tid = threadIdx.x;
    int T0 = blockIdx.x * 64;
    for (int i = tid; i < 1024; i += 256)
        ((float4*)s_z)[i] = ((const float4*)(z + (size_t)T0 * 64))[i];
    for (int i = tid; i < 2048; i += 256)
        ((float4*)s_dec)[i] = ((const float4*)decW)[i];
    __syncthreads();
    int q = tid & 31, m4 = q * 4;
    int tg = tid >> 5;                         // 8 groups x 8 tokens
    float4 dbv = *(const float4*)&decb[m4];
    float acc[8][4];
    #pragma unroll
    for (int i = 0; i < 8; ++i) {
        acc[i][0] = 2.f * dbv.x; acc[i][1] = 2.f * dbv.y;
        acc[i][2] = 2.f * dbv.z; acc[i][3] = 2.f * dbv.w;
    }
    for (int c = 0; c < 64; ++c) {
        float4 w = *(const float4*)&s_dec[c * 128 + m4];
        #pragma unroll
        for (int i = 0; i < 8; ++i) {
            float a = s_z[(tg * 8 + i) * 64 + c];
            acc[i][0] = fmaf(a, w.x, acc[i][0]);
            acc[i][1] = fmaf(a, w.y, acc[i][1]);
            acc[i][2] = fmaf(a, w.z, acc[i][2]);
            acc[i][3] = fmaf(a, w.w, acc[i][3]);
        }
    }
    #pragma unroll
    for (int i = 0; i < 8; ++i) {
        size_t t = T0 + tg * 8 + i;
        float4 o; o.x = acc[i][0]; o.y = acc[i][1]; o.z = acc[i][2]; o.w = acc[i][3];
        *(float4*)&out[t * 128 + m4] = o;
    }
}

extern "C" void kernel_launch(void* const* d_in, const int* in_sizes, int n_in,
                              void* d_out, int out_size, void* d_ws, size_t ws_size,
                              hipStream_t stream) {
    const float* x_C   = (const float*)d_in[0];
    const float* x_T   = (const float*)d_in[1];
    const float* dwW   = (const float*)d_in[2];
    const float* dwB   = (const float*)d_in[3];
    const float* pw    = (const float*)d_in[4];
    const float* pwb   = (const float*)d_in[5];
    const float* gam   = (const float*)d_in[6];
    const float* bet   = (const float*)d_in[7];
    const float* mean  = (const float*)d_in[8];
    const float* var   = (const float*)d_in[9];
    const float* encW  = (const float*)d_in[10];
    const float* encb  = (const float*)d_in[11];
    const float* pos   = (const float*)d_in[12];
    const float* lng   = (const float*)d_in[13];
    const float* lnb   = (const float*)d_in[14];
    const float* qkvW  = (const float*)d_in[15];
    const float* projW = (const float*)d_in[16];
    const float* projb = (const float*)d_in[17];
    const float* W1    = (const float*)d_in[18];
    const float* b1    = (const float*)d_in[19];
    const float* W2    = (const float*)d_in[20];
    const float* b2    = (const float*)d_in[21];
    const float* decW  = (const float*)d_in[22];
    const float* decb  = (const float*)d_in[23];
    float* out = (float*)d_out;

    float* ws = (float*)d_ws;
    // region A (6,291,456 f): xdw/x1 (K1-K3), then qkv bf16 (K4-K5), then z (K6-K7)
    float* xbuf = ws;
    unsigned short* qkv = (unsigned short*)ws;
    float* z    = ws;
    float* wx   = ws + 6291456;
    float* wy   = ws + 8388608;
    float* ox   = ws + 10485760;
    float* oy   = ws + 12582912;

    k_dwconv<<<1024, 256, 0, stream>>>(x_C, dwW, dwB, xbuf);
    k_pw<<<512, 512, 0, stream>>>(xbuf, x_C, pw, pwb, gam, bet, mean, var);
    k_encln<<<dim3(512, 2), 512, 0, stream>>>(xbuf, x_T, encW, encb, pos, lng, lnb, wx, wy);
    k_qkv<<<dim3(512, 2), 256, 0, stream>>>(wx, wy, qkvW, qkv);
    k_attn<<<1024, 256, 0, stream>>>(qkv, ox, oy);
    k_fuse<<<512, 256, 0, stream>>>(ox, oy, wx, wy, projW, projb,
                                    W1, b1, W2, b2, lng, lnb, z);
    k_dec<<<512, 256, 0, stream>>>(z, decW, decb, out);
}

// Round 3
// 191.038 us; speedup vs baseline: 3.4231x; 1.2896x over previous
//
#include <hip/hip_runtime.h>
#include <hip/hip_bf16.h>
#include <math.h>

#define EPSF 1e-5f
// scale (1/sqrt(8)) * log2(e), folded into k at qkv time
#define KSCL 0.51010090329771713f

typedef __attribute__((ext_vector_type(8))) short short8;   // 8 bf16 = 4 VGPR
typedef __attribute__((ext_vector_type(16))) float f32x16;  // MFMA 32x32 acc

__device__ __forceinline__ float bf2f(unsigned short u) {
    union { unsigned int i; float f; } x; x.i = ((unsigned int)u) << 16; return x.f;
}
__device__ __forceinline__ unsigned int f2bf(float f) {
    union { float f; unsigned int i; } u; u.f = f;
    unsigned int r = u.i + 0x7FFFu + ((u.i >> 16) & 1u);
    return r >> 16;
}

// ---------------- K1: depthwise 3x3 conv + bias (4 ch x 4 px per thread) ----------------
__global__ __launch_bounds__(256) void k_dwconv(
    const float* __restrict__ xC, const float* __restrict__ dwW,
    const float* __restrict__ dwB, float* __restrict__ xdw)
{
    __shared__ float s_w[128 * 9];
    __shared__ float s_bias[128];
    int tid = threadIdx.x;
    for (int i = tid; i < 128 * 9; i += 256) s_w[i] = dwW[i];
    if (tid < 128) s_bias[tid] = dwB[tid];
    __syncthreads();
    int idx = blockIdx.x * 256 + tid;
    int c4 = (idx & 31) * 4;
    int pg = idx >> 5;
    int t0 = pg * 4;
    int b = t0 >> 14, n = t0 & 16383;
    int row = n >> 7, col0 = n & 127;
    float vb[3][6][4];
    #pragma unroll
    for (int ky = 0; ky < 3; ++ky) {
        int r = row + ky - 1;
        #pragma unroll
        for (int cx = 0; cx < 6; ++cx) {
            int cl = col0 + cx - 1;
            if ((unsigned)r < 128u && (unsigned)cl < 128u) {
                *(float4*)&vb[ky][cx][0] =
                    *(const float4*)&xC[((size_t)(b << 14) + (r << 7) + cl) * 128 + c4];
            } else {
                vb[ky][cx][0] = 0.f; vb[ky][cx][1] = 0.f; vb[ky][cx][2] = 0.f; vb[ky][cx][3] = 0.f;
            }
        }
    }
    float acc[4][4];
    #pragma unroll
    for (int p = 0; p < 4; ++p)
        #pragma unroll
        for (int j = 0; j < 4; ++j) acc[p][j] = s_bias[c4 + j];
    #pragma unroll
    for (int ky = 0; ky < 3; ++ky)
        #pragma unroll
        for (int kx = 0; kx < 3; ++kx)
            #pragma unroll
            for (int j = 0; j < 4; ++j) {
                float w = s_w[(c4 + j) * 9 + ky * 3 + kx];
                #pragma unroll
                for (int p = 0; p < 4; ++p)
                    acc[p][j] = fmaf(w, vb[ky][p + kx][j], acc[p][j]);
            }
    #pragma unroll
    for (int p = 0; p < 4; ++p) {
        float4 o; o.x = acc[p][0]; o.y = acc[p][1]; o.z = acc[p][2]; o.w = acc[p][3];
        *(float4*)&xdw[((size_t)t0 + p) * 128 + c4] = o;
    }
}

// ---------------- K2: pointwise conv + BN + ReLU + residual (in-place on xbuf) ----------------
__global__ __launch_bounds__(512) void k_pw(
    float* xbuf,
    const float* __restrict__ xC, const float* __restrict__ pw,
    const float* __restrict__ pwb, const float* __restrict__ gam,
    const float* __restrict__ bet, const float* __restrict__ mean,
    const float* __restrict__ var)
{
    __shared__ float s_in[64 * 128];
    __shared__ float s_wT[128 * 130];
    __shared__ float s_scale[128];
    __shared__ float s_beff[128];
    int tid = threadIdx.x;
    int T0 = blockIdx.x * 64;
    if (tid < 128) {
        float sc = gam[tid] * rsqrtf(var[tid] + EPSF);
        s_scale[tid] = sc;
        s_beff[tid] = (pwb[tid] - mean[tid]) * sc + bet[tid];
    }
    for (int i = tid; i < 2048; i += 512)
        ((float4*)s_in)[i] = ((const float4*)(xbuf + (size_t)T0 * 128))[i];
    __syncthreads();
    for (int i = tid; i < 4096; i += 512) {
        float4 w = ((const float4*)pw)[i];
        int co = i >> 5;
        int ci0 = (i & 31) * 4;
        float sc = s_scale[co];
        s_wT[(ci0 + 0) * 130 + co] = w.x * sc;
        s_wT[(ci0 + 1) * 130 + co] = w.y * sc;
        s_wT[(ci0 + 2) * 130 + co] = w.z * sc;
        s_wT[(ci0 + 3) * 130 + co] = w.w * sc;
    }
    __syncthreads();
    int q = tid & 31, co4 = q * 4;
    int tg = tid >> 5;
    float acc[4][4];
    #pragma unroll
    for (int i = 0; i < 4; ++i)
        #pragma unroll
        for (int j = 0; j < 4; ++j) acc[i][j] = s_beff[co4 + j];
    for (int ci = 0; ci < 128; ++ci) {
        float4 w = *(const float4*)&s_wT[ci * 130 + co4];
        #pragma unroll
        for (int i = 0; i < 4; ++i) {
            float xin = s_in[(tg * 4 + i) * 128 + ci];
            acc[i][0] = fmaf(xin, w.x, acc[i][0]);
            acc[i][1] = fmaf(xin, w.y, acc[i][1]);
            acc[i][2] = fmaf(xin, w.z, acc[i][2]);
            acc[i][3] = fmaf(xin, w.w, acc[i][3]);
        }
    }
    #pragma unroll
    for (int i = 0; i < 4; ++i) {
        size_t t = T0 + tg * 4 + i;
        float4 r = *(const float4*)&xC[t * 128 + co4];
        float4 o;
        o.x = fmaxf(acc[i][0], 0.f) + r.x;
        o.y = fmaxf(acc[i][1], 0.f) + r.y;
        o.z = fmaxf(acc[i][2], 0.f) + r.z;
        o.w = fmaxf(acc[i][3], 0.f) + r.w;
        *(float4*)&xbuf[t * 128 + co4] = o;
    }
}

// ---------------- K3: enc + pos + LayerNorm -> wx / wy ----------------
__global__ __launch_bounds__(512) void k_encln(
    const float* __restrict__ x1, const float* __restrict__ xT,
    const float* __restrict__ encW, const float* __restrict__ encb,
    const float* __restrict__ pos, const float* __restrict__ lng,
    const float* __restrict__ lnb, float* __restrict__ wx, float* __restrict__ wy)
{
    __shared__ float s_in[64 * 128];
    __shared__ float s_w[128 * 64];
    int tid = threadIdx.x;
    int T0 = blockIdx.x * 64;
    int stream = blockIdx.y;
    for (int i = tid; i < 2048; i += 512) ((float4*)s_w)[i] = ((const float4*)encW)[i];
    if (stream == 0) {
        for (int i = tid; i < 2048; i += 512)
            ((float4*)s_in)[i] = ((const float4*)(x1 + (size_t)T0 * 128))[i];
    } else {
        for (int i = tid; i < 2048; i += 512) {
            float4 v = ((const float4*)(xT + (size_t)T0 * 128))[i];
            float4 o;
            o.x = v.x > 0.f ? 2.f * v.x : v.x;
            o.y = v.y > 0.f ? 2.f * v.y : v.y;
            o.z = v.z > 0.f ? 2.f * v.z : v.z;
            o.w = v.w > 0.f ? 2.f * v.w : v.w;
            ((float4*)s_in)[i] = o;
        }
    }
    __syncthreads();
    int q = tid & 15, o4 = q * 4;
    int tg = tid >> 4;
    float acc[2][4] = {};
    for (int ci = 0; ci < 128; ++ci) {
        float4 w = *(const float4*)&s_w[ci * 64 + o4];
        #pragma unroll
        for (int i = 0; i < 2; ++i) {
            float xin = s_in[(tg * 2 + i) * 128 + ci];
            acc[i][0] = fmaf(xin, w.x, acc[i][0]);
            acc[i][1] = fmaf(xin, w.y, acc[i][1]);
            acc[i][2] = fmaf(xin, w.z, acc[i][2]);
            acc[i][3] = fmaf(xin, w.w, acc[i][3]);
        }
    }
    float4 eb = *(const float4*)&encb[o4];
    float4 g  = *(const float4*)&lng[o4];
    float4 bb = *(const float4*)&lnb[o4];
    float* dst = stream == 0 ? wx : wy;
    #pragma unroll
    for (int i = 0; i < 2; ++i) {
        int t = T0 + tg * 2 + i;
        int n = t & 16383;
        float4 pv = *(const float4*)&pos[(size_t)n * 64 + o4];
        float v0 = acc[i][0] + eb.x + pv.x;
        float v1 = acc[i][1] + eb.y + pv.y;
        float v2 = acc[i][2] + eb.z + pv.z;
        float v3 = acc[i][3] + eb.w + pv.w;
        float sm = v0 + v1 + v2 + v3;
        float sq = v0 * v0 + v1 * v1 + v2 * v2 + v3 * v3;
        #pragma unroll
        for (int off = 1; off < 16; off <<= 1) {
            sm += __shfl_xor(sm, off);
            sq += __shfl_xor(sq, off);
        }
        float m = sm * (1.f / 64.f);
        float vr = sq * (1.f / 64.f) - m * m;
        float rs = rsqrtf(vr + EPSF);
        float4 o;
        o.x = (v0 - m) * rs * g.x + bb.x;
        o.y = (v1 - m) * rs * g.y + bb.y;
        o.z = (v2 - m) * rs * g.z + bb.z;
        o.w = (v3 - m) * rs * g.w + bb.w;
        *(float4*)&dst[(size_t)t * 64 + o4] = o;
    }
}

// ---------------- K4: qkv GEMM (64 -> 192), bf16 outputs for MFMA attention ----------
// qk: per combo=((s*2+b)*8+head)*64+wid, token p: 16 bf16 {q[0..7], k[0..7]*KSCL}
// vT: per combo: [d=0..7][p=0..255] bf16 (transposed v)
__global__ __launch_bounds__(256) void k_qkv(
    const float* __restrict__ wx, const float* __restrict__ wy,
    const float* __restrict__ qkvW, unsigned short* __restrict__ qk,
    unsigned short* __restrict__ vT)
{
    __shared__ float s_in[64 * 64];
    __shared__ float s_qW[64 * 192];
    int tid = threadIdx.x;
    int T0 = blockIdx.x * 64;
    int s = blockIdx.y;
    const float* src = s == 0 ? wx : wy;
    for (int i = tid; i < 1024; i += 256)
        ((float4*)s_in)[i] = ((const float4*)(src + (size_t)T0 * 64))[i];
    for (int i = tid; i < 3072; i += 256)
        ((float4*)s_qW)[i] = ((const float4*)qkvW)[i];
    __syncthreads();
    int q = tid & 15, o4 = q * 4;
    int tg = tid >> 4;
    float acc[3][4][4] = {};
    for (int c = 0; c < 64; ++c) {
        float4 w0 = *(const float4*)&s_qW[c * 192 + o4];
        float4 w1 = *(const float4*)&s_qW[c * 192 + 64 + o4];
        float4 w2 = *(const float4*)&s_qW[c * 192 + 128 + o4];
        #pragma unroll
        for (int i = 0; i < 4; ++i) {
            float xin = s_in[(tg * 4 + i) * 64 + c];
            acc[0][i][0] = fmaf(xin, w0.x, acc[0][i][0]);
            acc[0][i][1] = fmaf(xin, w0.y, acc[0][i][1]);
            acc[0][i][2] = fmaf(xin, w0.z, acc[0][i][2]);
            acc[0][i][3] = fmaf(xin, w0.w, acc[0][i][3]);
            acc[1][i][0] = fmaf(xin, w1.x, acc[1][i][0]);
            acc[1][i][1] = fmaf(xin, w1.y, acc[1][i][1]);
            acc[1][i][2] = fmaf(xin, w1.z, acc[1][i][2]);
            acc[1][i][3] = fmaf(xin, w1.w, acc[1][i][3]);
            acc[2][i][0] = fmaf(xin, w2.x, acc[2][i][0]);
            acc[2][i][1] = fmaf(xin, w2.y, acc[2][i][1]);
            acc[2][i][2] = fmaf(xin, w2.z, acc[2][i][2]);
            acc[2][i][3] = fmaf(xin, w2.w, acc[2][i][3]);
        }
    }
    int head = o4 >> 3, dpos = o4 & 7;
    int t0 = T0 + tg * 4;
    int b = t0 >> 14, n = t0 & 16383;
    int row = n >> 7, cp = n & 127;
    int wid = (row >> 4) * 8 + (cp >> 4);
    int p0 = (row & 15) * 16 + (cp & 15);
    size_t combo = (size_t)(s * 2 + b) * 512 + head * 64 + wid;
    unsigned short* qrec = qk + combo * 4096;
    #pragma unroll
    for (int i = 0; i < 4; ++i) {
        int p = p0 + i;
        uint2 qv;
        qv.x = f2bf(acc[0][i][0]) | (f2bf(acc[0][i][1]) << 16);
        qv.y = f2bf(acc[0][i][2]) | (f2bf(acc[0][i][3]) << 16);
        *(uint2*)(qrec + p * 16 + dpos) = qv;
        uint2 kv;
        kv.x = f2bf(acc[1][i][0] * KSCL) | (f2bf(acc[1][i][1] * KSCL) << 16);
        kv.y = f2bf(acc[1][i][2] * KSCL) | (f2bf(acc[1][i][3] * KSCL) << 16);
        *(uint2*)(qrec + p * 16 + 8 + dpos) = kv;
    }
    unsigned short* vrec = vT + combo * 2048;
    #pragma unroll
    for (int jj = 0; jj < 4; ++jj) {
        uint2 vv;
        vv.x = f2bf(acc[2][0][jj]) | (f2bf(acc[2][1][jj]) << 16);
        vv.y = f2bf(acc[2][2][jj]) | (f2bf(acc[2][3][jj]) << 16);
        *(uint2*)(vrec + (dpos + jj) * 256 + p0) = vv;
    }
}

// ---------------- K5: MFMA dual-stream windowed attention (cross values) -------------
// block = (s, b, head, wid); 4 waves x 64 queries. No LDS.
// C[j][q] = mfma(K, Q^T); P = exp2(C); D[d][q] = mfma(V^T, P) accumulated over j,
// with V rows >= 8 set to 1.0 so D row 8 = softmax denominator.
__global__ __launch_bounds__(256) void k_attn(
    const unsigned short* __restrict__ qk, const unsigned short* __restrict__ vT,
    float* __restrict__ ox, float* __restrict__ oy)
{
    int tid = threadIdx.x;
    int wave = tid >> 6, lane = tid & 63;
    int lh = lane >> 5, l31 = lane & 31;
    int bx = blockIdx.x;
    int s = bx >> 10;
    int r = bx & 1023;                 // (b*8+head)*64 + wid
    int head = (r >> 6) & 7, wid = r & 63, b = r >> 9;
    const unsigned short* qbase = qk + ((size_t)s * 1024 + r) * 4096;
    const unsigned short* vbase = vT + ((size_t)(s ^ 1) * 1024 + r) * 2048;  // cross v

    short8 qf[2];
    #pragma unroll
    for (int qt = 0; qt < 2; ++qt) {
        uint4 v = {0u, 0u, 0u, 0u};
        if (lh == 0) v = *(const uint4*)(qbase + (size_t)(wave * 64 + qt * 32 + l31) * 16);
        qf[qt] = __builtin_bit_cast(short8, v);
    }
    f32x16 acc[2];
    #pragma unroll
    for (int qt = 0; qt < 2; ++qt) acc[qt] = (f32x16){};
    const uint4 onesv = {0x3F803F80u, 0x3F803F80u, 0x3F803F80u, 0x3F803F80u};

    for (int jt = 0; jt < 8; ++jt) {
        uint4 kv = {0u, 0u, 0u, 0u};
        if (lh == 0) kv = *(const uint4*)(qbase + (size_t)(jt * 32 + l31) * 16 + 8);
        short8 kf = __builtin_bit_cast(short8, kv);
        uint4 v0 = onesv, v1 = onesv;
        if (l31 < 8) {
            const unsigned short* vp = vbase + l31 * 256 + jt * 32 + lh * 8;
            v0 = *(const uint4*)vp;
            v1 = *(const uint4*)(vp + 16);
        }
        short8 vf0 = __builtin_bit_cast(short8, v0);
        short8 vf1 = __builtin_bit_cast(short8, v1);
        #pragma unroll
        for (int qt = 0; qt < 2; ++qt) {
            f32x16 c = __builtin_amdgcn_mfma_f32_32x32x16_bf16(kf, qf[qt], (f32x16){}, 0, 0, 0);
            float p[16];
            #pragma unroll
            for (int i = 0; i < 16; ++i) p[i] = exp2f(c[i]);
            unsigned pk[8], xs[8];
            #pragma unroll
            for (int i = 0; i < 8; ++i) {
                unsigned pkv;
                asm("v_cvt_pk_bf16_f32 %0, %1, %2" : "=v"(pkv) : "v"(p[2 * i]), "v"(p[2 * i + 1]));
                pk[i] = pkv;
            }
            #pragma unroll
            for (int i = 0; i < 8; ++i) xs[i] = (unsigned)__shfl_xor((int)pk[i], 32);
            // B fragment for K-step 0 (j = jt*32 + 0..15)
            uint4 bw0;
            bw0.x = lh ? xs[2] : pk[0];
            bw0.y = lh ? xs[3] : pk[1];
            bw0.z = lh ? pk[2] : xs[0];
            bw0.w = lh ? pk[3] : xs[1];
            // B fragment for K-step 1 (j = jt*32 + 16..31)
            uint4 bw1;
            bw1.x = lh ? xs[6] : pk[4];
            bw1.y = lh ? xs[7] : pk[5];
            bw1.z = lh ? pk[6] : xs[4];
            bw1.w = lh ? pk[7] : xs[5];
            short8 B0 = __builtin_bit_cast(short8, bw0);
            short8 B1 = __builtin_bit_cast(short8, bw1);
            acc[qt] = __builtin_amdgcn_mfma_f32_32x32x16_bf16(vf0, B0, acc[qt], 0, 0, 0);
            acc[qt] = __builtin_amdgcn_mfma_f32_32x32x16_bf16(vf1, B1, acc[qt], 0, 0, 0);
        }
    }
    float* dst = s ? oy : ox;
    #pragma unroll
    for (int qt = 0; qt < 2; ++qt) {
        float sown = acc[qt][4];               // D row 8 (lh==0 lanes) = sum
        float sxc = __shfl_xor(sown, 32);
        float ssum = lh ? sxc : sown;
        float inv = 1.f / ssum;
        int p = wave * 64 + qt * 32 + l31;
        int orow = (wid >> 3) * 16 + (p >> 4);
        int ocol = (wid & 7) * 16 + (p & 15);
        size_t t = (size_t)b * 16384 + orow * 128 + ocol;
        float4 o;
        o.x = acc[qt][0] * inv; o.y = acc[qt][1] * inv;
        o.z = acc[qt][2] * inv; o.w = acc[qt][3] * inv;
        *(float4*)&dst[t * 64 + head * 8 + lh * 4] = o;
    }
}

// ---------------- K6: proj + residual + FFN (both streams) -> z = xf_x + xf_y -------
__global__ __launch_bounds__(256) void k_fuse(
    const float* __restrict__ ox, const float* __restrict__ oy,
    const float* __restrict__ wx, const float* __restrict__ wy,
    const float* __restrict__ projW, const float* __restrict__ projb,
    const float* __restrict__ W1, const float* __restrict__ b1,
    const float* __restrict__ W2, const float* __restrict__ b2,
    const float* __restrict__ lng, const float* __restrict__ lnb,
    float* __restrict__ z)
{
    __shared__ float s_proj[4096];
    __shared__ float s_W1[4096];
    __shared__ float s_W2[4096];
    __shared__ float s_a[4096];
    __shared__ float s_b[4096];
    int tid = threadIdx.x;
    int T0 = blockIdx.x * 64;
    for (int i = tid; i < 1024; i += 256) {
        ((float4*)s_proj)[i] = ((const float4*)projW)[i];
        ((float4*)s_W1)[i]   = ((const float4*)W1)[i];
        ((float4*)s_W2)[i]   = ((const float4*)W2)[i];
    }
    int q = tid & 15, o4 = q * 4;
    int tg = tid >> 4;
    float4 pbv = *(const float4*)&projb[o4];
    float4 b1v = *(const float4*)&b1[o4];
    float4 b2v = *(const float4*)&b2[o4];
    float4 gv  = *(const float4*)&lng[o4];
    float4 bv  = *(const float4*)&lnb[o4];
    float zacc[4][4] = {};
    for (int s = 0; s < 2; ++s) {
        const float* osrc = s == 0 ? ox : oy;
        const float* wsrc = s == 0 ? wx : wy;
        __syncthreads();
        for (int i = tid; i < 1024; i += 256)
            ((float4*)s_a)[i] = ((const float4*)(osrc + (size_t)T0 * 64))[i];
        __syncthreads();
        float xm[4][4];
        #pragma unroll
        for (int i = 0; i < 4; ++i) {
            xm[i][0] = pbv.x; xm[i][1] = pbv.y; xm[i][2] = pbv.z; xm[i][3] = pbv.w;
        }
        for (int c = 0; c < 64; ++c) {
            float4 w = *(const float4*)&s_proj[c * 64 + o4];
            #pragma unroll
            for (int i = 0; i < 4; ++i) {
                float a = s_a[(tg * 4 + i) * 64 + c];
                xm[i][0] = fmaf(a, w.x, xm[i][0]);
                xm[i][1] = fmaf(a, w.y, xm[i][1]);
                xm[i][2] = fmaf(a, w.z, xm[i][2]);
                xm[i][3] = fmaf(a, w.w, xm[i][3]);
            }
        }
        #pragma unroll
        for (int i = 0; i < 4; ++i) {
            size_t t = T0 + tg * 4 + i;
            float4 wv = *(const float4*)&wsrc[t * 64 + o4];
            xm[i][0] += wv.x; xm[i][1] += wv.y; xm[i][2] += wv.z; xm[i][3] += wv.w;
        }
        #pragma unroll
        for (int i = 0; i < 4; ++i) {
            float sm = xm[i][0] + xm[i][1] + xm[i][2] + xm[i][3];
            float sq = xm[i][0] * xm[i][0] + xm[i][1] * xm[i][1]
                     + xm[i][2] * xm[i][2] + xm[i][3] * xm[i][3];
            #pragma unroll
            for (int off = 1; off < 16; off <<= 1) {
                sm += __shfl_xor(sm, off);
                sq += __shfl_xor(sq, off);
            }
            float m = sm * (1.f / 64.f);
            float vr = sq * (1.f / 64.f) - m * m;
            float rs = rsqrtf(vr + EPSF);
            float4 u;
            u.x = (xm[i][0] - m) * rs * gv.x + bv.x;
            u.y = (xm[i][1] - m) * rs * gv.y + bv.y;
            u.z = (xm[i][2] - m) * rs * gv.z + bv.z;
            u.w = (xm[i][3] - m) * rs * gv.w + bv.w;
            *(float4*)&s_b[(tg * 4 + i) * 64 + o4] = u;
        }
        __syncthreads();
        float h[4][4];
        #pragma unroll
        for (int i = 0; i < 4; ++i) {
            h[i][0] = b1v.x; h[i][1] = b1v.y; h[i][2] = b1v.z; h[i][3] = b1v.w;
        }
        for (int c = 0; c < 64; ++c) {
            float4 w = *(const float4*)&s_W1[c * 64 + o4];
            #pragma unroll
            for (int i = 0; i < 4; ++i) {
                float a = s_b[(tg * 4 + i) * 64 + c];
                h[i][0] = fmaf(a, w.x, h[i][0]);
                h[i][1] = fmaf(a, w.y, h[i][1]);
                h[i][2] = fmaf(a, w.z, h[i][2]);
                h[i][3] = fmaf(a, w.w, h[i][3]);
            }
        }
        #pragma unroll
        for (int i = 0; i < 4; ++i) {
            float4 u;
            u.x = fmaxf(h[i][0], 0.f); u.y = fmaxf(h[i][1], 0.f);
            u.z = fmaxf(h[i][2], 0.f); u.w = fmaxf(h[i][3], 0.f);
            *(float4*)&s_a[(tg * 4 + i) * 64 + o4] = u;
        }
        __syncthreads();
        float xf[4][4];
        #pragma unroll
        for (int i = 0; i < 4; ++i) {
            xf[i][0] = xm[i][0] + b2v.x; xf[i][1] = xm[i][1] + b2v.y;
            xf[i][2] = xm[i][2] + b2v.z; xf[i][3] = xm[i][3] + b2v.w;
        }
        for (int c = 0; c < 64; ++c) {
            float4 w = *(const float4*)&s_W2[c * 64 + o4];
            #pragma unroll
            for (int i = 0; i < 4; ++i) {
                float a = s_a[(tg * 4 + i) * 64 + c];
                xf[i][0] = fmaf(a, w.x, xf[i][0]);
                xf[i][1] = fmaf(a, w.y, xf[i][1]);
                xf[i][2] = fmaf(a, w.z, xf[i][2]);
                xf[i][3] = fmaf(a, w.w, xf[i][3]);
            }
        }
        #pragma unroll
        for (int i = 0; i < 4; ++i) {
            zacc[i][0] += xf[i][0]; zacc[i][1] += xf[i][1];
            zacc[i][2] += xf[i][2]; zacc[i][3] += xf[i][3];
        }
    }
    #pragma unroll
    for (int i = 0; i < 4; ++i) {
        size_t t = T0 + tg * 4 + i;
        float4 o; o.x = zacc[i][0]; o.y = zacc[i][1]; o.z = zacc[i][2]; o.w = zacc[i][3];
        *(float4*)&z[t * 64 + o4] = o;
    }
}

// ---------------- K7: dec GEMM (64 -> 128) + 2*decb ----------------
__global__ __launch_bounds__(256) void k_dec(
    const float* __restrict__ z, const float* __restrict__ decW,
    const float* __restrict__ decb, float* __restrict__ out)
{
    __shared__ float s_z[4096];
    __shared__ float s_dec[8192];
    int tid = threadIdx.x;
    int T0 = blockIdx.x * 64;
    for (int i = tid; i < 1024; i += 256)
        ((float4*)s_z)[i] = ((const float4*)(z + (size_t)T0 * 64))[i];
    for (int i = tid; i < 2048; i += 256)
        ((float4*)s_dec)[i] = ((const float4*)decW)[i];
    __syncthreads();
    int q = tid & 31, m4 = q * 4;
    int tg = tid >> 5;
    float4 dbv = *(const float4*)&decb[m4];
    float acc[8][4];
    #pragma unroll
    for (int i = 0; i < 8; ++i) {
        acc[i][0] = 2.f * dbv.x; acc[i][1] = 2.f * dbv.y;
        acc[i][2] = 2.f * dbv.z; acc[i][3] = 2.f * dbv.w;
    }
    for (int c = 0; c < 64; ++c) {
        float4 w = *(const float4*)&s_dec[c * 128 + m4];
        #pragma unroll
        for (int i = 0; i < 8; ++i) {
            float a = s_z[(tg * 8 + i) * 64 + c];
            acc[i][0] = fmaf(a, w.x, acc[i][0]);
            acc[i][1] = fmaf(a, w.y, acc[i][1]);
            acc[i][2] = fmaf(a, w.z, acc[i][2]);
            acc[i][3] = fmaf(a, w.w, acc[i][3]);
        }
    }
    #pragma unroll
    for (int i = 0; i < 8; ++i) {
        size_t t = T0 + tg * 8 + i;
        float4 o; o.x = acc[i][0]; o.y = acc[i][1]; o.z = acc[i][2]; o.w = acc[i][3];
        *(float4*)&out[t * 128 + m4] = o;
    }
}

extern "C" void kernel_launch(void* const* d_in, const int* in_sizes, int n_in,
                              void* d_out, int out_size, void* d_ws, size_t ws_size,
                              hipStream_t stream) {
    const float* x_C   = (const float*)d_in[0];
    const float* x_T   = (const float*)d_in[1];
    const float* dwW   = (const float*)d_in[2];
    const float* dwB   = (const float*)d_in[3];
    const float* pw    = (const float*)d_in[4];
    const float* pwb   = (const float*)d_in[5];
    const float* gam   = (const float*)d_in[6];
    const float* bet   = (const float*)d_in[7];
    const float* mean  = (const float*)d_in[8];
    const float* var   = (const float*)d_in[9];
    const float* encW  = (const float*)d_in[10];
    const float* encb  = (const float*)d_in[11];
    const float* pos   = (const float*)d_in[12];
    const float* lng   = (const float*)d_in[13];
    const float* lnb   = (const float*)d_in[14];
    const float* qkvW  = (const float*)d_in[15];
    const float* projW = (const float*)d_in[16];
    const float* projb = (const float*)d_in[17];
    const float* W1    = (const float*)d_in[18];
    const float* b1    = (const float*)d_in[19];
    const float* W2    = (const float*)d_in[20];
    const float* b2    = (const float*)d_in[21];
    const float* decW  = (const float*)d_in[22];
    const float* decb  = (const float*)d_in[23];
    float* out = (float*)d_out;

    float* ws = (float*)d_ws;
    // Region ws[0 .. 6,291,456 f): xbuf (K1-K3) -> qk_buf+vT (K4-K5) -> z (K6-K7)
    float* xbuf = ws;
    unsigned short* qkb = (unsigned short*)ws;                 // 8,388,608 bf16
    unsigned short* vTb = (unsigned short*)(ws + 4194304);     // 4,194,304 bf16
    float* z    = ws;
    float* wx   = ws + 6291456;
    float* wy   = ws + 8388608;
    float* ox   = ws + 10485760;
    float* oy   = ws + 12582912;

    k_dwconv<<<1024, 256, 0, stream>>>(x_C, dwW, dwB, xbuf);
    k_pw<<<512, 512, 0, stream>>>(xbuf, x_C, pw, pwb, gam, bet, mean, var);
    k_encln<<<dim3(512, 2), 512, 0, stream>>>(xbuf, x_T, encW, encb, pos, lng, lnb, wx, wy);
    k_qkv<<<dim3(512, 2), 256, 0, stream>>>(wx, wy, qkvW, qkb, vTb);
    k_attn<<<2048, 256, 0, stream>>>(qkb, vTb, ox, oy);
    k_fuse<<<512, 256, 0, stream>>>(ox, oy, wx, wy, projW, projb,
                                    W1, b1, W2, b2, lng, lnb, z);
    k_dec<<<512, 256, 0, stream>>>(z, decW, decb, out);
}

// Round 4
// 175.082 us; speedup vs baseline: 3.7350x; 1.0911x over previous
//
#include <hip/hip_runtime.h>
#include <hip/hip_bf16.h>
#include <math.h>

#define EPSF 1e-5f
// scale (1/sqrt(8)) * log2(e), folded into k at qkv time
#define KSCL 0.51010090329771713f

#if __has_builtin(__builtin_amdgcn_exp2f)
#define EXP2(x) __builtin_amdgcn_exp2f(x)
#else
#define EXP2(x) exp2f(x)
#endif

typedef __attribute__((ext_vector_type(8))) short short8;   // 8 bf16 = 4 VGPR
typedef __attribute__((ext_vector_type(16))) float f32x16;  // MFMA 32x32 acc

__device__ __forceinline__ float bf2f(unsigned short u) {
    union { unsigned int i; float f; } x; x.i = ((unsigned int)u) << 16; return x.f;
}
__device__ __forceinline__ unsigned int f2bf(float f) {
    union { float f; unsigned int i; } u; u.f = f;
    unsigned int r = u.i + 0x7FFFu + ((u.i >> 16) & 1u);
    return r >> 16;
}

// ---------------- K1: depthwise 3x3 conv + bias (4 ch x 4 px per thread) ----------------
__global__ __launch_bounds__(256) void k_dwconv(
    const float* __restrict__ xC, const float* __restrict__ dwW,
    const float* __restrict__ dwB, float* __restrict__ xdw)
{
    __shared__ float s_w[128 * 9];
    __shared__ float s_bias[128];
    int tid = threadIdx.x;
    for (int i = tid; i < 128 * 9; i += 256) s_w[i] = dwW[i];
    if (tid < 128) s_bias[tid] = dwB[tid];
    __syncthreads();
    int idx = blockIdx.x * 256 + tid;
    int c4 = (idx & 31) * 4;
    int pg = idx >> 5;
    int t0 = pg * 4;
    int b = t0 >> 14, n = t0 & 16383;
    int row = n >> 7, col0 = n & 127;
    float vb[3][6][4];
    #pragma unroll
    for (int ky = 0; ky < 3; ++ky) {
        int r = row + ky - 1;
        #pragma unroll
        for (int cx = 0; cx < 6; ++cx) {
            int cl = col0 + cx - 1;
            if ((unsigned)r < 128u && (unsigned)cl < 128u) {
                *(float4*)&vb[ky][cx][0] =
                    *(const float4*)&xC[((size_t)(b << 14) + (r << 7) + cl) * 128 + c4];
            } else {
                vb[ky][cx][0] = 0.f; vb[ky][cx][1] = 0.f; vb[ky][cx][2] = 0.f; vb[ky][cx][3] = 0.f;
            }
        }
    }
    float acc[4][4];
    #pragma unroll
    for (int p = 0; p < 4; ++p)
        #pragma unroll
        for (int j = 0; j < 4; ++j) acc[p][j] = s_bias[c4 + j];
    #pragma unroll
    for (int ky = 0; ky < 3; ++ky)
        #pragma unroll
        for (int kx = 0; kx < 3; ++kx)
            #pragma unroll
            for (int j = 0; j < 4; ++j) {
                float w = s_w[(c4 + j) * 9 + ky * 3 + kx];
                #pragma unroll
                for (int p = 0; p < 4; ++p)
                    acc[p][j] = fmaf(w, vb[ky][p + kx][j], acc[p][j]);
            }
    #pragma unroll
    for (int p = 0; p < 4; ++p) {
        float4 o; o.x = acc[p][0]; o.y = acc[p][1]; o.z = acc[p][2]; o.w = acc[p][3];
        *(float4*)&xdw[((size_t)t0 + p) * 128 + c4] = o;
    }
}

// ---------------- K2: pointwise conv + BN + ReLU + residual (in-place on xbuf) ----------------
__global__ __launch_bounds__(512) void k_pw(
    float* xbuf,
    const float* __restrict__ xC, const float* __restrict__ pw,
    const float* __restrict__ pwb, const float* __restrict__ gam,
    const float* __restrict__ bet, const float* __restrict__ mean,
    const float* __restrict__ var)
{
    __shared__ float s_in[64 * 128];
    __shared__ float s_wT[128 * 130];
    __shared__ float s_scale[128];
    __shared__ float s_beff[128];
    int tid = threadIdx.x;
    int T0 = blockIdx.x * 64;
    if (tid < 128) {
        float sc = gam[tid] * rsqrtf(var[tid] + EPSF);
        s_scale[tid] = sc;
        s_beff[tid] = (pwb[tid] - mean[tid]) * sc + bet[tid];
    }
    for (int i = tid; i < 2048; i += 512)
        ((float4*)s_in)[i] = ((const float4*)(xbuf + (size_t)T0 * 128))[i];
    __syncthreads();
    for (int i = tid; i < 4096; i += 512) {
        float4 w = ((const float4*)pw)[i];
        int co = i >> 5;
        int ci0 = (i & 31) * 4;
        float sc = s_scale[co];
        s_wT[(ci0 + 0) * 130 + co] = w.x * sc;
        s_wT[(ci0 + 1) * 130 + co] = w.y * sc;
        s_wT[(ci0 + 2) * 130 + co] = w.z * sc;
        s_wT[(ci0 + 3) * 130 + co] = w.w * sc;
    }
    __syncthreads();
    int q = tid & 31, co4 = q * 4;
    int tg = tid >> 5;
    float acc[4][4];
    #pragma unroll
    for (int i = 0; i < 4; ++i)
        #pragma unroll
        for (int j = 0; j < 4; ++j) acc[i][j] = s_beff[co4 + j];
    for (int ci = 0; ci < 128; ++ci) {
        float4 w = *(const float4*)&s_wT[ci * 130 + co4];
        #pragma unroll
        for (int i = 0; i < 4; ++i) {
            float xin = s_in[(tg * 4 + i) * 128 + ci];
            acc[i][0] = fmaf(xin, w.x, acc[i][0]);
            acc[i][1] = fmaf(xin, w.y, acc[i][1]);
            acc[i][2] = fmaf(xin, w.z, acc[i][2]);
            acc[i][3] = fmaf(xin, w.w, acc[i][3]);
        }
    }
    #pragma unroll
    for (int i = 0; i < 4; ++i) {
        size_t t = T0 + tg * 4 + i;
        float4 r = *(const float4*)&xC[t * 128 + co4];
        float4 o;
        o.x = fmaxf(acc[i][0], 0.f) + r.x;
        o.y = fmaxf(acc[i][1], 0.f) + r.y;
        o.z = fmaxf(acc[i][2], 0.f) + r.z;
        o.w = fmaxf(acc[i][3], 0.f) + r.w;
        *(float4*)&xbuf[t * 128 + co4] = o;
    }
}

// ---------------- K3: enc + pos + LayerNorm -> wx / wy ----------------
__global__ __launch_bounds__(512) void k_encln(
    const float* __restrict__ x1, const float* __restrict__ xT,
    const float* __restrict__ encW, const float* __restrict__ encb,
    const float* __restrict__ pos, const float* __restrict__ lng,
    const float* __restrict__ lnb, float* __restrict__ wx, float* __restrict__ wy)
{
    __shared__ float s_in[64 * 128];
    __shared__ float s_w[128 * 64];
    int tid = threadIdx.x;
    int T0 = blockIdx.x * 64;
    int stream = blockIdx.y;
    for (int i = tid; i < 2048; i += 512) ((float4*)s_w)[i] = ((const float4*)encW)[i];
    if (stream == 0) {
        for (int i = tid; i < 2048; i += 512)
            ((float4*)s_in)[i] = ((const float4*)(x1 + (size_t)T0 * 128))[i];
    } else {
        for (int i = tid; i < 2048; i += 512) {
            float4 v = ((const float4*)(xT + (size_t)T0 * 128))[i];
            float4 o;
            o.x = v.x > 0.f ? 2.f * v.x : v.x;
            o.y = v.y > 0.f ? 2.f * v.y : v.y;
            o.z = v.z > 0.f ? 2.f * v.z : v.z;
            o.w = v.w > 0.f ? 2.f * v.w : v.w;
            ((float4*)s_in)[i] = o;
        }
    }
    __syncthreads();
    int q = tid & 15, o4 = q * 4;
    int tg = tid >> 4;
    float acc[2][4] = {};
    for (int ci = 0; ci < 128; ++ci) {
        float4 w = *(const float4*)&s_w[ci * 64 + o4];
        #pragma unroll
        for (int i = 0; i < 2; ++i) {
            float xin = s_in[(tg * 2 + i) * 128 + ci];
            acc[i][0] = fmaf(xin, w.x, acc[i][0]);
            acc[i][1] = fmaf(xin, w.y, acc[i][1]);
            acc[i][2] = fmaf(xin, w.z, acc[i][2]);
            acc[i][3] = fmaf(xin, w.w, acc[i][3]);
        }
    }
    float4 eb = *(const float4*)&encb[o4];
    float4 g  = *(const float4*)&lng[o4];
    float4 bb = *(const float4*)&lnb[o4];
    float* dst = stream == 0 ? wx : wy;
    #pragma unroll
    for (int i = 0; i < 2; ++i) {
        int t = T0 + tg * 2 + i;
        int n = t & 16383;
        float4 pv = *(const float4*)&pos[(size_t)n * 64 + o4];
        float v0 = acc[i][0] + eb.x + pv.x;
        float v1 = acc[i][1] + eb.y + pv.y;
        float v2 = acc[i][2] + eb.z + pv.z;
        float v3 = acc[i][3] + eb.w + pv.w;
        float sm = v0 + v1 + v2 + v3;
        float sq = v0 * v0 + v1 * v1 + v2 * v2 + v3 * v3;
        #pragma unroll
        for (int off = 1; off < 16; off <<= 1) {
            sm += __shfl_xor(sm, off);
            sq += __shfl_xor(sq, off);
        }
        float m = sm * (1.f / 64.f);
        float vr = sq * (1.f / 64.f) - m * m;
        float rs = rsqrtf(vr + EPSF);
        float4 o;
        o.x = (v0 - m) * rs * g.x + bb.x;
        o.y = (v1 - m) * rs * g.y + bb.y;
        o.z = (v2 - m) * rs * g.z + bb.z;
        o.w = (v3 - m) * rs * g.w + bb.w;
        *(float4*)&dst[(size_t)t * 64 + o4] = o;
    }
}

// ---------------- K4: qkv GEMM (64 -> 192), bf16 outputs for MFMA attention ----------
// qk: per combo=((s*2+b)*8+head)*64+wid, token p: 16 bf16 {q[0..7], k[0..7]*KSCL}
// vT: per combo: [d=0..7][p=0..255] bf16 (transposed v)
__global__ __launch_bounds__(256) void k_qkv(
    const float* __restrict__ wx, const float* __restrict__ wy,
    const float* __restrict__ qkvW, unsigned short* __restrict__ qk,
    unsigned short* __restrict__ vT)
{
    __shared__ float s_in[64 * 64];
    __shared__ float s_qW[64 * 192];
    int tid = threadIdx.x;
    int T0 = blockIdx.x * 64;
    int s = blockIdx.y;
    const float* src = s == 0 ? wx : wy;
    for (int i = tid; i < 1024; i += 256)
        ((float4*)s_in)[i] = ((const float4*)(src + (size_t)T0 * 64))[i];
    for (int i = tid; i < 3072; i += 256)
        ((float4*)s_qW)[i] = ((const float4*)qkvW)[i];
    __syncthreads();
    int q = tid & 15, o4 = q * 4;
    int tg = tid >> 4;
    float acc[3][4][4] = {};
    for (int c = 0; c < 64; ++c) {
        float4 w0 = *(const float4*)&s_qW[c * 192 + o4];
        float4 w1 = *(const float4*)&s_qW[c * 192 + 64 + o4];
        float4 w2 = *(const float4*)&s_qW[c * 192 + 128 + o4];
        #pragma unroll
        for (int i = 0; i < 4; ++i) {
            float xin = s_in[(tg * 4 + i) * 64 + c];
            acc[0][i][0] = fmaf(xin, w0.x, acc[0][i][0]);
            acc[0][i][1] = fmaf(xin, w0.y, acc[0][i][1]);
            acc[0][i][2] = fmaf(xin, w0.z, acc[0][i][2]);
            acc[0][i][3] = fmaf(xin, w0.w, acc[0][i][3]);
            acc[1][i][0] = fmaf(xin, w1.x, acc[1][i][0]);
            acc[1][i][1] = fmaf(xin, w1.y, acc[1][i][1]);
            acc[1][i][2] = fmaf(xin, w1.z, acc[1][i][2]);
            acc[1][i][3] = fmaf(xin, w1.w, acc[1][i][3]);
            acc[2][i][0] = fmaf(xin, w2.x, acc[2][i][0]);
            acc[2][i][1] = fmaf(xin, w2.y, acc[2][i][1]);
            acc[2][i][2] = fmaf(xin, w2.z, acc[2][i][2]);
            acc[2][i][3] = fmaf(xin, w2.w, acc[2][i][3]);
        }
    }
    int head = o4 >> 3, dpos = o4 & 7;
    int t0 = T0 + tg * 4;
    int b = t0 >> 14, n = t0 & 16383;
    int row = n >> 7, cp = n & 127;
    int wid = (row >> 4) * 8 + (cp >> 4);
    int p0 = (row & 15) * 16 + (cp & 15);
    size_t combo = (size_t)(s * 2 + b) * 512 + head * 64 + wid;
    unsigned short* qrec = qk + combo * 4096;
    #pragma unroll
    for (int i = 0; i < 4; ++i) {
        int p = p0 + i;
        uint2 qv;
        qv.x = f2bf(acc[0][i][0]) | (f2bf(acc[0][i][1]) << 16);
        qv.y = f2bf(acc[0][i][2]) | (f2bf(acc[0][i][3]) << 16);
        *(uint2*)(qrec + p * 16 + dpos) = qv;
        uint2 kv;
        kv.x = f2bf(acc[1][i][0] * KSCL) | (f2bf(acc[1][i][1] * KSCL) << 16);
        kv.y = f2bf(acc[1][i][2] * KSCL) | (f2bf(acc[1][i][3] * KSCL) << 16);
        *(uint2*)(qrec + p * 16 + 8 + dpos) = kv;
    }
    unsigned short* vrec = vT + combo * 2048;
    #pragma unroll
    for (int jj = 0; jj < 4; ++jj) {
        uint2 vv;
        vv.x = f2bf(acc[2][0][jj]) | (f2bf(acc[2][1][jj]) << 16);
        vv.y = f2bf(acc[2][2][jj]) | (f2bf(acc[2][3][jj]) << 16);
        *(uint2*)(vrec + (dpos + jj) * 256 + p0) = vv;
    }
}

// ---------------- K5: MFMA dual-stream windowed attention (cross values) -------------
// block = (s, b, head, wid); 4 waves x 64 queries. No LDS, no cross-lane ops.
// C[j][q] = mfma(K, Q^T); P = exp2(C); D = mfma(V^T_perm, P_natural) accumulated,
// where P stays in its natural C-layout k-order sigma(k)=(r&3)+8*(r>>2)+4*lh and
// the V^T A-operand is loaded sigma-permuted. V rows >= 8 are 1.0 so D reg 4
// (rows 8/12) is the softmax denominator in both lane halves.
__global__ __launch_bounds__(256) void k_attn(
    const unsigned short* __restrict__ qk, const unsigned short* __restrict__ vT,
    float* __restrict__ ox, float* __restrict__ oy)
{
    int tid = threadIdx.x;
    int wave = tid >> 6, lane = tid & 63;
    int lh = lane >> 5, l31 = lane & 31;
    int bx = blockIdx.x;
    int s = bx >> 10;
    int r = bx & 1023;                 // (b*8+head)*64 + wid
    int head = (r >> 6) & 7, wid = r & 63, b = r >> 9;
    const unsigned short* qbase = qk + ((size_t)s * 1024 + r) * 4096;
    const unsigned short* vbase = vT + ((size_t)(s ^ 1) * 1024 + r) * 2048;  // cross v

    short8 qf[2];
    #pragma unroll
    for (int qt = 0; qt < 2; ++qt) {
        uint4 v = {0u, 0u, 0u, 0u};
        if (lh == 0) v = *(const uint4*)(qbase + (size_t)(wave * 64 + qt * 32 + l31) * 16);
        qf[qt] = __builtin_bit_cast(short8, v);
    }
    f32x16 acc[2];
    #pragma unroll
    for (int qt = 0; qt < 2; ++qt) acc[qt] = (f32x16){};
    const unsigned ONES = 0x3F803F80u;

    for (int jt = 0; jt < 8; ++jt) {
        uint4 kv = {0u, 0u, 0u, 0u};
        if (lh == 0) kv = *(const uint4*)(qbase + (size_t)(jt * 32 + l31) * 16 + 8);
        short8 kf = __builtin_bit_cast(short8, kv);
        // sigma-permuted V^T A-operands (4 x 8B loads)
        uint2 a0 = {ONES, ONES}, a1 = {ONES, ONES}, a2 = {ONES, ONES}, a3 = {ONES, ONES};
        if (l31 < 8) {
            const unsigned short* vp = vbase + l31 * 256 + jt * 32 + lh * 4;
            a0 = *(const uint2*)vp;          // k-slots r0..3  -> j: +0..3
            a1 = *(const uint2*)(vp + 8);    // r4..7 -> j: +8..11
            a2 = *(const uint2*)(vp + 16);   // second mfma r0..3 -> j: +16..19
            a3 = *(const uint2*)(vp + 24);   // r4..7 -> j: +24..27
        }
        uint4 vaw = {a0.x, a0.y, a1.x, a1.y};
        uint4 vbw = {a2.x, a2.y, a3.x, a3.y};
        short8 vf0 = __builtin_bit_cast(short8, vaw);
        short8 vf1 = __builtin_bit_cast(short8, vbw);
        #pragma unroll
        for (int qt = 0; qt < 2; ++qt) {
            f32x16 c = __builtin_amdgcn_mfma_f32_32x32x16_bf16(kf, qf[qt], (f32x16){}, 0, 0, 0);
            float p[16];
            #pragma unroll
            for (int i = 0; i < 16; ++i) p[i] = EXP2(c[i]);
            unsigned pk[8];
            #pragma unroll
            for (int i = 0; i < 8; ++i) {
                unsigned pkv;
                asm("v_cvt_pk_bf16_f32 %0, %1, %2" : "=v"(pkv) : "v"(p[2 * i]), "v"(p[2 * i + 1]));
                pk[i] = pkv;
            }
            uint4 bw0 = {pk[0], pk[1], pk[2], pk[3]};
            uint4 bw1 = {pk[4], pk[5], pk[6], pk[7]};
            short8 B0 = __builtin_bit_cast(short8, bw0);
            short8 B1 = __builtin_bit_cast(short8, bw1);
            acc[qt] = __builtin_amdgcn_mfma_f32_32x32x16_bf16(vf0, B0, acc[qt], 0, 0, 0);
            acc[qt] = __builtin_amdgcn_mfma_f32_32x32x16_bf16(vf1, B1, acc[qt], 0, 0, 0);
        }
    }
    float* dst = s ? oy : ox;
    #pragma unroll
    for (int qt = 0; qt < 2; ++qt) {
        float inv = 1.f / acc[qt][4];          // D rows 8/12 = denominator
        int p = wave * 64 + qt * 32 + l31;
        int orow = (wid >> 3) * 16 + (p >> 4);
        int ocol = (wid & 7) * 16 + (p & 15);
        size_t t = (size_t)b * 16384 + orow * 128 + ocol;
        float4 o;
        o.x = acc[qt][0] * inv; o.y = acc[qt][1] * inv;
        o.z = acc[qt][2] * inv; o.w = acc[qt][3] * inv;
        *(float4*)&dst[t * 64 + head * 8 + lh * 4] = o;
    }
}

// ---------------- K6: proj + residual + FFN (both streams) -> z = xf_x + xf_y -------
__global__ __launch_bounds__(256) void k_fuse(
    const float* __restrict__ ox, const float* __restrict__ oy,
    const float* __restrict__ wx, const float* __restrict__ wy,
    const float* __restrict__ projW, const float* __restrict__ projb,
    const float* __restrict__ W1, const float* __restrict__ b1,
    const float* __restrict__ W2, const float* __restrict__ b2,
    const float* __restrict__ lng, const float* __restrict__ lnb,
    float* __restrict__ z)
{
    __shared__ float s_proj[4096];
    __shared__ float s_W1[4096];
    __shared__ float s_W2[4096];
    __shared__ float s_a[4096];
    __shared__ float s_b[4096];
    int tid = threadIdx.x;
    int T0 = blockIdx.x * 64;
    for (int i = tid; i < 1024; i += 256) {
        ((float4*)s_proj)[i] = ((const float4*)projW)[i];
        ((float4*)s_W1)[i]   = ((const float4*)W1)[i];
        ((float4*)s_W2)[i]   = ((const float4*)W2)[i];
    }
    int q = tid & 15, o4 = q * 4;
    int tg = tid >> 4;
    float4 pbv = *(const float4*)&projb[o4];
    float4 b1v = *(const float4*)&b1[o4];
    float4 b2v = *(const float4*)&b2[o4];
    float4 gv  = *(const float4*)&lng[o4];
    float4 bv  = *(const float4*)&lnb[o4];
    float zacc[4][4] = {};
    for (int s = 0; s < 2; ++s) {
        const float* osrc = s == 0 ? ox : oy;
        const float* wsrc = s == 0 ? wx : wy;
        __syncthreads();
        for (int i = tid; i < 1024; i += 256)
            ((float4*)s_a)[i] = ((const float4*)(osrc + (size_t)T0 * 64))[i];
        __syncthreads();
        float xm[4][4];
        #pragma unroll
        for (int i = 0; i < 4; ++i) {
            xm[i][0] = pbv.x; xm[i][1] = pbv.y; xm[i][2] = pbv.z; xm[i][3] = pbv.w;
        }
        for (int c = 0; c < 64; ++c) {
            float4 w = *(const float4*)&s_proj[c * 64 + o4];
            #pragma unroll
            for (int i = 0; i < 4; ++i) {
                float a = s_a[(tg * 4 + i) * 64 + c];
                xm[i][0] = fmaf(a, w.x, xm[i][0]);
                xm[i][1] = fmaf(a, w.y, xm[i][1]);
                xm[i][2] = fmaf(a, w.z, xm[i][2]);
                xm[i][3] = fmaf(a, w.w, xm[i][3]);
            }
        }
        #pragma unroll
        for (int i = 0; i < 4; ++i) {
            size_t t = T0 + tg * 4 + i;
            float4 wv = *(const float4*)&wsrc[t * 64 + o4];
            xm[i][0] += wv.x; xm[i][1] += wv.y; xm[i][2] += wv.z; xm[i][3] += wv.w;
        }
        #pragma unroll
        for (int i = 0; i < 4; ++i) {
            float sm = xm[i][0] + xm[i][1] + xm[i][2] + xm[i][3];
            float sq = xm[i][0] * xm[i][0] + xm[i][1] * xm[i][1]
                     + xm[i][2] * xm[i][2] + xm[i][3] * xm[i][3];
            #pragma unroll
            for (int off = 1; off < 16; off <<= 1) {
                sm += __shfl_xor(sm, off);
                sq += __shfl_xor(sq, off);
            }
            float m = sm * (1.f / 64.f);
            float vr = sq * (1.f / 64.f) - m * m;
            float rs = rsqrtf(vr + EPSF);
            float4 u;
            u.x = (xm[i][0] - m) * rs * gv.x + bv.x;
            u.y = (xm[i][1] - m) * rs * gv.y + bv.y;
            u.z = (xm[i][2] - m) * rs * gv.z + bv.z;
            u.w = (xm[i][3] - m) * rs * gv.w + bv.w;
            *(float4*)&s_b[(tg * 4 + i) * 64 + o4] = u;
        }
        __syncthreads();
        float h[4][4];
        #pragma unroll
        for (int i = 0; i < 4; ++i) {
            h[i][0] = b1v.x; h[i][1] = b1v.y; h[i][2] = b1v.z; h[i][3] = b1v.w;
        }
        for (int c = 0; c < 64; ++c) {
            float4 w = *(const float4*)&s_W1[c * 64 + o4];
            #pragma unroll
            for (int i = 0; i < 4; ++i) {
                float a = s_b[(tg * 4 + i) * 64 + c];
                h[i][0] = fmaf(a, w.x, h[i][0]);
                h[i][1] = fmaf(a, w.y, h[i][1]);
                h[i][2] = fmaf(a, w.z, h[i][2]);
                h[i][3] = fmaf(a, w.w, h[i][3]);
            }
        }
        #pragma unroll
        for (int i = 0; i < 4; ++i) {
            float4 u;
            u.x = fmaxf(h[i][0], 0.f); u.y = fmaxf(h[i][1], 0.f);
            u.z = fmaxf(h[i][2], 0.f); u.w = fmaxf(h[i][3], 0.f);
            *(float4*)&s_a[(tg * 4 + i) * 64 + o4] = u;
        }
        __syncthreads();
        float xf[4][4];
        #pragma unroll
        for (int i = 0; i < 4; ++i) {
            xf[i][0] = xm[i][0] + b2v.x; xf[i][1] = xm[i][1] + b2v.y;
            xf[i][2] = xm[i][2] + b2v.z; xf[i][3] = xm[i][3] + b2v.w;
        }
        for (int c = 0; c < 64; ++c) {
            float4 w = *(const float4*)&s_W2[c * 64 + o4];
            #pragma unroll
            for (int i = 0; i < 4; ++i) {
                float a = s_a[(tg * 4 + i) * 64 + c];
                xf[i][0] = fmaf(a, w.x, xf[i][0]);
                xf[i][1] = fmaf(a, w.y, xf[i][1]);
                xf[i][2] = fmaf(a, w.z, xf[i][2]);
                xf[i][3] = fmaf(a, w.w, xf[i][3]);
            }
        }
        #pragma unroll
        for (int i = 0; i < 4; ++i) {
            zacc[i][0] += xf[i][0]; zacc[i][1] += xf[i][1];
            zacc[i][2] += xf[i][2]; zacc[i][3] += xf[i][3];
        }
    }
    #pragma unroll
    for (int i = 0; i < 4; ++i) {
        size_t t = T0 + tg * 4 + i;
        float4 o; o.x = zacc[i][0]; o.y = zacc[i][1]; o.z = zacc[i][2]; o.w = zacc[i][3];
        *(float4*)&z[t * 64 + o4] = o;
    }
}

// ---------------- K7: dec GEMM (64 -> 128) + 2*decb ----------------
__global__ __launch_bounds__(256) void k_dec(
    const float* __restrict__ z, const float* __restrict__ decW,
    const float* __restrict__ decb, float* __restrict__ out)
{
    __shared__ float s_z[4096];
    __shared__ float s_dec[8192];
    int tid = threadIdx.x;
    int T0 = blockIdx.x * 64;
    for (int i = tid; i < 1024; i += 256)
        ((float4*)s_z)[i] = ((const float4*)(z + (size_t)T0 * 64))[i];
    for (int i = tid; i < 2048; i += 256)
        ((float4*)s_dec)[i] = ((const float4*)decW)[i];
    __syncthreads();
    int q = tid & 31, m4 = q * 4;
    int tg = tid >> 5;
    float4 dbv = *(const float4*)&decb[m4];
    float acc[8][4];
    #pragma unroll
    for (int i = 0; i < 8; ++i) {
        acc[i][0] = 2.f * dbv.x; acc[i][1] = 2.f * dbv.y;
        acc[i][2] = 2.f * dbv.z; acc[i][3] = 2.f * dbv.w;
    }
    for (int c = 0; c < 64; ++c) {
        float4 w = *(const float4*)&s_dec[c * 128 + m4];
        #pragma unroll
        for (int i = 0; i < 8; ++i) {
            float a = s_z[(tg * 8 + i) * 64 + c];
            acc[i][0] = fmaf(a, w.x, acc[i][0]);
            acc[i][1] = fmaf(a, w.y, acc[i][1]);
            acc[i][2] = fmaf(a, w.z, acc[i][2]);
            acc[i][3] = fmaf(a, w.w, acc[i][3]);
        }
    }
    #pragma unroll
    for (int i = 0; i < 8; ++i) {
        size_t t = T0 + tg * 8 + i;
        float4 o; o.x = acc[i][0]; o.y = acc[i][1]; o.z = acc[i][2]; o.w = acc[i][3];
        *(float4*)&out[t * 128 + m4] = o;
    }
}

extern "C" void kernel_launch(void* const* d_in, const int* in_sizes, int n_in,
                              void* d_out, int out_size, void* d_ws, size_t ws_size,
                              hipStream_t stream) {
    const float* x_C   = (const float*)d_in[0];
    const float* x_T   = (const float*)d_in[1];
    const float* dwW   = (const float*)d_in[2];
    const float* dwB   = (const float*)d_in[3];
    const float* pw    = (const float*)d_in[4];
    const float* pwb   = (const float*)d_in[5];
    const float* gam   = (const float*)d_in[6];
    const float* bet   = (const float*)d_in[7];
    const float* mean  = (const float*)d_in[8];
    const float* var   = (const float*)d_in[9];
    const float* encW  = (const float*)d_in[10];
    const float* encb  = (const float*)d_in[11];
    const float* pos   = (const float*)d_in[12];
    const float* lng   = (const float*)d_in[13];
    const float* lnb   = (const float*)d_in[14];
    const float* qkvW  = (const float*)d_in[15];
    const float* projW = (const float*)d_in[16];
    const float* projb = (const float*)d_in[17];
    const float* W1    = (const float*)d_in[18];
    const float* b1    = (const float*)d_in[19];
    const float* W2    = (const float*)d_in[20];
    const float* b2    = (const float*)d_in[21];
    const float* decW  = (const float*)d_in[22];
    const float* decb  = (const float*)d_in[23];
    float* out = (float*)d_out;

    float* ws = (float*)d_ws;
    // Region ws[0 .. 6,291,456 f): xbuf (K1-K3) -> qk_buf+vT (K4-K5) -> z (K6-K7)
    float* xbuf = ws;
    unsigned short* qkb = (unsigned short*)ws;                 // 8,388,608 bf16
    unsigned short* vTb = (unsigned short*)(ws + 4194304);     // 4,194,304 bf16
    float* z    = ws;
    float* wx   = ws + 6291456;
    float* wy   = ws + 8388608;
    float* ox   = ws + 10485760;
    float* oy   = ws + 12582912;

    k_dwconv<<<1024, 256, 0, stream>>>(x_C, dwW, dwB, xbuf);
    k_pw<<<512, 512, 0, stream>>>(xbuf, x_C, pw, pwb, gam, bet, mean, var);
    k_encln<<<dim3(512, 2), 512, 0, stream>>>(xbuf, x_T, encW, encb, pos, lng, lnb, wx, wy);
    k_qkv<<<dim3(512, 2), 256, 0, stream>>>(wx, wy, qkvW, qkb, vTb);
    k_attn<<<2048, 256, 0, stream>>>(qkb, vTb, ox, oy);
    k_fuse<<<512, 256, 0, stream>>>(ox, oy, wx, wy, projW, projb,
                                    W1, b1, W2, b2, lng, lnb, z);
    k_dec<<<512, 256, 0, stream>>>(z, decW, decb, out);
}

// Round 5
// 140.396 us; speedup vs baseline: 4.6578x; 1.2471x over previous
//
#include <hip/hip_runtime.h>
#include <hip/hip_bf16.h>
#include <math.h>

#define EPSF 1e-5f
// scale (1/sqrt(8)) * log2(e), folded into k at qkv time
#define KSCL 0.51010090329771713f

#if __has_builtin(__builtin_amdgcn_exp2f)
#define EXP2(x) __builtin_amdgcn_exp2f(x)
#else
#define EXP2(x) exp2f(x)
#endif

typedef __attribute__((ext_vector_type(8))) short short8;   // 8 bf16 = 4 VGPR
typedef __attribute__((ext_vector_type(16))) float f32x16;  // MFMA 32x32 acc

__device__ __forceinline__ float bf2f(unsigned short u) {
    union { unsigned int i; float f; } x; x.i = ((unsigned int)u) << 16; return x.f;
}
__device__ __forceinline__ unsigned int f2bf(float f) {
    union { float f; unsigned int i; } u; u.f = f;
    unsigned int r = u.i + 0x7FFFu + ((u.i >> 16) & 1u);
    return r >> 16;
}

// ---------------- K1: depthwise 3x3 conv + bias -> bf16; extra blocks do weight prep ----
__global__ __launch_bounds__(256) void k_dwconv(
    const float* __restrict__ xC, const float* __restrict__ dwW,
    const float* __restrict__ dwB, unsigned short* __restrict__ xdwb,
    const float* __restrict__ qkvW, const float* __restrict__ pw,
    const float* __restrict__ pwb, const float* __restrict__ gam,
    const float* __restrict__ bet, const float* __restrict__ mean,
    const float* __restrict__ var, unsigned short* __restrict__ qkvWT,
    unsigned short* __restrict__ weff, float* __restrict__ beff)
{
    __shared__ float s_w[128 * 9];
    __shared__ float s_bias[128];
    int tid = threadIdx.x;
    if (blockIdx.x >= 1024) {           // prep blocks
        int pid = (blockIdx.x - 1024) * 256 + tid;   // 0..16383
        if (pid < 12288) {              // qkvWT[o*64+c] = bf16(qkvW[c*192+o])
            int o = pid >> 6, c = pid & 63;
            qkvWT[pid] = (unsigned short)f2bf(qkvW[c * 192 + o]);
        }
        {                               // weff[co*128+ci] = bf16(pw*scale)
            int co = pid >> 7;
            float sc = gam[co] * rsqrtf(var[co] + EPSF);
            weff[pid] = (unsigned short)f2bf(pw[pid] * sc);
        }
        if (pid < 128) {
            float sc = gam[pid] * rsqrtf(var[pid] + EPSF);
            beff[pid] = (pwb[pid] - mean[pid]) * sc + bet[pid];
        }
        return;
    }
    for (int i = tid; i < 128 * 9; i += 256) s_w[i] = dwW[i];
    if (tid < 128) s_bias[tid] = dwB[tid];
    __syncthreads();
    int idx = blockIdx.x * 256 + tid;
    int c4 = (idx & 31) * 4;
    int pg = idx >> 5;
    int t0 = pg * 4;
    int b = t0 >> 14, n = t0 & 16383;
    int row = n >> 7, col0 = n & 127;
    float vb[3][6][4];
    #pragma unroll
    for (int ky = 0; ky < 3; ++ky) {
        int r = row + ky - 1;
        #pragma unroll
        for (int cx = 0; cx < 6; ++cx) {
            int cl = col0 + cx - 1;
            if ((unsigned)r < 128u && (unsigned)cl < 128u) {
                *(float4*)&vb[ky][cx][0] =
                    *(const float4*)&xC[((size_t)(b << 14) + (r << 7) + cl) * 128 + c4];
            } else {
                vb[ky][cx][0] = 0.f; vb[ky][cx][1] = 0.f; vb[ky][cx][2] = 0.f; vb[ky][cx][3] = 0.f;
            }
        }
    }
    float acc[4][4];
    #pragma unroll
    for (int p = 0; p < 4; ++p)
        #pragma unroll
        for (int j = 0; j < 4; ++j) acc[p][j] = s_bias[c4 + j];
    #pragma unroll
    for (int ky = 0; ky < 3; ++ky)
        #pragma unroll
        for (int kx = 0; kx < 3; ++kx)
            #pragma unroll
            for (int j = 0; j < 4; ++j) {
                float w = s_w[(c4 + j) * 9 + ky * 3 + kx];
                #pragma unroll
                for (int p = 0; p < 4; ++p)
                    acc[p][j] = fmaf(w, vb[ky][p + kx][j], acc[p][j]);
            }
    #pragma unroll
    for (int p = 0; p < 4; ++p) {
        uint2 o;
        o.x = f2bf(acc[p][0]) | (f2bf(acc[p][1]) << 16);
        o.y = f2bf(acc[p][2]) | (f2bf(acc[p][3]) << 16);
        *(uint2*)&xdwb[((size_t)t0 + p) * 128 + c4] = o;
    }
}

// ---------------- K2: pointwise conv + BN + ReLU + residual via MFMA (no LDS) --------
// C[tok][co]: A = xdwb (lane=token), B = weff^T (lane=co). 64 tok x 128 co per block.
__global__ __launch_bounds__(256) void k_pw(
    const unsigned short* __restrict__ xdwb, const float* __restrict__ xC,
    const unsigned short* __restrict__ weff, const float* __restrict__ beff,
    float* __restrict__ x1)
{
    int tid = threadIdx.x;
    int wv = tid >> 6, lane = tid & 63, l31 = lane & 31, lh = lane >> 5;
    int wr = wv >> 1, wc = wv & 1;
    int T0 = blockIdx.x * 64;
    int ta = T0 + wr * 32 + l31;
    short8 af[8];
    #pragma unroll
    for (int ks = 0; ks < 8; ++ks)
        af[ks] = *(const short8*)&xdwb[(size_t)ta * 128 + ks * 16 + lh * 8];
    #pragma unroll
    for (int nt = 0; nt < 2; ++nt) {
        int co = wc * 64 + nt * 32 + l31;
        f32x16 acc = {};
        #pragma unroll
        for (int ks = 0; ks < 8; ++ks) {
            short8 bfr = *(const short8*)&weff[(size_t)co * 128 + ks * 16 + lh * 8];
            acc = __builtin_amdgcn_mfma_f32_32x32x16_bf16(af[ks], bfr, acc, 0, 0, 0);
        }
        float be = beff[co];
        #pragma unroll
        for (int r = 0; r < 16; ++r) {
            int tt = T0 + wr * 32 + (r & 3) + 8 * (r >> 2) + 4 * lh;
            float v = fmaxf(acc[r] + be, 0.f) + xC[(size_t)tt * 128 + co];
            x1[(size_t)tt * 128 + co] = v;
        }
    }
}

// ---------------- K3: enc + pos + LayerNorm -> wx/wy (f32) + wxb/wyb (bf16) ----------
__global__ __launch_bounds__(512) void k_encln(
    const float* __restrict__ x1, const float* __restrict__ xT,
    const float* __restrict__ encW, const float* __restrict__ encb,
    const float* __restrict__ pos, const float* __restrict__ lng,
    const float* __restrict__ lnb, float* __restrict__ wx, float* __restrict__ wy,
    unsigned short* __restrict__ wxb, unsigned short* __restrict__ wyb)
{
    __shared__ float s_in[64 * 128];
    __shared__ float s_w[128 * 64];
    int tid = threadIdx.x;
    int T0 = blockIdx.x * 64;
    int stream = blockIdx.y;
    for (int i = tid; i < 2048; i += 512) ((float4*)s_w)[i] = ((const float4*)encW)[i];
    if (stream == 0) {
        for (int i = tid; i < 2048; i += 512)
            ((float4*)s_in)[i] = ((const float4*)(x1 + (size_t)T0 * 128))[i];
    } else {
        for (int i = tid; i < 2048; i += 512) {
            float4 v = ((const float4*)(xT + (size_t)T0 * 128))[i];
            float4 o;
            o.x = v.x > 0.f ? 2.f * v.x : v.x;
            o.y = v.y > 0.f ? 2.f * v.y : v.y;
            o.z = v.z > 0.f ? 2.f * v.z : v.z;
            o.w = v.w > 0.f ? 2.f * v.w : v.w;
            ((float4*)s_in)[i] = o;
        }
    }
    __syncthreads();
    int q = tid & 15, o4 = q * 4;
    int tg = tid >> 4;
    float acc[2][4] = {};
    for (int ci = 0; ci < 128; ++ci) {
        float4 w = *(const float4*)&s_w[ci * 64 + o4];
        #pragma unroll
        for (int i = 0; i < 2; ++i) {
            float xin = s_in[(tg * 2 + i) * 128 + ci];
            acc[i][0] = fmaf(xin, w.x, acc[i][0]);
            acc[i][1] = fmaf(xin, w.y, acc[i][1]);
            acc[i][2] = fmaf(xin, w.z, acc[i][2]);
            acc[i][3] = fmaf(xin, w.w, acc[i][3]);
        }
    }
    float4 eb = *(const float4*)&encb[o4];
    float4 g  = *(const float4*)&lng[o4];
    float4 bb = *(const float4*)&lnb[o4];
    float* dst = stream == 0 ? wx : wy;
    unsigned short* dstb = stream == 0 ? wxb : wyb;
    #pragma unroll
    for (int i = 0; i < 2; ++i) {
        int t = T0 + tg * 2 + i;
        int n = t & 16383;
        float4 pv = *(const float4*)&pos[(size_t)n * 64 + o4];
        float v0 = acc[i][0] + eb.x + pv.x;
        float v1 = acc[i][1] + eb.y + pv.y;
        float v2 = acc[i][2] + eb.z + pv.z;
        float v3 = acc[i][3] + eb.w + pv.w;
        float sm = v0 + v1 + v2 + v3;
        float sq = v0 * v0 + v1 * v1 + v2 * v2 + v3 * v3;
        #pragma unroll
        for (int off = 1; off < 16; off <<= 1) {
            sm += __shfl_xor(sm, off);
            sq += __shfl_xor(sq, off);
        }
        float m = sm * (1.f / 64.f);
        float vr = sq * (1.f / 64.f) - m * m;
        float rs = rsqrtf(vr + EPSF);
        float4 o;
        o.x = (v0 - m) * rs * g.x + bb.x;
        o.y = (v1 - m) * rs * g.y + bb.y;
        o.z = (v2 - m) * rs * g.z + bb.z;
        o.w = (v3 - m) * rs * g.w + bb.w;
        *(float4*)&dst[(size_t)t * 64 + o4] = o;
        uint2 ob;
        ob.x = f2bf(o.x) | (f2bf(o.y) << 16);
        ob.y = f2bf(o.z) | (f2bf(o.w) << 16);
        *(uint2*)&dstb[(size_t)t * 64 + o4] = ob;
    }
}

// ---------------- K4: qkv GEMM via MFMA (no LDS), direct window-major bf16 out -------
// C[out][tok]: A = qkvWT (lane=out), B = wxb/wyb (lane=token). 128 tok x 192 out/block.
// qk: per combo=((s*2+b)*8+head)*64+wid, token p: 16 bf16 {q[0..7], k[0..7]*KSCL}
// vT: per combo: [d=0..7][p=0..255] bf16
__global__ __launch_bounds__(256) void k_qkv(
    const unsigned short* __restrict__ wxb, const unsigned short* __restrict__ wyb,
    const unsigned short* __restrict__ qkvWT,
    unsigned short* __restrict__ qk, unsigned short* __restrict__ vT)
{
    int tid = threadIdx.x;
    int wv = tid >> 6, lane = tid & 63, l31 = lane & 31, lh = lane >> 5;
    int s = blockIdx.y;
    int T0 = blockIdx.x * 128;
    int b = T0 >> 14;
    int row = (T0 & 16383) >> 7;
    const unsigned short* src = s ? wyb : wxb;
    int t = T0 + wv * 32 + l31;
    short8 bfr[4];
    #pragma unroll
    for (int ks = 0; ks < 4; ++ks)
        bfr[ks] = *(const short8*)&src[(size_t)t * 64 + ks * 16 + lh * 8];
    int cp = wv * 32 + l31;
    int wid = ((row >> 4) << 3) + (cp >> 4);
    int p = ((row & 15) << 4) + (cp & 15);
    size_t cb = (size_t)(s * 2 + b) * 512 + wid;     // + head*64 = combo
    #pragma unroll
    for (int nt = 0; nt < 6; ++nt) {
        f32x16 acc = {};
        #pragma unroll
        for (int ks = 0; ks < 4; ++ks) {
            short8 afr = *(const short8*)&qkvWT[(size_t)(nt * 32 + l31) * 64 + ks * 16 + lh * 8];
            acc = __builtin_amdgcn_mfma_f32_32x32x16_bf16(afr, bfr[ks], acc, 0, 0, 0);
        }
        if (nt < 4) {
            const float scl = nt < 2 ? 1.f : KSCL;
            const int sec = nt < 2 ? 0 : 1;
            #pragma unroll
            for (int g = 0; g < 4; ++g) {
                int head = (nt & 1) * 4 + g;
                unsigned short* rec = qk + (cb + head * 64) * 4096;
                float f0 = acc[4 * g + 0] * scl, f1 = acc[4 * g + 1] * scl;
                float f2 = acc[4 * g + 2] * scl, f3 = acc[4 * g + 3] * scl;
                unsigned u01, u23;
                asm("v_cvt_pk_bf16_f32 %0, %1, %2" : "=v"(u01) : "v"(f0), "v"(f1));
                asm("v_cvt_pk_bf16_f32 %0, %1, %2" : "=v"(u23) : "v"(f2), "v"(f3));
                int off = p * 16 + sec * 8 + 4 * lh;
                *(unsigned*)(rec + off) = u01;
                *(unsigned*)(rec + off + 2) = u23;
            }
        } else {
            #pragma unroll
            for (int g = 0; g < 4; ++g) {
                int head = (nt - 4) * 4 + g;
                unsigned short* vrec = vT + (cb + head * 64) * 2048;
                int d0 = 4 * lh;
                vrec[(d0 + 0) * 256 + p] = (unsigned short)f2bf(acc[4 * g + 0]);
                vrec[(d0 + 1) * 256 + p] = (unsigned short)f2bf(acc[4 * g + 1]);
                vrec[(d0 + 2) * 256 + p] = (unsigned short)f2bf(acc[4 * g + 2]);
                vrec[(d0 + 3) * 256 + p] = (unsigned short)f2bf(acc[4 * g + 3]);
            }
        }
    }
}

// ---------------- K5: MFMA dual-stream windowed attention (cross values) -------------
__global__ __launch_bounds__(256) void k_attn(
    const unsigned short* __restrict__ qk, const unsigned short* __restrict__ vT,
    float* __restrict__ ox, float* __restrict__ oy)
{
    int tid = threadIdx.x;
    int wave = tid >> 6, lane = tid & 63;
    int lh = lane >> 5, l31 = lane & 31;
    int bx = blockIdx.x;
    int s = bx >> 10;
    int r = bx & 1023;                 // (b*8+head)*64 + wid
    int head = (r >> 6) & 7, wid = r & 63, b = r >> 9;
    const unsigned short* qbase = qk + ((size_t)s * 1024 + r) * 4096;
    const unsigned short* vbase = vT + ((size_t)(s ^ 1) * 1024 + r) * 2048;  // cross v

    short8 qf[2];
    #pragma unroll
    for (int qt = 0; qt < 2; ++qt) {
        uint4 v = {0u, 0u, 0u, 0u};
        if (lh == 0) v = *(const uint4*)(qbase + (size_t)(wave * 64 + qt * 32 + l31) * 16);
        qf[qt] = __builtin_bit_cast(short8, v);
    }
    f32x16 acc[2];
    #pragma unroll
    for (int qt = 0; qt < 2; ++qt) acc[qt] = (f32x16){};
    const unsigned ONES = 0x3F803F80u;

    for (int jt = 0; jt < 8; ++jt) {
        uint4 kv = {0u, 0u, 0u, 0u};
        if (lh == 0) kv = *(const uint4*)(qbase + (size_t)(jt * 32 + l31) * 16 + 8);
        short8 kf = __builtin_bit_cast(short8, kv);
        uint2 a0 = {ONES, ONES}, a1 = {ONES, ONES}, a2 = {ONES, ONES}, a3 = {ONES, ONES};
        if (l31 < 8) {
            const unsigned short* vp = vbase + l31 * 256 + jt * 32 + lh * 4;
            a0 = *(const uint2*)vp;
            a1 = *(const uint2*)(vp + 8);
            a2 = *(const uint2*)(vp + 16);
            a3 = *(const uint2*)(vp + 24);
        }
        uint4 vaw = {a0.x, a0.y, a1.x, a1.y};
        uint4 vbw = {a2.x, a2.y, a3.x, a3.y};
        short8 vf0 = __builtin_bit_cast(short8, vaw);
        short8 vf1 = __builtin_bit_cast(short8, vbw);
        #pragma unroll
        for (int qt = 0; qt < 2; ++qt) {
            f32x16 c = __builtin_amdgcn_mfma_f32_32x32x16_bf16(kf, qf[qt], (f32x16){}, 0, 0, 0);
            float p[16];
            #pragma unroll
            for (int i = 0; i < 16; ++i) p[i] = EXP2(c[i]);
            unsigned pk[8];
            #pragma unroll
            for (int i = 0; i < 8; ++i) {
                unsigned pkv;
                asm("v_cvt_pk_bf16_f32 %0, %1, %2" : "=v"(pkv) : "v"(p[2 * i]), "v"(p[2 * i + 1]));
                pk[i] = pkv;
            }
            uint4 bw0 = {pk[0], pk[1], pk[2], pk[3]};
            uint4 bw1 = {pk[4], pk[5], pk[6], pk[7]};
            short8 B0 = __builtin_bit_cast(short8, bw0);
            short8 B1 = __builtin_bit_cast(short8, bw1);
            acc[qt] = __builtin_amdgcn_mfma_f32_32x32x16_bf16(vf0, B0, acc[qt], 0, 0, 0);
            acc[qt] = __builtin_amdgcn_mfma_f32_32x32x16_bf16(vf1, B1, acc[qt], 0, 0, 0);
        }
    }
    float* dst = s ? oy : ox;
    #pragma unroll
    for (int qt = 0; qt < 2; ++qt) {
        float inv = 1.f / acc[qt][4];
        int p = wave * 64 + qt * 32 + l31;
        int orow = (wid >> 3) * 16 + (p >> 4);
        int ocol = (wid & 7) * 16 + (p & 15);
        size_t t = (size_t)b * 16384 + orow * 128 + ocol;
        float4 o;
        o.x = acc[qt][0] * inv; o.y = acc[qt][1] * inv;
        o.z = acc[qt][2] * inv; o.w = acc[qt][3] * inv;
        *(float4*)&dst[t * 64 + head * 8 + lh * 4] = o;
    }
}

// ---------------- K6: proj + residual + FFN (both streams) -> z = xf_x + xf_y -------
__global__ __launch_bounds__(256) void k_fuse(
    const float* __restrict__ ox, const float* __restrict__ oy,
    const float* __restrict__ wx, const float* __restrict__ wy,
    const float* __restrict__ projW, const float* __restrict__ projb,
    const float* __restrict__ W1, const float* __restrict__ b1,
    const float* __restrict__ W2, const float* __restrict__ b2,
    const float* __restrict__ lng, const float* __restrict__ lnb,
    float* __restrict__ z)
{
    __shared__ float s_proj[4096];
    __shared__ float s_W1[4096];
    __shared__ float s_W2[4096];
    __shared__ float s_a[4096];
    __shared__ float s_b[4096];
    int tid = threadIdx.x;
    int T0 = blockIdx.x * 64;
    for (int i = tid; i < 1024; i += 256) {
        ((float4*)s_proj)[i] = ((const float4*)projW)[i];
        ((float4*)s_W1)[i]   = ((const float4*)W1)[i];
        ((float4*)s_W2)[i]   = ((const float4*)W2)[i];
    }
    int q = tid & 15, o4 = q * 4;
    int tg = tid >> 4;
    float4 pbv = *(const float4*)&projb[o4];
    float4 b1v = *(const float4*)&b1[o4];
    float4 b2v = *(const float4*)&b2[o4];
    float4 gv  = *(const float4*)&lng[o4];
    float4 bv  = *(const float4*)&lnb[o4];
    float zacc[4][4] = {};
    for (int s = 0; s < 2; ++s) {
        const float* osrc = s == 0 ? ox : oy;
        const float* wsrc = s == 0 ? wx : wy;
        __syncthreads();
        for (int i = tid; i < 1024; i += 256)
            ((float4*)s_a)[i] = ((const float4*)(osrc + (size_t)T0 * 64))[i];
        __syncthreads();
        float xm[4][4];
        #pragma unroll
        for (int i = 0; i < 4; ++i) {
            xm[i][0] = pbv.x; xm[i][1] = pbv.y; xm[i][2] = pbv.z; xm[i][3] = pbv.w;
        }
        for (int c = 0; c < 64; ++c) {
            float4 w = *(const float4*)&s_proj[c * 64 + o4];
            #pragma unroll
            for (int i = 0; i < 4; ++i) {
                float a = s_a[(tg * 4 + i) * 64 + c];
                xm[i][0] = fmaf(a, w.x, xm[i][0]);
                xm[i][1] = fmaf(a, w.y, xm[i][1]);
                xm[i][2] = fmaf(a, w.z, xm[i][2]);
                xm[i][3] = fmaf(a, w.w, xm[i][3]);
            }
        }
        #pragma unroll
        for (int i = 0; i < 4; ++i) {
            size_t t = T0 + tg * 4 + i;
            float4 wv = *(const float4*)&wsrc[t * 64 + o4];
            xm[i][0] += wv.x; xm[i][1] += wv.y; xm[i][2] += wv.z; xm[i][3] += wv.w;
        }
        #pragma unroll
        for (int i = 0; i < 4; ++i) {
            float sm = xm[i][0] + xm[i][1] + xm[i][2] + xm[i][3];
            float sq = xm[i][0] * xm[i][0] + xm[i][1] * xm[i][1]
                     + xm[i][2] * xm[i][2] + xm[i][3] * xm[i][3];
            #pragma unroll
            for (int off = 1; off < 16; off <<= 1) {
                sm += __shfl_xor(sm, off);
                sq += __shfl_xor(sq, off);
            }
            float m = sm * (1.f / 64.f);
            float vr = sq * (1.f / 64.f) - m * m;
            float rs = rsqrtf(vr + EPSF);
            float4 u;
            u.x = (xm[i][0] - m) * rs * gv.x + bv.x;
            u.y = (xm[i][1] - m) * rs * gv.y + bv.y;
            u.z = (xm[i][2] - m) * rs * gv.z + bv.z;
            u.w = (xm[i][3] - m) * rs * gv.w + bv.w;
            *(float4*)&s_b[(tg * 4 + i) * 64 + o4] = u;
        }
        __syncthreads();
        float h[4][4];
        #pragma unroll
        for (int i = 0; i < 4; ++i) {
            h[i][0] = b1v.x; h[i][1] = b1v.y; h[i][2] = b1v.z; h[i][3] = b1v.w;
        }
        for (int c = 0; c < 64; ++c) {
            float4 w = *(const float4*)&s_W1[c * 64 + o4];
            #pragma unroll
            for (int i = 0; i < 4; ++i) {
                float a = s_b[(tg * 4 + i) * 64 + c];
                h[i][0] = fmaf(a, w.x, h[i][0]);
                h[i][1] = fmaf(a, w.y, h[i][1]);
                h[i][2] = fmaf(a, w.z, h[i][2]);
                h[i][3] = fmaf(a, w.w, h[i][3]);
            }
        }
        #pragma unroll
        for (int i = 0; i < 4; ++i) {
            float4 u;
            u.x = fmaxf(h[i][0], 0.f); u.y = fmaxf(h[i][1], 0.f);
            u.z = fmaxf(h[i][2], 0.f); u.w = fmaxf(h[i][3], 0.f);
            *(float4*)&s_a[(tg * 4 + i) * 64 + o4] = u;
        }
        __syncthreads();
        float xf[4][4];
        #pragma unroll
        for (int i = 0; i < 4; ++i) {
            xf[i][0] = xm[i][0] + b2v.x; xf[i][1] = xm[i][1] + b2v.y;
            xf[i][2] = xm[i][2] + b2v.z; xf[i][3] = xm[i][3] + b2v.w;
        }
        for (int c = 0; c < 64; ++c) {
            float4 w = *(const float4*)&s_W2[c * 64 + o4];
            #pragma unroll
            for (int i = 0; i < 4; ++i) {
                float a = s_a[(tg * 4 + i) * 64 + c];
                xf[i][0] = fmaf(a, w.x, xf[i][0]);
                xf[i][1] = fmaf(a, w.y, xf[i][1]);
                xf[i][2] = fmaf(a, w.z, xf[i][2]);
                xf[i][3] = fmaf(a, w.w, xf[i][3]);
            }
        }
        #pragma unroll
        for (int i = 0; i < 4; ++i) {
            zacc[i][0] += xf[i][0]; zacc[i][1] += xf[i][1];
            zacc[i][2] += xf[i][2]; zacc[i][3] += xf[i][3];
        }
    }
    #pragma unroll
    for (int i = 0; i < 4; ++i) {
        size_t t = T0 + tg * 4 + i;
        float4 o; o.x = zacc[i][0]; o.y = zacc[i][1]; o.z = zacc[i][2]; o.w = zacc[i][3];
        *(float4*)&z[t * 64 + o4] = o;
    }
}

// ---------------- K7: dec GEMM (64 -> 128) + 2*decb ----------------
__global__ __launch_bounds__(256) void k_dec(
    const float* __restrict__ z, const float* __restrict__ decW,
    const float* __restrict__ decb, float* __restrict__ out)
{
    __shared__ float s_z[4096];
    __shared__ float s_dec[8192];
    int tid = threadIdx.x;
    int T0 = blockIdx.x * 64;
    for (int i = tid; i < 1024; i += 256)
        ((float4*)s_z)[i] = ((const float4*)(z + (size_t)T0 * 64))[i];
    for (int i = tid; i < 2048; i += 256)
        ((float4*)s_dec)[i] = ((const float4*)decW)[i];
    __syncthreads();
    int q = tid & 31, m4 = q * 4;
    int tg = tid >> 5;
    float4 dbv = *(const float4*)&decb[m4];
    float acc[8][4];
    #pragma unroll
    for (int i = 0; i < 8; ++i) {
        acc[i][0] = 2.f * dbv.x; acc[i][1] = 2.f * dbv.y;
        acc[i][2] = 2.f * dbv.z; acc[i][3] = 2.f * dbv.w;
    }
    for (int c = 0; c < 64; ++c) {
        float4 w = *(const float4*)&s_dec[c * 128 + m4];
        #pragma unroll
        for (int i = 0; i < 8; ++i) {
            float a = s_z[(tg * 8 + i) * 64 + c];
            acc[i][0] = fmaf(a, w.x, acc[i][0]);
            acc[i][1] = fmaf(a, w.y, acc[i][1]);
            acc[i][2] = fmaf(a, w.z, acc[i][2]);
            acc[i][3] = fmaf(a, w.w, acc[i][3]);
        }
    }
    #pragma unroll
    for (int i = 0; i < 8; ++i) {
        size_t t = T0 + tg * 8 + i;
        float4 o; o.x = acc[i][0]; o.y = acc[i][1]; o.z = acc[i][2]; o.w = acc[i][3];
        *(float4*)&out[t * 128 + m4] = o;
    }
}

extern "C" void kernel_launch(void* const* d_in, const int* in_sizes, int n_in,
                              void* d_out, int out_size, void* d_ws, size_t ws_size,
                              hipStream_t stream) {
    const float* x_C   = (const float*)d_in[0];
    const float* x_T   = (const float*)d_in[1];
    const float* dwW   = (const float*)d_in[2];
    const float* dwB   = (const float*)d_in[3];
    const float* pw    = (const float*)d_in[4];
    const float* pwb   = (const float*)d_in[5];
    const float* gam   = (const float*)d_in[6];
    const float* bet   = (const float*)d_in[7];
    const float* mean  = (const float*)d_in[8];
    const float* var   = (const float*)d_in[9];
    const float* encW  = (const float*)d_in[10];
    const float* encb  = (const float*)d_in[11];
    const float* pos   = (const float*)d_in[12];
    const float* lng   = (const float*)d_in[13];
    const float* lnb   = (const float*)d_in[14];
    const float* qkvW  = (const float*)d_in[15];
    const float* projW = (const float*)d_in[16];
    const float* projb = (const float*)d_in[17];
    const float* W1    = (const float*)d_in[18];
    const float* b1    = (const float*)d_in[19];
    const float* W2    = (const float*)d_in[20];
    const float* b2    = (const float*)d_in[21];
    const float* decW  = (const float*)d_in[22];
    const float* decb  = (const float*)d_in[23];
    float* out = (float*)d_out;

    float* ws = (float*)d_ws;
    // region0 [0 .. 6,291,456 f): xdwb(bf16)+x1 (K1-K3) -> qk+vT (K4-K5) -> z (K6-K7)
    unsigned short* xdwb = (unsigned short*)ws;                 // 4,194,304 bf16
    float* x1   = ws + 2097152;                                 // 4,194,304 f
    unsigned short* qkb = (unsigned short*)ws;                  // 8,388,608 bf16
    unsigned short* vTb = (unsigned short*)(ws + 4194304);      // 4,194,304 bf16
    float* z    = ws;
    float* wx   = ws + 6291456;
    float* wy   = ws + 8388608;
    float* ox   = ws + 10485760;
    float* oy   = ws + 12582912;
    unsigned short* wxb = (unsigned short*)(ws + 14680064);     // 2,097,152 bf16
    unsigned short* wyb = (unsigned short*)(ws + 15728640);     // 2,097,152 bf16
    unsigned short* qkvWT = (unsigned short*)(ws + 16777216);   // 12,288 bf16
    unsigned short* weff  = (unsigned short*)(ws + 16783360);   // 16,384 bf16
    float* beff = ws + 16791552;                                // 128 f

    k_dwconv<<<1088, 256, 0, stream>>>(x_C, dwW, dwB, xdwb, qkvW, pw, pwb,
                                       gam, bet, mean, var, qkvWT, weff, beff);
    k_pw<<<512, 256, 0, stream>>>(xdwb, x_C, weff, beff, x1);
    k_encln<<<dim3(512, 2), 512, 0, stream>>>(x1, x_T, encW, encb, pos, lng, lnb,
                                              wx, wy, wxb, wyb);
    k_qkv<<<dim3(256, 2), 256, 0, stream>>>(wxb, wyb, qkvWT, qkb, vTb);
    k_attn<<<2048, 256, 0, stream>>>(qkb, vTb, ox, oy);
    k_fuse<<<512, 256, 0, stream>>>(ox, oy, wx, wy, projW, projb,
                                    W1, b1, W2, b2, lng, lnb, z);
    k_dec<<<512, 256, 0, stream>>>(z, decW, decb, out);
}

// Round 8
// 113.579 us; speedup vs baseline: 5.7575x; 1.2361x over previous
//
#include <hip/hip_runtime.h>
#include <hip/hip_bf16.h>
#include <math.h>

#define EPSF 1e-5f
// scale (1/sqrt(8)) * log2(e), folded into k at qkv time
#define KSCL 0.51010090329771713f

#if __has_builtin(__builtin_amdgcn_exp2f)
#define EXP2(x) __builtin_amdgcn_exp2f(x)
#else
#define EXP2(x) exp2f(x)
#endif

typedef __attribute__((ext_vector_type(8))) short short8;   // 8 bf16 = 4 VGPR
typedef __attribute__((ext_vector_type(16))) float f32x16;  // MFMA 32x32 acc

__device__ __forceinline__ unsigned int f2bf(float f) {
    union { float f; unsigned int i; } u; u.f = f;
    unsigned int r = u.i + 0x7FFFu + ((u.i >> 16) & 1u);
    return r >> 16;
}
__device__ __forceinline__ unsigned cvtpk(float a, float b) {
    unsigned r;
    asm("v_cvt_pk_bf16_f32 %0, %1, %2" : "=v"(r) : "v"(a), "v"(b));
    return r;
}
// Round-2-proven: build natural-k B fragments for a 32-row C block from 8
// pairwise-packed words (pk[i] = rows (2i,2i+1) in C reg order) + partner xchg.
__device__ __forceinline__ void bbuild(const unsigned pk[8], int lh,
                                       short8& B0, short8& B1) {
    unsigned xs[8];
    #pragma unroll
    for (int i = 0; i < 8; ++i) xs[i] = (unsigned)__shfl_xor((int)pk[i], 32);
    uint4 w0, w1;
    w0.x = lh ? xs[2] : pk[0]; w0.y = lh ? xs[3] : pk[1];
    w0.z = lh ? pk[2] : xs[0]; w0.w = lh ? pk[3] : xs[1];
    w1.x = lh ? xs[6] : pk[4]; w1.y = lh ? xs[7] : pk[5];
    w1.z = lh ? pk[6] : xs[4]; w1.w = lh ? pk[7] : xs[5];
    B0 = __builtin_bit_cast(short8, w0);
    B1 = __builtin_bit_cast(short8, w1);
}

// ---------------- K1: depthwise 3x3 conv + bias -> bf16; extra blocks: weight prep ----
__global__ __launch_bounds__(256) void k_dwconv(
    const float* __restrict__ xC, const float* __restrict__ dwW,
    const float* __restrict__ dwB, unsigned short* __restrict__ xdwb,
    const float* __restrict__ qkvW, const float* __restrict__ pw,
    const float* __restrict__ pwb, const float* __restrict__ gam,
    const float* __restrict__ bet, const float* __restrict__ mean,
    const float* __restrict__ var, const float* __restrict__ projW,
    const float* __restrict__ W1, const float* __restrict__ W2,
    const float* __restrict__ decW,
    unsigned short* __restrict__ qkvWT, unsigned short* __restrict__ weff,
    float* __restrict__ beff, unsigned short* __restrict__ projWTn,
    unsigned short* __restrict__ W1Tn, unsigned short* __restrict__ W2Tn,
    unsigned short* __restrict__ decTn)
{
    int tid = threadIdx.x;
    int bid = blockIdx.x;
    if (bid >= 1024) {                  // -------- weight prep (plain transposes) -----
        int pid = (bid - 1024) * 256 + tid;
        if (pid < 12288) {              // qkvWT[o*64+c] = qkvW[c*192+o]
            int o = pid >> 6, c = pid & 63;
            qkvWT[pid] = (unsigned short)f2bf(qkvW[c * 192 + o]);
        } else if (pid < 28672) {       // weff[co*128+ci] = pw*scale
            int i = pid - 12288;
            int co = i >> 7;
            float sc = gam[co] * rsqrtf(var[co] + EPSF);
            weff[i] = (unsigned short)f2bf(pw[i] * sc);
        } else if (pid < 32768) {       // projWTn[m*64+c] = projW[c*64+m]
            int i = pid - 28672, m = i >> 6, c = i & 63;
            projWTn[i] = (unsigned short)f2bf(projW[c * 64 + m]);
        } else if (pid < 36864) {       // W1Tn[m*64+c] = W1[c*64+m]
            int i = pid - 32768, m = i >> 6, c = i & 63;
            W1Tn[i] = (unsigned short)f2bf(W1[c * 64 + m]);
        } else if (pid < 40960) {       // W2Tn[m*64+c] = W2[c*64+m]
            int i = pid - 36864, m = i >> 6, c = i & 63;
            W2Tn[i] = (unsigned short)f2bf(W2[c * 64 + m]);
        } else if (pid < 49152) {       // decTn[m*64+c] = decW[c*128+m], m<128
            int i = pid - 40960, m = i >> 6, c = i & 63;
            decTn[i] = (unsigned short)f2bf(decW[c * 128 + m]);
        } else if (pid < 49280) {       // beff
            int i = pid - 49152;
            float sc = gam[i] * rsqrtf(var[i] + EPSF);
            beff[i] = (pwb[i] - mean[i]) * sc + bet[i];
        }
        return;
    }
    __shared__ float s_w[128 * 9];
    __shared__ float s_bias[128];
    for (int i = tid; i < 128 * 9; i += 256) s_w[i] = dwW[i];
    if (tid < 128) s_bias[tid] = dwB[tid];
    __syncthreads();
    int idx = bid * 256 + tid;
    int c4 = (idx & 31) * 4;
    int pg = idx >> 5;
    int t0 = pg * 4;
    int b = t0 >> 14, n = t0 & 16383;
    int row = n >> 7, col0 = n & 127;
    float vb[3][6][4];
    #pragma unroll
    for (int ky = 0; ky < 3; ++ky) {
        int r = row + ky - 1;
        #pragma unroll
        for (int cx = 0; cx < 6; ++cx) {
            int cl = col0 + cx - 1;
            if ((unsigned)r < 128u && (unsigned)cl < 128u) {
                *(float4*)&vb[ky][cx][0] =
                    *(const float4*)&xC[((size_t)(b << 14) + (r << 7) + cl) * 128 + c4];
            } else {
                vb[ky][cx][0] = 0.f; vb[ky][cx][1] = 0.f; vb[ky][cx][2] = 0.f; vb[ky][cx][3] = 0.f;
            }
        }
    }
    float acc[4][4];
    #pragma unroll
    for (int p = 0; p < 4; ++p)
        #pragma unroll
        for (int j = 0; j < 4; ++j) acc[p][j] = s_bias[c4 + j];
    #pragma unroll
    for (int ky = 0; ky < 3; ++ky)
        #pragma unroll
        for (int kx = 0; kx < 3; ++kx)
            #pragma unroll
            for (int j = 0; j < 4; ++j) {
                float w = s_w[(c4 + j) * 9 + ky * 3 + kx];
                #pragma unroll
                for (int p = 0; p < 4; ++p)
                    acc[p][j] = fmaf(w, vb[ky][p + kx][j], acc[p][j]);
            }
    #pragma unroll
    for (int p = 0; p < 4; ++p) {
        uint2 o;
        o.x = f2bf(acc[p][0]) | (f2bf(acc[p][1]) << 16);
        o.y = f2bf(acc[p][2]) | (f2bf(acc[p][3]) << 16);
        *(uint2*)&xdwb[((size_t)t0 + p) * 128 + c4] = o;
    }
}

// ---------------- K2: pointwise conv + BN + ReLU + residual via MFMA (no LDS) --------
__global__ __launch_bounds__(256) void k_pw(
    const unsigned short* __restrict__ xdwb, const float* __restrict__ xC,
    const unsigned short* __restrict__ weff, const float* __restrict__ beff,
    float* __restrict__ x1)
{
    int tid = threadIdx.x;
    int wv = tid >> 6, lane = tid & 63, l31 = lane & 31, lh = lane >> 5;
    int wr = wv >> 1, wc = wv & 1;
    int T0 = blockIdx.x * 64;
    int ta = T0 + wr * 32 + l31;
    short8 af[8];
    #pragma unroll
    for (int ks = 0; ks < 8; ++ks)
        af[ks] = *(const short8*)&xdwb[(size_t)ta * 128 + ks * 16 + lh * 8];
    #pragma unroll
    for (int nt = 0; nt < 2; ++nt) {
        int co = wc * 64 + nt * 32 + l31;
        f32x16 acc = {};
        #pragma unroll
        for (int ks = 0; ks < 8; ++ks) {
            short8 bfr = *(const short8*)&weff[(size_t)co * 128 + ks * 16 + lh * 8];
            acc = __builtin_amdgcn_mfma_f32_32x32x16_bf16(af[ks], bfr, acc, 0, 0, 0);
        }
        float be = beff[co];
        #pragma unroll
        for (int r = 0; r < 16; ++r) {
            int tt = T0 + wr * 32 + (r & 3) + 8 * (r >> 2) + 4 * lh;
            float v = fmaxf(acc[r] + be, 0.f) + xC[(size_t)tt * 128 + co];
            x1[(size_t)tt * 128 + co] = v;
        }
    }
}

// ---------------- K3: enc + pos + LayerNorm -> wx/wy (f32) + wxb/wyb (bf16) ----------
__global__ __launch_bounds__(512) void k_encln(
    const float* __restrict__ x1, const float* __restrict__ xT,
    const float* __restrict__ encW, const float* __restrict__ encb,
    const float* __restrict__ pos, const float* __restrict__ lng,
    const float* __restrict__ lnb, float* __restrict__ wx, float* __restrict__ wy,
    unsigned short* __restrict__ wxb, unsigned short* __restrict__ wyb)
{
    __shared__ float s_in[64 * 128];
    __shared__ float s_w[128 * 64];
    int tid = threadIdx.x;
    int T0 = blockIdx.x * 64;
    int stream = blockIdx.y;
    for (int i = tid; i < 2048; i += 512) ((float4*)s_w)[i] = ((const float4*)encW)[i];
    if (stream == 0) {
        for (int i = tid; i < 2048; i += 512)
            ((float4*)s_in)[i] = ((const float4*)(x1 + (size_t)T0 * 128))[i];
    } else {
        for (int i = tid; i < 2048; i += 512) {
            float4 v = ((const float4*)(xT + (size_t)T0 * 128))[i];
            float4 o;
            o.x = v.x > 0.f ? 2.f * v.x : v.x;
            o.y = v.y > 0.f ? 2.f * v.y : v.y;
            o.z = v.z > 0.f ? 2.f * v.z : v.z;
            o.w = v.w > 0.f ? 2.f * v.w : v.w;
            ((float4*)s_in)[i] = o;
        }
    }
    __syncthreads();
    int q = tid & 15, o4 = q * 4;
    int tg = tid >> 4;
    float acc[2][4] = {};
    for (int ci = 0; ci < 128; ++ci) {
        float4 w = *(const float4*)&s_w[ci * 64 + o4];
        #pragma unroll
        for (int i = 0; i < 2; ++i) {
            float xin = s_in[(tg * 2 + i) * 128 + ci];
            acc[i][0] = fmaf(xin, w.x, acc[i][0]);
            acc[i][1] = fmaf(xin, w.y, acc[i][1]);
            acc[i][2] = fmaf(xin, w.z, acc[i][2]);
            acc[i][3] = fmaf(xin, w.w, acc[i][3]);
        }
    }
    float4 eb = *(const float4*)&encb[o4];
    float4 g  = *(const float4*)&lng[o4];
    float4 bb = *(const float4*)&lnb[o4];
    float* dst = stream == 0 ? wx : wy;
    unsigned short* dstb = stream == 0 ? wxb : wyb;
    #pragma unroll
    for (int i = 0; i < 2; ++i) {
        int t = T0 + tg * 2 + i;
        int n = t & 16383;
        float4 pv = *(const float4*)&pos[(size_t)n * 64 + o4];
        float v0 = acc[i][0] + eb.x + pv.x;
        float v1 = acc[i][1] + eb.y + pv.y;
        float v2 = acc[i][2] + eb.z + pv.z;
        float v3 = acc[i][3] + eb.w + pv.w;
        float sm = v0 + v1 + v2 + v3;
        float sq = v0 * v0 + v1 * v1 + v2 * v2 + v3 * v3;
        #pragma unroll
        for (int off = 1; off < 16; off <<= 1) {
            sm += __shfl_xor(sm, off);
            sq += __shfl_xor(sq, off);
        }
        float m = sm * (1.f / 64.f);
        float vr = sq * (1.f / 64.f) - m * m;
        float rs = rsqrtf(fmaxf(vr, 0.f) + EPSF);
        float4 o;
        o.x = (v0 - m) * rs * g.x + bb.x;
        o.y = (v1 - m) * rs * g.y + bb.y;
        o.z = (v2 - m) * rs * g.z + bb.z;
        o.w = (v3 - m) * rs * g.w + bb.w;
        *(float4*)&dst[(size_t)t * 64 + o4] = o;
        uint2 ob;
        ob.x = f2bf(o.x) | (f2bf(o.y) << 16);
        ob.y = f2bf(o.z) | (f2bf(o.w) << 16);
        *(uint2*)&dstb[(size_t)t * 64 + o4] = ob;
    }
}

// ---------------- K4: qkv GEMM via MFMA (no LDS), direct window-major bf16 out -------
__global__ __launch_bounds__(256) void k_qkv(
    const unsigned short* __restrict__ wxb, const unsigned short* __restrict__ wyb,
    const unsigned short* __restrict__ qkvWT,
    unsigned short* __restrict__ qk, unsigned short* __restrict__ vT)
{
    int tid = threadIdx.x;
    int wv = tid >> 6, lane = tid & 63, l31 = lane & 31, lh = lane >> 5;
    int s = blockIdx.y;
    int T0 = blockIdx.x * 128;
    int b = T0 >> 14;
    int row = (T0 & 16383) >> 7;
    const unsigned short* src = s ? wyb : wxb;
    int t = T0 + wv * 32 + l31;
    short8 bfr[4];
    #pragma unroll
    for (int ks = 0; ks < 4; ++ks)
        bfr[ks] = *(const short8*)&src[(size_t)t * 64 + ks * 16 + lh * 8];
    int cp = wv * 32 + l31;
    int wid = ((row >> 4) << 3) + (cp >> 4);
    int p = ((row & 15) << 4) + (cp & 15);
    size_t cb = (size_t)(s * 2 + b) * 512 + wid;     // + head*64 = combo
    #pragma unroll
    for (int nt = 0; nt < 6; ++nt) {
        f32x16 acc = {};
        #pragma unroll
        for (int ks = 0; ks < 4; ++ks) {
            short8 afr = *(const short8*)&qkvWT[(size_t)(nt * 32 + l31) * 64 + ks * 16 + lh * 8];
            acc = __builtin_amdgcn_mfma_f32_32x32x16_bf16(afr, bfr[ks], acc, 0, 0, 0);
        }
        if (nt < 4) {
            const float scl = nt < 2 ? 1.f : KSCL;
            const int sec = nt < 2 ? 0 : 1;
            #pragma unroll
            for (int g = 0; g < 4; ++g) {
                int head = (nt & 1) * 4 + g;
                unsigned short* rec = qk + (cb + head * 64) * 4096;
                float f0 = acc[4 * g + 0] * scl, f1 = acc[4 * g + 1] * scl;
                float f2 = acc[4 * g + 2] * scl, f3 = acc[4 * g + 3] * scl;
                unsigned u01 = cvtpk(f0, f1), u23 = cvtpk(f2, f3);
                int off = p * 16 + sec * 8 + 4 * lh;
                *(unsigned*)(rec + off) = u01;
                *(unsigned*)(rec + off + 2) = u23;
            }
        } else {
            #pragma unroll
            for (int g = 0; g < 4; ++g) {
                int head = (nt - 4) * 4 + g;
                unsigned short* vrec = vT + (cb + head * 64) * 2048;
                int d0 = 4 * lh;
                vrec[(d0 + 0) * 256 + p] = (unsigned short)f2bf(acc[4 * g + 0]);
                vrec[(d0 + 1) * 256 + p] = (unsigned short)f2bf(acc[4 * g + 1]);
                vrec[(d0 + 2) * 256 + p] = (unsigned short)f2bf(acc[4 * g + 2]);
                vrec[(d0 + 3) * 256 + p] = (unsigned short)f2bf(acc[4 * g + 3]);
            }
        }
    }
}

// ---------------- K5: MFMA dual-stream windowed attention (r5 verbatim, fp32 out) ----
__global__ __launch_bounds__(256) void k_attn(
    const unsigned short* __restrict__ qk, const unsigned short* __restrict__ vT,
    float* __restrict__ ox, float* __restrict__ oy)
{
    int tid = threadIdx.x;
    int wave = tid >> 6, lane = tid & 63;
    int lh = lane >> 5, l31 = lane & 31;
    int bx = blockIdx.x;
    int s = bx >> 10;
    int r = bx & 1023;
    int head = (r >> 6) & 7, wid = r & 63, b = r >> 9;
    const unsigned short* qbase = qk + ((size_t)s * 1024 + r) * 4096;
    const unsigned short* vbase = vT + ((size_t)(s ^ 1) * 1024 + r) * 2048;  // cross v

    short8 qf[2];
    #pragma unroll
    for (int qt = 0; qt < 2; ++qt) {
        uint4 v = {0u, 0u, 0u, 0u};
        if (lh == 0) v = *(const uint4*)(qbase + (size_t)(wave * 64 + qt * 32 + l31) * 16);
        qf[qt] = __builtin_bit_cast(short8, v);
    }
    f32x16 acc[2];
    #pragma unroll
    for (int qt = 0; qt < 2; ++qt) acc[qt] = (f32x16){};
    const unsigned ONES = 0x3F803F80u;

    for (int jt = 0; jt < 8; ++jt) {
        uint4 kv = {0u, 0u, 0u, 0u};
        if (lh == 0) kv = *(const uint4*)(qbase + (size_t)(jt * 32 + l31) * 16 + 8);
        short8 kf = __builtin_bit_cast(short8, kv);
        uint2 a0 = {ONES, ONES}, a1 = {ONES, ONES}, a2 = {ONES, ONES}, a3 = {ONES, ONES};
        if (l31 < 8) {
            const unsigned short* vp = vbase + l31 * 256 + jt * 32 + lh * 4;
            a0 = *(const uint2*)vp;
            a1 = *(const uint2*)(vp + 8);
            a2 = *(const uint2*)(vp + 16);
            a3 = *(const uint2*)(vp + 24);
        }
        uint4 vaw = {a0.x, a0.y, a1.x, a1.y};
        uint4 vbw = {a2.x, a2.y, a3.x, a3.y};
        short8 vf0 = __builtin_bit_cast(short8, vaw);
        short8 vf1 = __builtin_bit_cast(short8, vbw);
        #pragma unroll
        for (int qt = 0; qt < 2; ++qt) {
            f32x16 c = __builtin_amdgcn_mfma_f32_32x32x16_bf16(kf, qf[qt], (f32x16){}, 0, 0, 0);
            float p[16];
            #pragma unroll
            for (int i = 0; i < 16; ++i) p[i] = EXP2(c[i]);
            unsigned pk[8];
            #pragma unroll
            for (int i = 0; i < 8; ++i) pk[i] = cvtpk(p[2 * i], p[2 * i + 1]);
            uint4 bw0 = {pk[0], pk[1], pk[2], pk[3]};
            uint4 bw1 = {pk[4], pk[5], pk[6], pk[7]};
            short8 B0 = __builtin_bit_cast(short8, bw0);
            short8 B1 = __builtin_bit_cast(short8, bw1);
            acc[qt] = __builtin_amdgcn_mfma_f32_32x32x16_bf16(vf0, B0, acc[qt], 0, 0, 0);
            acc[qt] = __builtin_amdgcn_mfma_f32_32x32x16_bf16(vf1, B1, acc[qt], 0, 0, 0);
        }
    }
    float* dst = s ? oy : ox;
    #pragma unroll
    for (int qt = 0; qt < 2; ++qt) {
        float inv = 1.f / acc[qt][4];
        int p = wave * 64 + qt * 32 + l31;
        int orow = (wid >> 3) * 16 + (p >> 4);
        int ocol = (wid & 7) * 16 + (p & 15);
        size_t t = (size_t)b * 16384 + orow * 128 + ocol;
        float4 o;
        o.x = acc[qt][0] * inv; o.y = acc[qt][1] * inv;
        o.z = acc[qt][2] * inv; o.w = acc[qt][3] * inv;
        *(float4*)&dst[t * 64 + head * 8 + lh * 4] = o;
    }
}

// ---------------- K6: proj + residual + LN + FFN + dec (proven blocks only) ----------
__global__ __launch_bounds__(256) void k_fusedec(
    const float* __restrict__ ox, const float* __restrict__ oy,
    const float* __restrict__ wx, const float* __restrict__ wy,
    const unsigned short* __restrict__ projWTn, const float* __restrict__ projb,
    const unsigned short* __restrict__ W1Tn, const float* __restrict__ b1,
    const unsigned short* __restrict__ W2Tn, const float* __restrict__ b2,
    const unsigned short* __restrict__ decTn, const float* __restrict__ decb,
    const float* __restrict__ lng, const float* __restrict__ lnb,
    float* __restrict__ out)
{
    int tid = threadIdx.x;
    int wv = tid >> 6, l31 = tid & 31, lh = (tid >> 5) & 1;
    int t = blockIdx.x * 128 + wv * 32 + l31;
    f32x16 zacc[2];
    zacc[0] = (f32x16){}; zacc[1] = (f32x16){};
    #pragma unroll 1
    for (int s = 0; s < 2; ++s) {
        const float* osrc = s ? oy : ox;
        const float* wsrc = s ? wy : wx;
        // B for GEMM1 from fp32 o, natural channel order
        short8 bo[4];
        #pragma unroll
        for (int kap = 0; kap < 4; ++kap) {
            float4 f0 = *(const float4*)&osrc[(size_t)t * 64 + kap * 16 + lh * 8];
            float4 f1 = *(const float4*)&osrc[(size_t)t * 64 + kap * 16 + lh * 8 + 4];
            uint4 w;
            w.x = cvtpk(f0.x, f0.y); w.y = cvtpk(f0.z, f0.w);
            w.z = cvtpk(f1.x, f1.y); w.w = cvtpk(f1.z, f1.w);
            bo[kap] = __builtin_bit_cast(short8, w);
        }
        // GEMM1: xm[m][tok] = projW^T @ o + projb + w
        f32x16 a1[2];
        #pragma unroll
        for (int ta = 0; ta < 2; ++ta) {
            f32x16 acc = {};
            #pragma unroll
            for (int kap = 0; kap < 4; ++kap) {
                short8 af = *(const short8*)&projWTn[(size_t)(ta * 32 + l31) * 64 + kap * 16 + lh * 8];
                acc = __builtin_amdgcn_mfma_f32_32x32x16_bf16(af, bo[kap], acc, 0, 0, 0);
            }
            #pragma unroll
            for (int g = 0; g < 4; ++g) {
                int c0 = ta * 32 + g * 8 + lh * 4;
                float4 pb = *(const float4*)&projb[c0];
                float4 wr = *(const float4*)&wsrc[(size_t)t * 64 + c0];
                acc[g * 4 + 0] += pb.x + wr.x;
                acc[g * 4 + 1] += pb.y + wr.y;
                acc[g * 4 + 2] += pb.z + wr.z;
                acc[g * 4 + 3] += pb.w + wr.w;
            }
            a1[ta] = acc;
        }
        // LN(xm)
        float sm = 0.f, sq = 0.f;
        #pragma unroll
        for (int ta = 0; ta < 2; ++ta)
            #pragma unroll
            for (int r = 0; r < 16; ++r) { float v = a1[ta][r]; sm += v; sq += v * v; }
        sm += __shfl_xor(sm, 32); sq += __shfl_xor(sq, 32);
        float mu = sm * (1.f / 64.f);
        float rs = rsqrtf(fmaxf(sq * (1.f / 64.f) - mu * mu, 0.f) + EPSF);
        unsigned pku[2][8];
        #pragma unroll
        for (int ta = 0; ta < 2; ++ta)
            #pragma unroll
            for (int g = 0; g < 4; ++g) {
                int c0 = ta * 32 + g * 8 + lh * 4;
                float4 gg = *(const float4*)&lng[c0];
                float4 bb = *(const float4*)&lnb[c0];
                float u0 = (a1[ta][g * 4 + 0] - mu) * rs * gg.x + bb.x;
                float u1 = (a1[ta][g * 4 + 1] - mu) * rs * gg.y + bb.y;
                float u2 = (a1[ta][g * 4 + 2] - mu) * rs * gg.z + bb.z;
                float u3 = (a1[ta][g * 4 + 3] - mu) * rs * gg.w + bb.w;
                pku[ta][g * 2]     = cvtpk(u0, u1);
                pku[ta][g * 2 + 1] = cvtpk(u2, u3);
            }
        short8 Bu[4];
        bbuild(pku[0], lh, Bu[0], Bu[1]);
        bbuild(pku[1], lh, Bu[2], Bu[3]);
        // GEMM2: h = relu(W1^T @ u + b1)
        unsigned pkh[2][8];
        #pragma unroll
        for (int th = 0; th < 2; ++th) {
            f32x16 acc = {};
            #pragma unroll
            for (int kap = 0; kap < 4; ++kap) {
                short8 af = *(const short8*)&W1Tn[(size_t)(th * 32 + l31) * 64 + kap * 16 + lh * 8];
                acc = __builtin_amdgcn_mfma_f32_32x32x16_bf16(af, Bu[kap], acc, 0, 0, 0);
            }
            #pragma unroll
            for (int g = 0; g < 4; ++g) {
                int c0 = th * 32 + g * 8 + lh * 4;
                float4 bb = *(const float4*)&b1[c0];
                float h0 = fmaxf(acc[g * 4 + 0] + bb.x, 0.f);
                float h1 = fmaxf(acc[g * 4 + 1] + bb.y, 0.f);
                float h2 = fmaxf(acc[g * 4 + 2] + bb.z, 0.f);
                float h3 = fmaxf(acc[g * 4 + 3] + bb.w, 0.f);
                pkh[th][g * 2]     = cvtpk(h0, h1);
                pkh[th][g * 2 + 1] = cvtpk(h2, h3);
            }
        }
        short8 Bh[4];
        bbuild(pkh[0], lh, Bh[0], Bh[1]);
        bbuild(pkh[1], lh, Bh[2], Bh[3]);
        // GEMM3: xf = xm + b2 + W2^T @ h ; z += xf
        #pragma unroll
        for (int ta = 0; ta < 2; ++ta) {
            f32x16 a3 = a1[ta];
            #pragma unroll
            for (int g = 0; g < 4; ++g) {
                int c0 = ta * 32 + g * 8 + lh * 4;
                float4 bb = *(const float4*)&b2[c0];
                a3[g * 4 + 0] += bb.x; a3[g * 4 + 1] += bb.y;
                a3[g * 4 + 2] += bb.z; a3[g * 4 + 3] += bb.w;
            }
            #pragma unroll
            for (int kap = 0; kap < 4; ++kap) {
                short8 af = *(const short8*)&W2Tn[(size_t)(ta * 32 + l31) * 64 + kap * 16 + lh * 8];
                a3 = __builtin_amdgcn_mfma_f32_32x32x16_bf16(af, Bh[kap], a3, 0, 0, 0);
            }
            zacc[ta] += a3;
        }
    }
    // dec: out[m][tok] = decW^T @ z + 2*decb
    unsigned pkz[2][8];
    #pragma unroll
    for (int ta = 0; ta < 2; ++ta)
        #pragma unroll
        for (int g = 0; g < 4; ++g) {
            pkz[ta][g * 2]     = cvtpk(zacc[ta][g * 4 + 0], zacc[ta][g * 4 + 1]);
            pkz[ta][g * 2 + 1] = cvtpk(zacc[ta][g * 4 + 2], zacc[ta][g * 4 + 3]);
        }
    short8 Bz[4];
    bbuild(pkz[0], lh, Bz[0], Bz[1]);
    bbuild(pkz[1], lh, Bz[2], Bz[3]);
    #pragma unroll
    for (int mu4 = 0; mu4 < 4; ++mu4) {
        f32x16 a4 = {};
        #pragma unroll
        for (int g = 0; g < 4; ++g) {
            int c0 = mu4 * 32 + g * 8 + lh * 4;
            float4 db = *(const float4*)&decb[c0];
            a4[g * 4 + 0] = 2.f * db.x; a4[g * 4 + 1] = 2.f * db.y;
            a4[g * 4 + 2] = 2.f * db.z; a4[g * 4 + 3] = 2.f * db.w;
        }
        #pragma unroll
        for (int kap = 0; kap < 4; ++kap) {
            short8 af = *(const short8*)&decTn[(size_t)(mu4 * 32 + l31) * 64 + kap * 16 + lh * 8];
            a4 = __builtin_amdgcn_mfma_f32_32x32x16_bf16(af, Bz[kap], a4, 0, 0, 0);
        }
        #pragma unroll
        for (int g = 0; g < 4; ++g) {
            int c0 = mu4 * 32 + g * 8 + lh * 4;
            float4 o;
            o.x = a4[g * 4 + 0]; o.y = a4[g * 4 + 1];
            o.z = a4[g * 4 + 2]; o.w = a4[g * 4 + 3];
            *(float4*)&out[(size_t)t * 128 + c0] = o;
        }
    }
}

extern "C" void kernel_launch(void* const* d_in, const int* in_sizes, int n_in,
                              void* d_out, int out_size, void* d_ws, size_t ws_size,
                              hipStream_t stream) {
    const float* x_C   = (const float*)d_in[0];
    const float* x_T   = (const float*)d_in[1];
    const float* dwW   = (const float*)d_in[2];
    const float* dwB   = (const float*)d_in[3];
    const float* pw    = (const float*)d_in[4];
    const float* pwb   = (const float*)d_in[5];
    const float* gam   = (const float*)d_in[6];
    const float* bet   = (const float*)d_in[7];
    const float* mean  = (const float*)d_in[8];
    const float* var   = (const float*)d_in[9];
    const float* encW  = (const float*)d_in[10];
    const float* encb  = (const float*)d_in[11];
    const float* pos   = (const float*)d_in[12];
    const float* lng   = (const float*)d_in[13];
    const float* lnb   = (const float*)d_in[14];
    const float* qkvW  = (const float*)d_in[15];
    const float* projW = (const float*)d_in[16];
    const float* projb = (const float*)d_in[17];
    const float* W1    = (const float*)d_in[18];
    const float* b1    = (const float*)d_in[19];
    const float* W2    = (const float*)d_in[20];
    const float* b2    = (const float*)d_in[21];
    const float* decW  = (const float*)d_in[22];
    const float* decb  = (const float*)d_in[23];
    float* out = (float*)d_out;

    float* ws = (float*)d_ws;
    unsigned short* xdwb = (unsigned short*)ws;                 // [0, 2097152) f
    float* x1   = ws + 2097152;                                 // [2097152, 6291456) f
    unsigned short* qkb  = (unsigned short*)(ws + 6291456);     // 8,388,608 bf16
    unsigned short* vTb  = (unsigned short*)(ws + 10485760);    // 4,194,304 bf16
    float* wx   = ws + 12582912;                                // 2,097,152 f
    float* wy   = ws + 14680064;                                // 2,097,152 f
    unsigned short* wxb = (unsigned short*)(ws + 16777216);     // 2,097,152 bf16
    unsigned short* wyb = (unsigned short*)(ws + 17825792);     // 2,097,152 bf16
    float* ox   = ws + 18874368;                                // 2,097,152 f
    float* oy   = ws + 20971520;                                // 2,097,152 f
    unsigned short* qkvWT   = (unsigned short*)(ws + 23068672); // 12,288 bf16
    unsigned short* weff    = (unsigned short*)(ws + 23074816); // 16,384 bf16
    float*          beff    = ws + 23083008;                    // 128 f
    unsigned short* projWTn = (unsigned short*)(ws + 23083136); // 4,096 bf16
    unsigned short* W1Tn    = (unsigned short*)(ws + 23085184); // 4,096 bf16
    unsigned short* W2Tn    = (unsigned short*)(ws + 23087232); // 4,096 bf16
    unsigned short* decTn   = (unsigned short*)(ws + 23089280); // 8,192 bf16

    k_dwconv<<<1217, 256, 0, stream>>>(x_C, dwW, dwB, xdwb, qkvW, pw, pwb,
                                       gam, bet, mean, var, projW, W1, W2, decW,
                                       qkvWT, weff, beff, projWTn, W1Tn, W2Tn, decTn);
    k_pw<<<512, 256, 0, stream>>>(xdwb, x_C, weff, beff, x1);
    k_encln<<<dim3(512, 2), 512, 0, stream>>>(x1, x_T, encW, encb, pos, lng, lnb,
                                              wx, wy, wxb, wyb);
    k_qkv<<<dim3(256, 2), 256, 0, stream>>>(wxb, wyb, qkvWT, qkb, vTb);
    k_attn<<<2048, 256, 0, stream>>>(qkb, vTb, ox, oy);
    k_fusedec<<<256, 256, 0, stream>>>(ox, oy, wx, wy, projWTn, projb,
                                       W1Tn, b1, W2Tn, b2, decTn, decb,
                                       lng, lnb, out);
}

// Round 9
// 100.798 us; speedup vs baseline: 6.4876x; 1.1268x over previous
//
#include <hip/hip_runtime.h>
#include <hip/hip_bf16.h>
#include <math.h>

#define EPSF 1e-5f
// scale (1/sqrt(8)) * log2(e), folded into k at qkv time
#define KSCL 0.51010090329771713f

#if __has_builtin(__builtin_amdgcn_exp2f)
#define EXP2(x) __builtin_amdgcn_exp2f(x)
#else
#define EXP2(x) exp2f(x)
#endif

typedef __attribute__((ext_vector_type(8))) short short8;   // 8 bf16 = 4 VGPR
typedef __attribute__((ext_vector_type(16))) float f32x16;  // MFMA 32x32 acc

__device__ __forceinline__ float bf2f(unsigned short u) {
    union { unsigned int i; float f; } x; x.i = ((unsigned int)u) << 16; return x.f;
}
__device__ __forceinline__ unsigned int f2bf(float f) {
    union { float f; unsigned int i; } u; u.f = f;
    unsigned int r = u.i + 0x7FFFu + ((u.i >> 16) & 1u);
    return r >> 16;
}
__device__ __forceinline__ unsigned cvtpk(float a, float b) {
    unsigned r;
    asm("v_cvt_pk_bf16_f32 %0, %1, %2" : "=v"(r) : "v"(a), "v"(b));
    return r;
}
// Proven (r2/r8): build natural-k B fragments for a 32-row C block from 8
// pairwise-packed words (pk[i] = rows (2i,2i+1) in C reg order) + partner xchg.
__device__ __forceinline__ void bbuild(const unsigned pk[8], int lh,
                                       short8& B0, short8& B1) {
    unsigned xs[8];
    #pragma unroll
    for (int i = 0; i < 8; ++i) xs[i] = (unsigned)__shfl_xor((int)pk[i], 32);
    uint4 w0, w1;
    w0.x = lh ? xs[2] : pk[0]; w0.y = lh ? xs[3] : pk[1];
    w0.z = lh ? pk[2] : xs[0]; w0.w = lh ? pk[3] : xs[1];
    w1.x = lh ? xs[6] : pk[4]; w1.y = lh ? xs[7] : pk[5];
    w1.z = lh ? pk[6] : xs[4]; w1.w = lh ? pk[7] : xs[5];
    B0 = __builtin_bit_cast(short8, w0);
    B1 = __builtin_bit_cast(short8, w1);
}

// ---------------- K1: depthwise 3x3 conv + bias -> bf16; extra blocks: weight prep ----
__global__ __launch_bounds__(256) void k_dwconv(
    const float* __restrict__ xC, const float* __restrict__ dwW,
    const float* __restrict__ dwB, unsigned short* __restrict__ xdwb,
    const float* __restrict__ qkvW, const float* __restrict__ pw,
    const float* __restrict__ pwb, const float* __restrict__ gam,
    const float* __restrict__ bet, const float* __restrict__ mean,
    const float* __restrict__ var, const float* __restrict__ projW,
    const float* __restrict__ W1, const float* __restrict__ W2,
    const float* __restrict__ decW, const float* __restrict__ encW,
    unsigned short* __restrict__ qkvWT, unsigned short* __restrict__ weff,
    float* __restrict__ beff, unsigned short* __restrict__ projWTn,
    unsigned short* __restrict__ W1Tn, unsigned short* __restrict__ W2Tn,
    unsigned short* __restrict__ decTn, unsigned short* __restrict__ encWTn)
{
    int tid = threadIdx.x;
    int bid = blockIdx.x;
    if (bid >= 1024) {                  // -------- weight prep (plain transposes) -----
        int pid = (bid - 1024) * 256 + tid;
        if (pid < 12288) {              // qkvWT[o*64+c] = qkvW[c*192+o]
            int o = pid >> 6, c = pid & 63;
            qkvWT[pid] = (unsigned short)f2bf(qkvW[c * 192 + o]);
        } else if (pid < 28672) {       // weff[co*128+ci] = pw*scale
            int i = pid - 12288;
            int co = i >> 7;
            float sc = gam[co] * rsqrtf(var[co] + EPSF);
            weff[i] = (unsigned short)f2bf(pw[i] * sc);
        } else if (pid < 32768) {       // projWTn[m*64+c] = projW[c*64+m]
            int i = pid - 28672, m = i >> 6, c = i & 63;
            projWTn[i] = (unsigned short)f2bf(projW[c * 64 + m]);
        } else if (pid < 36864) {       // W1Tn[m*64+c] = W1[c*64+m]
            int i = pid - 32768, m = i >> 6, c = i & 63;
            W1Tn[i] = (unsigned short)f2bf(W1[c * 64 + m]);
        } else if (pid < 40960) {       // W2Tn[m*64+c] = W2[c*64+m]
            int i = pid - 36864, m = i >> 6, c = i & 63;
            W2Tn[i] = (unsigned short)f2bf(W2[c * 64 + m]);
        } else if (pid < 49152) {       // decTn[m*64+c] = decW[c*128+m], m<128
            int i = pid - 40960, m = i >> 6, c = i & 63;
            decTn[i] = (unsigned short)f2bf(decW[c * 128 + m]);
        } else if (pid < 57344) {       // encWTn[m*128+c] = encW[c*64+m], m<64
            int i = pid - 49152, m = i >> 7, c = i & 127;
            encWTn[i] = (unsigned short)f2bf(encW[c * 64 + m]);
        } else if (pid < 57472) {       // beff
            int i = pid - 57344;
            float sc = gam[i] * rsqrtf(var[i] + EPSF);
            beff[i] = (pwb[i] - mean[i]) * sc + bet[i];
        }
        return;
    }
    __shared__ float s_w[128 * 9];
    __shared__ float s_bias[128];
    for (int i = tid; i < 128 * 9; i += 256) s_w[i] = dwW[i];
    if (tid < 128) s_bias[tid] = dwB[tid];
    __syncthreads();
    int idx = bid * 256 + tid;
    int c4 = (idx & 31) * 4;
    int pg = idx >> 5;
    int t0 = pg * 4;
    int b = t0 >> 14, n = t0 & 16383;
    int row = n >> 7, col0 = n & 127;
    float vb[3][6][4];
    #pragma unroll
    for (int ky = 0; ky < 3; ++ky) {
        int r = row + ky - 1;
        #pragma unroll
        for (int cx = 0; cx < 6; ++cx) {
            int cl = col0 + cx - 1;
            if ((unsigned)r < 128u && (unsigned)cl < 128u) {
                *(float4*)&vb[ky][cx][0] =
                    *(const float4*)&xC[((size_t)(b << 14) + (r << 7) + cl) * 128 + c4];
            } else {
                vb[ky][cx][0] = 0.f; vb[ky][cx][1] = 0.f; vb[ky][cx][2] = 0.f; vb[ky][cx][3] = 0.f;
            }
        }
    }
    float acc[4][4];
    #pragma unroll
    for (int p = 0; p < 4; ++p)
        #pragma unroll
        for (int j = 0; j < 4; ++j) acc[p][j] = s_bias[c4 + j];
    #pragma unroll
    for (int ky = 0; ky < 3; ++ky)
        #pragma unroll
        for (int kx = 0; kx < 3; ++kx)
            #pragma unroll
            for (int j = 0; j < 4; ++j) {
                float w = s_w[(c4 + j) * 9 + ky * 3 + kx];
                #pragma unroll
                for (int p = 0; p < 4; ++p)
                    acc[p][j] = fmaf(w, vb[ky][p + kx][j], acc[p][j]);
            }
    #pragma unroll
    for (int p = 0; p < 4; ++p) {
        uint2 o;
        o.x = f2bf(acc[p][0]) | (f2bf(acc[p][1]) << 16);
        o.y = f2bf(acc[p][2]) | (f2bf(acc[p][3]) << 16);
        *(uint2*)&xdwb[((size_t)t0 + p) * 128 + c4] = o;
    }
}

// ---------------- K2: pointwise conv + BN + ReLU + residual via MFMA, x1 -> bf16 -----
__global__ __launch_bounds__(256) void k_pw(
    const unsigned short* __restrict__ xdwb, const float* __restrict__ xC,
    const unsigned short* __restrict__ weff, const float* __restrict__ beff,
    unsigned short* __restrict__ x1b)
{
    int tid = threadIdx.x;
    int wv = tid >> 6, lane = tid & 63, l31 = lane & 31, lh = lane >> 5;
    int wr = wv >> 1, wc = wv & 1;
    int T0 = blockIdx.x * 64;
    int ta = T0 + wr * 32 + l31;
    short8 af[8];
    #pragma unroll
    for (int ks = 0; ks < 8; ++ks)
        af[ks] = *(const short8*)&xdwb[(size_t)ta * 128 + ks * 16 + lh * 8];
    #pragma unroll
    for (int nt = 0; nt < 2; ++nt) {
        int co = wc * 64 + nt * 32 + l31;
        f32x16 acc = {};
        #pragma unroll
        for (int ks = 0; ks < 8; ++ks) {
            short8 bfr = *(const short8*)&weff[(size_t)co * 128 + ks * 16 + lh * 8];
            acc = __builtin_amdgcn_mfma_f32_32x32x16_bf16(af[ks], bfr, acc, 0, 0, 0);
        }
        float be = beff[co];
        #pragma unroll
        for (int r = 0; r < 16; ++r) {
            int tt = T0 + wr * 32 + (r & 3) + 8 * (r >> 2) + 4 * lh;
            float v = fmaxf(acc[r] + be, 0.f) + xC[(size_t)tt * 128 + co];
            x1b[(size_t)tt * 128 + co] = (unsigned short)f2bf(v);
        }
    }
}

// ---------------- K3: enc + pos + LayerNorm via MFMA (no LDS) -> wxb/wyb bf16 --------
// C_enc[co][tok]: A = encWTn (lane=co-row), B = x1b (s=0) or on-the-fly
// relu(xT)+xT (s=1). LN fully in-lane (32 regs + xor32).
__global__ __launch_bounds__(256) void k_enc(
    const unsigned short* __restrict__ x1b, const float* __restrict__ xT,
    const unsigned short* __restrict__ encWTn, const float* __restrict__ encb,
    const float* __restrict__ pos, const float* __restrict__ lng,
    const float* __restrict__ lnb,
    unsigned short* __restrict__ wxb, unsigned short* __restrict__ wyb)
{
    int tid = threadIdx.x;
    int wv = tid >> 6, l31 = tid & 31, lh = (tid >> 5) & 1;
    int s = blockIdx.y;
    int t = blockIdx.x * 128 + wv * 32 + l31;
    int n = t & 16383;
    short8 bf[8];
    if (s == 0) {
        #pragma unroll
        for (int ks = 0; ks < 8; ++ks)
            bf[ks] = *(const short8*)&x1b[(size_t)t * 128 + ks * 16 + lh * 8];
    } else {
        #pragma unroll
        for (int ks = 0; ks < 8; ++ks) {
            float4 f0 = *(const float4*)&xT[(size_t)t * 128 + ks * 16 + lh * 8];
            float4 f1 = *(const float4*)&xT[(size_t)t * 128 + ks * 16 + lh * 8 + 4];
            float r0 = f0.x > 0.f ? 2.f * f0.x : f0.x;
            float r1 = f0.y > 0.f ? 2.f * f0.y : f0.y;
            float r2 = f0.z > 0.f ? 2.f * f0.z : f0.z;
            float r3 = f0.w > 0.f ? 2.f * f0.w : f0.w;
            float r4 = f1.x > 0.f ? 2.f * f1.x : f1.x;
            float r5 = f1.y > 0.f ? 2.f * f1.y : f1.y;
            float r6 = f1.z > 0.f ? 2.f * f1.z : f1.z;
            float r7 = f1.w > 0.f ? 2.f * f1.w : f1.w;
            uint4 w;
            w.x = cvtpk(r0, r1); w.y = cvtpk(r2, r3);
            w.z = cvtpk(r4, r5); w.w = cvtpk(r6, r7);
            bf[ks] = __builtin_bit_cast(short8, w);
        }
    }
    f32x16 xm[2];
    #pragma unroll
    for (int ta = 0; ta < 2; ++ta) {
        f32x16 acc = {};
        #pragma unroll
        for (int ks = 0; ks < 8; ++ks) {
            short8 af = *(const short8*)&encWTn[(size_t)(ta * 32 + l31) * 128 + ks * 16 + lh * 8];
            acc = __builtin_amdgcn_mfma_f32_32x32x16_bf16(af, bf[ks], acc, 0, 0, 0);
        }
        #pragma unroll
        for (int g = 0; g < 4; ++g) {
            int c0 = ta * 32 + g * 8 + lh * 4;
            float4 eb = *(const float4*)&encb[c0];
            float4 pv = *(const float4*)&pos[(size_t)n * 64 + c0];
            acc[g * 4 + 0] += eb.x + pv.x;
            acc[g * 4 + 1] += eb.y + pv.y;
            acc[g * 4 + 2] += eb.z + pv.z;
            acc[g * 4 + 3] += eb.w + pv.w;
        }
        xm[ta] = acc;
    }
    float sm = 0.f, sq = 0.f;
    #pragma unroll
    for (int ta = 0; ta < 2; ++ta)
        #pragma unroll
        for (int r = 0; r < 16; ++r) { float v = xm[ta][r]; sm += v; sq += v * v; }
    sm += __shfl_xor(sm, 32); sq += __shfl_xor(sq, 32);
    float mu = sm * (1.f / 64.f);
    float rs = rsqrtf(fmaxf(sq * (1.f / 64.f) - mu * mu, 0.f) + EPSF);
    unsigned short* dstb = s ? wyb : wxb;
    #pragma unroll
    for (int ta = 0; ta < 2; ++ta)
        #pragma unroll
        for (int g = 0; g < 4; ++g) {
            int c0 = ta * 32 + g * 8 + lh * 4;
            float4 gg = *(const float4*)&lng[c0];
            float4 bb = *(const float4*)&lnb[c0];
            float u0 = (xm[ta][g * 4 + 0] - mu) * rs * gg.x + bb.x;
            float u1 = (xm[ta][g * 4 + 1] - mu) * rs * gg.y + bb.y;
            float u2 = (xm[ta][g * 4 + 2] - mu) * rs * gg.z + bb.z;
            float u3 = (xm[ta][g * 4 + 3] - mu) * rs * gg.w + bb.w;
            uint2 o; o.x = cvtpk(u0, u1); o.y = cvtpk(u2, u3);
            *(uint2*)&dstb[(size_t)t * 64 + c0] = o;
        }
}

// ---------------- K4: qkv GEMM via MFMA (no LDS), direct window-major bf16 out -------
__global__ __launch_bounds__(256) void k_qkv(
    const unsigned short* __restrict__ wxb, const unsigned short* __restrict__ wyb,
    const unsigned short* __restrict__ qkvWT,
    unsigned short* __restrict__ qk, unsigned short* __restrict__ vT)
{
    int tid = threadIdx.x;
    int wv = tid >> 6, lane = tid & 63, l31 = lane & 31, lh = lane >> 5;
    int s = blockIdx.y;
    int T0 = blockIdx.x * 128;
    int b = T0 >> 14;
    int row = (T0 & 16383) >> 7;
    const unsigned short* src = s ? wyb : wxb;
    int t = T0 + wv * 32 + l31;
    short8 bfr[4];
    #pragma unroll
    for (int ks = 0; ks < 4; ++ks)
        bfr[ks] = *(const short8*)&src[(size_t)t * 64 + ks * 16 + lh * 8];
    int cp = wv * 32 + l31;
    int wid = ((row >> 4) << 3) + (cp >> 4);
    int p = ((row & 15) << 4) + (cp & 15);
    size_t cb = (size_t)(s * 2 + b) * 512 + wid;     // + head*64 = combo
    #pragma unroll
    for (int nt = 0; nt < 6; ++nt) {
        f32x16 acc = {};
        #pragma unroll
        for (int ks = 0; ks < 4; ++ks) {
            short8 afr = *(const short8*)&qkvWT[(size_t)(nt * 32 + l31) * 64 + ks * 16 + lh * 8];
            acc = __builtin_amdgcn_mfma_f32_32x32x16_bf16(afr, bfr[ks], acc, 0, 0, 0);
        }
        if (nt < 4) {
            const float scl = nt < 2 ? 1.f : KSCL;
            const int sec = nt < 2 ? 0 : 1;
            #pragma unroll
            for (int g = 0; g < 4; ++g) {
                int head = (nt & 1) * 4 + g;
                unsigned short* rec = qk + (cb + head * 64) * 4096;
                float f0 = acc[4 * g + 0] * scl, f1 = acc[4 * g + 1] * scl;
                float f2 = acc[4 * g + 2] * scl, f3 = acc[4 * g + 3] * scl;
                unsigned u01 = cvtpk(f0, f1), u23 = cvtpk(f2, f3);
                int off = p * 16 + sec * 8 + 4 * lh;
                *(unsigned*)(rec + off) = u01;
                *(unsigned*)(rec + off + 2) = u23;
            }
        } else {
            #pragma unroll
            for (int g = 0; g < 4; ++g) {
                int head = (nt - 4) * 4 + g;
                unsigned short* vrec = vT + (cb + head * 64) * 2048;
                int d0 = 4 * lh;
                vrec[(d0 + 0) * 256 + p] = (unsigned short)f2bf(acc[4 * g + 0]);
                vrec[(d0 + 1) * 256 + p] = (unsigned short)f2bf(acc[4 * g + 1]);
                vrec[(d0 + 2) * 256 + p] = (unsigned short)f2bf(acc[4 * g + 2]);
                vrec[(d0 + 3) * 256 + p] = (unsigned short)f2bf(acc[4 * g + 3]);
            }
        }
    }
}

// ---------------- K5: MFMA dual-stream windowed attention (proven, fp32 out) ---------
__global__ __launch_bounds__(256) void k_attn(
    const unsigned short* __restrict__ qk, const unsigned short* __restrict__ vT,
    float* __restrict__ ox, float* __restrict__ oy)
{
    int tid = threadIdx.x;
    int wave = tid >> 6, lane = tid & 63;
    int lh = lane >> 5, l31 = lane & 31;
    int bx = blockIdx.x;
    int s = bx >> 10;
    int r = bx & 1023;
    int head = (r >> 6) & 7, wid = r & 63, b = r >> 9;
    const unsigned short* qbase = qk + ((size_t)s * 1024 + r) * 4096;
    const unsigned short* vbase = vT + ((size_t)(s ^ 1) * 1024 + r) * 2048;  // cross v

    short8 qf[2];
    #pragma unroll
    for (int qt = 0; qt < 2; ++qt) {
        uint4 v = {0u, 0u, 0u, 0u};
        if (lh == 0) v = *(const uint4*)(qbase + (size_t)(wave * 64 + qt * 32 + l31) * 16);
        qf[qt] = __builtin_bit_cast(short8, v);
    }
    f32x16 acc[2];
    #pragma unroll
    for (int qt = 0; qt < 2; ++qt) acc[qt] = (f32x16){};
    const unsigned ONES = 0x3F803F80u;

    for (int jt = 0; jt < 8; ++jt) {
        uint4 kv = {0u, 0u, 0u, 0u};
        if (lh == 0) kv = *(const uint4*)(qbase + (size_t)(jt * 32 + l31) * 16 + 8);
        short8 kf = __builtin_bit_cast(short8, kv);
        uint2 a0 = {ONES, ONES}, a1 = {ONES, ONES}, a2 = {ONES, ONES}, a3 = {ONES, ONES};
        if (l31 < 8) {
            const unsigned short* vp = vbase + l31 * 256 + jt * 32 + lh * 4;
            a0 = *(const uint2*)vp;
            a1 = *(const uint2*)(vp + 8);
            a2 = *(const uint2*)(vp + 16);
            a3 = *(const uint2*)(vp + 24);
        }
        uint4 vaw = {a0.x, a0.y, a1.x, a1.y};
        uint4 vbw = {a2.x, a2.y, a3.x, a3.y};
        short8 vf0 = __builtin_bit_cast(short8, vaw);
        short8 vf1 = __builtin_bit_cast(short8, vbw);
        #pragma unroll
        for (int qt = 0; qt < 2; ++qt) {
            f32x16 c = __builtin_amdgcn_mfma_f32_32x32x16_bf16(kf, qf[qt], (f32x16){}, 0, 0, 0);
            float p[16];
            #pragma unroll
            for (int i = 0; i < 16; ++i) p[i] = EXP2(c[i]);
            unsigned pk[8];
            #pragma unroll
            for (int i = 0; i < 8; ++i) pk[i] = cvtpk(p[2 * i], p[2 * i + 1]);
            uint4 bw0 = {pk[0], pk[1], pk[2], pk[3]};
            uint4 bw1 = {pk[4], pk[5], pk[6], pk[7]};
            short8 B0 = __builtin_bit_cast(short8, bw0);
            short8 B1 = __builtin_bit_cast(short8, bw1);
            acc[qt] = __builtin_amdgcn_mfma_f32_32x32x16_bf16(vf0, B0, acc[qt], 0, 0, 0);
            acc[qt] = __builtin_amdgcn_mfma_f32_32x32x16_bf16(vf1, B1, acc[qt], 0, 0, 0);
        }
    }
    float* dst = s ? oy : ox;
    #pragma unroll
    for (int qt = 0; qt < 2; ++qt) {
        float inv = 1.f / acc[qt][4];
        int p = wave * 64 + qt * 32 + l31;
        int orow = (wid >> 3) * 16 + (p >> 4);
        int ocol = (wid & 7) * 16 + (p & 15);
        size_t t = (size_t)b * 16384 + orow * 128 + ocol;
        float4 o;
        o.x = acc[qt][0] * inv; o.y = acc[qt][1] * inv;
        o.z = acc[qt][2] * inv; o.w = acc[qt][3] * inv;
        *(float4*)&dst[t * 64 + head * 8 + lh * 4] = o;
    }
}

// ---------------- K6: proj + residual + LN + FFN + dec (bf16 residual input) ---------
__global__ __launch_bounds__(256) void k_fusedec(
    const float* __restrict__ ox, const float* __restrict__ oy,
    const unsigned short* __restrict__ wxb, const unsigned short* __restrict__ wyb,
    const unsigned short* __restrict__ projWTn, const float* __restrict__ projb,
    const unsigned short* __restrict__ W1Tn, const float* __restrict__ b1,
    const unsigned short* __restrict__ W2Tn, const float* __restrict__ b2,
    const unsigned short* __restrict__ decTn, const float* __restrict__ decb,
    const float* __restrict__ lng, const float* __restrict__ lnb,
    float* __restrict__ out)
{
    int tid = threadIdx.x;
    int wv = tid >> 6, l31 = tid & 31, lh = (tid >> 5) & 1;
    int t = blockIdx.x * 128 + wv * 32 + l31;
    f32x16 zacc[2];
    zacc[0] = (f32x16){}; zacc[1] = (f32x16){};
    #pragma unroll 1
    for (int s = 0; s < 2; ++s) {
        const float* osrc = s ? oy : ox;
        const unsigned short* wsrc = s ? wyb : wxb;
        // B for GEMM1 from fp32 o, natural channel order
        short8 bo[4];
        #pragma unroll
        for (int kap = 0; kap < 4; ++kap) {
            float4 f0 = *(const float4*)&osrc[(size_t)t * 64 + kap * 16 + lh * 8];
            float4 f1 = *(const float4*)&osrc[(size_t)t * 64 + kap * 16 + lh * 8 + 4];
            uint4 w;
            w.x = cvtpk(f0.x, f0.y); w.y = cvtpk(f0.z, f0.w);
            w.z = cvtpk(f1.x, f1.y); w.w = cvtpk(f1.z, f1.w);
            bo[kap] = __builtin_bit_cast(short8, w);
        }
        // GEMM1: xm[m][tok] = projW^T @ o + projb + w
        f32x16 a1[2];
        #pragma unroll
        for (int ta = 0; ta < 2; ++ta) {
            f32x16 acc = {};
            #pragma unroll
            for (int kap = 0; kap < 4; ++kap) {
                short8 af = *(const short8*)&projWTn[(size_t)(ta * 32 + l31) * 64 + kap * 16 + lh * 8];
                acc = __builtin_amdgcn_mfma_f32_32x32x16_bf16(af, bo[kap], acc, 0, 0, 0);
            }
            #pragma unroll
            for (int g = 0; g < 4; ++g) {
                int c0 = ta * 32 + g * 8 + lh * 4;
                float4 pb = *(const float4*)&projb[c0];
                uint2 wr2 = *(const uint2*)&wsrc[(size_t)t * 64 + c0];
                acc[g * 4 + 0] += pb.x + bf2f((unsigned short)(wr2.x & 0xffffu));
                acc[g * 4 + 1] += pb.y + bf2f((unsigned short)(wr2.x >> 16));
                acc[g * 4 + 2] += pb.z + bf2f((unsigned short)(wr2.y & 0xffffu));
                acc[g * 4 + 3] += pb.w + bf2f((unsigned short)(wr2.y >> 16));
            }
            a1[ta] = acc;
        }
        // LN(xm)
        float sm = 0.f, sq = 0.f;
        #pragma unroll
        for (int ta = 0; ta < 2; ++ta)
            #pragma unroll
            for (int r = 0; r < 16; ++r) { float v = a1[ta][r]; sm += v; sq += v * v; }
        sm += __shfl_xor(sm, 32); sq += __shfl_xor(sq, 32);
        float mu = sm * (1.f / 64.f);
        float rs = rsqrtf(fmaxf(sq * (1.f / 64.f) - mu * mu, 0.f) + EPSF);
        unsigned pku[2][8];
        #pragma unroll
        for (int ta = 0; ta < 2; ++ta)
            #pragma unroll
            for (int g = 0; g < 4; ++g) {
                int c0 = ta * 32 + g * 8 + lh * 4;
                float4 gg = *(const float4*)&lng[c0];
                float4 bb = *(const float4*)&lnb[c0];
                float u0 = (a1[ta][g * 4 + 0] - mu) * rs * gg.x + bb.x;
                float u1 = (a1[ta][g * 4 + 1] - mu) * rs * gg.y + bb.y;
                float u2 = (a1[ta][g * 4 + 2] - mu) * rs * gg.z + bb.z;
                float u3 = (a1[ta][g * 4 + 3] - mu) * rs * gg.w + bb.w;
                pku[ta][g * 2]     = cvtpk(u0, u1);
                pku[ta][g * 2 + 1] = cvtpk(u2, u3);
            }
        short8 Bu[4];
        bbuild(pku[0], lh, Bu[0], Bu[1]);
        bbuild(pku[1], lh, Bu[2], Bu[3]);
        // GEMM2: h = relu(W1^T @ u + b1)
        unsigned pkh[2][8];
        #pragma unroll
        for (int th = 0; th < 2; ++th) {
            f32x16 acc = {};
            #pragma unroll
            for (int kap = 0; kap < 4; ++kap) {
                short8 af = *(const short8*)&W1Tn[(size_t)(th * 32 + l31) * 64 + kap * 16 + lh * 8];
                acc = __builtin_amdgcn_mfma_f32_32x32x16_bf16(af, Bu[kap], acc, 0, 0, 0);
            }
            #pragma unroll
            for (int g = 0; g < 4; ++g) {
                int c0 = th * 32 + g * 8 + lh * 4;
                float4 bb = *(const float4*)&b1[c0];
                float h0 = fmaxf(acc[g * 4 + 0] + bb.x, 0.f);
                float h1 = fmaxf(acc[g * 4 + 1] + bb.y, 0.f);
                float h2 = fmaxf(acc[g * 4 + 2] + bb.z, 0.f);
                float h3 = fmaxf(acc[g * 4 + 3] + bb.w, 0.f);
                pkh[th][g * 2]     = cvtpk(h0, h1);
                pkh[th][g * 2 + 1] = cvtpk(h2, h3);
            }
        }
        short8 Bh[4];
        bbuild(pkh[0], lh, Bh[0], Bh[1]);
        bbuild(pkh[1], lh, Bh[2], Bh[3]);
        // GEMM3: xf = xm + b2 + W2^T @ h ; z += xf
        #pragma unroll
        for (int ta = 0; ta < 2; ++ta) {
            f32x16 a3 = a1[ta];
            #pragma unroll
            for (int g = 0; g < 4; ++g) {
                int c0 = ta * 32 + g * 8 + lh * 4;
                float4 bb = *(const float4*)&b2[c0];
                a3[g * 4 + 0] += bb.x; a3[g * 4 + 1] += bb.y;
                a3[g * 4 + 2] += bb.z; a3[g * 4 + 3] += bb.w;
            }
            #pragma unroll
            for (int kap = 0; kap < 4; ++kap) {
                short8 af = *(const short8*)&W2Tn[(size_t)(ta * 32 + l31) * 64 + kap * 16 + lh * 8];
                a3 = __builtin_amdgcn_mfma_f32_32x32x16_bf16(af, Bh[kap], a3, 0, 0, 0);
            }
            zacc[ta] += a3;
        }
    }
    // dec: out[m][tok] = decW^T @ z + 2*decb
    unsigned pkz[2][8];
    #pragma unroll
    for (int ta = 0; ta < 2; ++ta)
        #pragma unroll
        for (int g = 0; g < 4; ++g) {
            pkz[ta][g * 2]     = cvtpk(zacc[ta][g * 4 + 0], zacc[ta][g * 4 + 1]);
            pkz[ta][g * 2 + 1] = cvtpk(zacc[ta][g * 4 + 2], zacc[ta][g * 4 + 3]);
        }
    short8 Bz[4];
    bbuild(pkz[0], lh, Bz[0], Bz[1]);
    bbuild(pkz[1], lh, Bz[2], Bz[3]);
    #pragma unroll
    for (int mu4 = 0; mu4 < 4; ++mu4) {
        f32x16 a4 = {};
        #pragma unroll
        for (int g = 0; g < 4; ++g) {
            int c0 = mu4 * 32 + g * 8 + lh * 4;
            float4 db = *(const float4*)&decb[c0];
            a4[g * 4 + 0] = 2.f * db.x; a4[g * 4 + 1] = 2.f * db.y;
            a4[g * 4 + 2] = 2.f * db.z; a4[g * 4 + 3] = 2.f * db.w;
        }
        #pragma unroll
        for (int kap = 0; kap < 4; ++kap) {
            short8 af = *(const short8*)&decTn[(size_t)(mu4 * 32 + l31) * 64 + kap * 16 + lh * 8];
            a4 = __builtin_amdgcn_mfma_f32_32x32x16_bf16(af, Bz[kap], a4, 0, 0, 0);
        }
        #pragma unroll
        for (int g = 0; g < 4; ++g) {
            int c0 = mu4 * 32 + g * 8 + lh * 4;
            float4 o;
            o.x = a4[g * 4 + 0]; o.y = a4[g * 4 + 1];
            o.z = a4[g * 4 + 2]; o.w = a4[g * 4 + 3];
            *(float4*)&out[(size_t)t * 128 + c0] = o;
        }
    }
}

extern "C" void kernel_launch(void* const* d_in, const int* in_sizes, int n_in,
                              void* d_out, int out_size, void* d_ws, size_t ws_size,
                              hipStream_t stream) {
    const float* x_C   = (const float*)d_in[0];
    const float* x_T   = (const float*)d_in[1];
    const float* dwW   = (const float*)d_in[2];
    const float* dwB   = (const float*)d_in[3];
    const float* pw    = (const float*)d_in[4];
    const float* pwb   = (const float*)d_in[5];
    const float* gam   = (const float*)d_in[6];
    const float* bet   = (const float*)d_in[7];
    const float* mean  = (const float*)d_in[8];
    const float* var   = (const float*)d_in[9];
    const float* encW  = (const float*)d_in[10];
    const float* encb  = (const float*)d_in[11];
    const float* pos   = (const float*)d_in[12];
    const float* lng   = (const float*)d_in[13];
    const float* lnb   = (const float*)d_in[14];
    const float* qkvW  = (const float*)d_in[15];
    const float* projW = (const float*)d_in[16];
    const float* projb = (const float*)d_in[17];
    const float* W1    = (const float*)d_in[18];
    const float* b1    = (const float*)d_in[19];
    const float* W2    = (const float*)d_in[20];
    const float* b2    = (const float*)d_in[21];
    const float* decW  = (const float*)d_in[22];
    const float* decb  = (const float*)d_in[23];
    float* out = (float*)d_out;

    float* ws = (float*)d_ws;
    unsigned short* xdwb = (unsigned short*)ws;                 // 4,194,304 bf16
    unsigned short* x1b  = (unsigned short*)(ws + 2097152);     // 4,194,304 bf16
    unsigned short* qkb  = (unsigned short*)(ws + 4194304);     // 8,388,608 bf16
    unsigned short* vTb  = (unsigned short*)(ws + 8388608);     // 4,194,304 bf16
    unsigned short* wxb  = (unsigned short*)(ws + 10485760);    // 2,097,152 bf16
    unsigned short* wyb  = (unsigned short*)(ws + 11534336);    // 2,097,152 bf16
    float* ox   = ws + 12582912;                                // 2,097,152 f
    float* oy   = ws + 14680064;                                // 2,097,152 f
    unsigned short* qkvWT   = (unsigned short*)(ws + 16777216); // 12,288 bf16
    unsigned short* weff    = (unsigned short*)(ws + 16783360); // 16,384 bf16
    float*          beff    = ws + 16791552;                    // 128 f
    unsigned short* projWTn = (unsigned short*)(ws + 16791680); // 4,096 bf16
    unsigned short* W1Tn    = (unsigned short*)(ws + 16793728); // 4,096 bf16
    unsigned short* W2Tn    = (unsigned short*)(ws + 16795776); // 4,096 bf16
    unsigned short* decTn   = (unsigned short*)(ws + 16797824); // 8,192 bf16
    unsigned short* encWTn  = (unsigned short*)(ws + 16801920); // 8,192 bf16

    k_dwconv<<<1249, 256, 0, stream>>>(x_C, dwW, dwB, xdwb, qkvW, pw, pwb,
                                       gam, bet, mean, var, projW, W1, W2, decW,
                                       encW, qkvWT, weff, beff, projWTn,
                                       W1Tn, W2Tn, decTn, encWTn);
    k_pw<<<512, 256, 0, stream>>>(xdwb, x_C, weff, beff, x1b);
    k_enc<<<dim3(256, 2), 256, 0, stream>>>(x1b, x_T, encWTn, encb, pos,
                                            lng, lnb, wxb, wyb);
    k_qkv<<<dim3(256, 2), 256, 0, stream>>>(wxb, wyb, qkvWT, qkb, vTb);
    k_attn<<<2048, 256, 0, stream>>>(qkb, vTb, ox, oy);
    k_fusedec<<<256, 256, 0, stream>>>(ox, oy, wxb, wyb, projWTn, projb,
                                       W1Tn, b1, W2Tn, b2, decTn, decb,
                                       lng, lnb, out);
}

// Round 10
// 95.668 us; speedup vs baseline: 6.8355x; 1.0536x over previous
//
#include <hip/hip_runtime.h>
#include <hip/hip_bf16.h>
#include <math.h>

#define EPSF 1e-5f
// scale (1/sqrt(8)) * log2(e), folded into k at qkv time
#define KSCL 0.51010090329771713f

#if __has_builtin(__builtin_amdgcn_exp2f)
#define EXP2(x) __builtin_amdgcn_exp2f(x)
#else
#define EXP2(x) exp2f(x)
#endif

typedef __attribute__((ext_vector_type(8))) short short8;   // 8 bf16 = 4 VGPR
typedef __attribute__((ext_vector_type(16))) float f32x16;  // MFMA 32x32 acc

__device__ __forceinline__ float bf2f(unsigned short u) {
    union { unsigned int i; float f; } x; x.i = ((unsigned int)u) << 16; return x.f;
}
__device__ __forceinline__ unsigned int f2bf(float f) {
    union { float f; unsigned int i; } u; u.f = f;
    unsigned int r = u.i + 0x7FFFu + ((u.i >> 16) & 1u);
    return r >> 16;
}
__device__ __forceinline__ unsigned cvtpk(float a, float b) {
    unsigned r;
    asm("v_cvt_pk_bf16_f32 %0, %1, %2" : "=v"(r) : "v"(a), "v"(b));
    return r;
}
// Proven (r2/r8): build natural-k B fragments for a 32-row C block from 8
// pairwise-packed words (pk[i] = rows (2i,2i+1) in C reg order) + partner xchg.
__device__ __forceinline__ void bbuild(const unsigned pk[8], int lh,
                                       short8& B0, short8& B1) {
    unsigned xs[8];
    #pragma unroll
    for (int i = 0; i < 8; ++i) xs[i] = (unsigned)__shfl_xor((int)pk[i], 32);
    uint4 w0, w1;
    w0.x = lh ? xs[2] : pk[0]; w0.y = lh ? xs[3] : pk[1];
    w0.z = lh ? pk[2] : xs[0]; w0.w = lh ? pk[3] : xs[1];
    w1.x = lh ? xs[6] : pk[4]; w1.y = lh ? xs[7] : pk[5];
    w1.z = lh ? pk[6] : xs[4]; w1.w = lh ? pk[7] : xs[5];
    B0 = __builtin_bit_cast(short8, w0);
    B1 = __builtin_bit_cast(short8, w1);
}

// ---------------- K1: depthwise 3x3 conv + bias -> bf16; extra blocks: weight prep ----
__global__ __launch_bounds__(256) void k_dwconv(
    const float* __restrict__ xC, const float* __restrict__ dwW,
    const float* __restrict__ dwB, unsigned short* __restrict__ xdwb,
    const float* __restrict__ qkvW, const float* __restrict__ pw,
    const float* __restrict__ pwb, const float* __restrict__ gam,
    const float* __restrict__ bet, const float* __restrict__ mean,
    const float* __restrict__ var, const float* __restrict__ projW,
    const float* __restrict__ W1, const float* __restrict__ W2,
    const float* __restrict__ decW, const float* __restrict__ encW,
    unsigned short* __restrict__ qkvWT, unsigned short* __restrict__ weff,
    float* __restrict__ beff, unsigned short* __restrict__ projWTn,
    unsigned short* __restrict__ W1Tn, unsigned short* __restrict__ W2Tn,
    unsigned short* __restrict__ decTn, unsigned short* __restrict__ encWTn)
{
    int tid = threadIdx.x;
    int bid = blockIdx.x;
    if (bid >= 1024) {                  // -------- weight prep (plain transposes) -----
        int pid = (bid - 1024) * 256 + tid;
        if (pid < 12288) {              // qkvWT[o*64+c] = qkvW[c*192+o]
            int o = pid >> 6, c = pid & 63;
            qkvWT[pid] = (unsigned short)f2bf(qkvW[c * 192 + o]);
        } else if (pid < 28672) {       // weff[co*128+ci] = pw*scale
            int i = pid - 12288;
            int co = i >> 7;
            float sc = gam[co] * rsqrtf(var[co] + EPSF);
            weff[i] = (unsigned short)f2bf(pw[i] * sc);
        } else if (pid < 32768) {       // projWTn[m*64+c] = projW[c*64+m]
            int i = pid - 28672, m = i >> 6, c = i & 63;
            projWTn[i] = (unsigned short)f2bf(projW[c * 64 + m]);
        } else if (pid < 36864) {       // W1Tn[m*64+c] = W1[c*64+m]
            int i = pid - 32768, m = i >> 6, c = i & 63;
            W1Tn[i] = (unsigned short)f2bf(W1[c * 64 + m]);
        } else if (pid < 40960) {       // W2Tn[m*64+c] = W2[c*64+m]
            int i = pid - 36864, m = i >> 6, c = i & 63;
            W2Tn[i] = (unsigned short)f2bf(W2[c * 64 + m]);
        } else if (pid < 49152) {       // decTn[m*64+c] = decW[c*128+m], m<128
            int i = pid - 40960, m = i >> 6, c = i & 63;
            decTn[i] = (unsigned short)f2bf(decW[c * 128 + m]);
        } else if (pid < 57344) {       // encWTn[m*128+c] = encW[c*64+m], m<64
            int i = pid - 49152, m = i >> 7, c = i & 127;
            encWTn[i] = (unsigned short)f2bf(encW[c * 64 + m]);
        } else if (pid < 57472) {       // beff
            int i = pid - 57344;
            float sc = gam[i] * rsqrtf(var[i] + EPSF);
            beff[i] = (pwb[i] - mean[i]) * sc + bet[i];
        }
        return;
    }
    __shared__ float s_w[128 * 9];
    __shared__ float s_bias[128];
    for (int i = tid; i < 128 * 9; i += 256) s_w[i] = dwW[i];
    if (tid < 128) s_bias[tid] = dwB[tid];
    __syncthreads();
    int idx = bid * 256 + tid;
    int c4 = (idx & 31) * 4;
    int pg = idx >> 5;
    int t0 = pg * 4;
    int b = t0 >> 14, n = t0 & 16383;
    int row = n >> 7, col0 = n & 127;
    float vb[3][6][4];
    #pragma unroll
    for (int ky = 0; ky < 3; ++ky) {
        int r = row + ky - 1;
        #pragma unroll
        for (int cx = 0; cx < 6; ++cx) {
            int cl = col0 + cx - 1;
            if ((unsigned)r < 128u && (unsigned)cl < 128u) {
                *(float4*)&vb[ky][cx][0] =
                    *(const float4*)&xC[((size_t)(b << 14) + (r << 7) + cl) * 128 + c4];
            } else {
                vb[ky][cx][0] = 0.f; vb[ky][cx][1] = 0.f; vb[ky][cx][2] = 0.f; vb[ky][cx][3] = 0.f;
            }
        }
    }
    float acc[4][4];
    #pragma unroll
    for (int p = 0; p < 4; ++p)
        #pragma unroll
        for (int j = 0; j < 4; ++j) acc[p][j] = s_bias[c4 + j];
    #pragma unroll
    for (int ky = 0; ky < 3; ++ky)
        #pragma unroll
        for (int kx = 0; kx < 3; ++kx)
            #pragma unroll
            for (int j = 0; j < 4; ++j) {
                float w = s_w[(c4 + j) * 9 + ky * 3 + kx];
                #pragma unroll
                for (int p = 0; p < 4; ++p)
                    acc[p][j] = fmaf(w, vb[ky][p + kx][j], acc[p][j]);
            }
    #pragma unroll
    for (int p = 0; p < 4; ++p) {
        uint2 o;
        o.x = f2bf(acc[p][0]) | (f2bf(acc[p][1]) << 16);
        o.y = f2bf(acc[p][2]) | (f2bf(acc[p][3]) << 16);
        *(uint2*)&xdwb[((size_t)t0 + p) * 128 + c4] = o;
    }
}

// ---------------- K2: pointwise conv + BN + ReLU + residual via MFMA, x1 -> bf16 -----
__global__ __launch_bounds__(256) void k_pw(
    const unsigned short* __restrict__ xdwb, const float* __restrict__ xC,
    const unsigned short* __restrict__ weff, const float* __restrict__ beff,
    unsigned short* __restrict__ x1b)
{
    int tid = threadIdx.x;
    int wv = tid >> 6, lane = tid & 63, l31 = lane & 31, lh = lane >> 5;
    int wr = wv >> 1, wc = wv & 1;
    int T0 = blockIdx.x * 64;
    int ta = T0 + wr * 32 + l31;
    short8 af[8];
    #pragma unroll
    for (int ks = 0; ks < 8; ++ks)
        af[ks] = *(const short8*)&xdwb[(size_t)ta * 128 + ks * 16 + lh * 8];
    #pragma unroll
    for (int nt = 0; nt < 2; ++nt) {
        int co = wc * 64 + nt * 32 + l31;
        f32x16 acc = {};
        #pragma unroll
        for (int ks = 0; ks < 8; ++ks) {
            short8 bfr = *(const short8*)&weff[(size_t)co * 128 + ks * 16 + lh * 8];
            acc = __builtin_amdgcn_mfma_f32_32x32x16_bf16(af[ks], bfr, acc, 0, 0, 0);
        }
        float be = beff[co];
        #pragma unroll
        for (int r = 0; r < 16; ++r) {
            int tt = T0 + wr * 32 + (r & 3) + 8 * (r >> 2) + 4 * lh;
            float v = fmaxf(acc[r] + be, 0.f) + xC[(size_t)tt * 128 + co];
            x1b[(size_t)tt * 128 + co] = (unsigned short)f2bf(v);
        }
    }
}

// ---------------- K3: enc + pos + LN + qkv fused (no LDS) -------------------------
// C_enc[co][tok] (lane=token) -> LN in-lane -> wxb/wyb store + bbuild -> Bu ->
// qkv GEMM (A=qkvWT) -> qk/vT window-major bf16.
__global__ __launch_bounds__(256) void k_encqkv(
    const unsigned short* __restrict__ x1b, const float* __restrict__ xT,
    const unsigned short* __restrict__ encWTn, const float* __restrict__ encb,
    const float* __restrict__ pos, const float* __restrict__ lng,
    const float* __restrict__ lnb, const unsigned short* __restrict__ qkvWT,
    unsigned short* __restrict__ wxb, unsigned short* __restrict__ wyb,
    unsigned short* __restrict__ qk, unsigned short* __restrict__ vT)
{
    int tid = threadIdx.x;
    int wv = tid >> 6, l31 = tid & 31, lh = (tid >> 5) & 1;
    int s = blockIdx.y;
    int T0 = blockIdx.x * 128;
    int t = T0 + wv * 32 + l31;
    int n = t & 16383;
    short8 bf[8];
    if (s == 0) {
        #pragma unroll
        for (int ks = 0; ks < 8; ++ks)
            bf[ks] = *(const short8*)&x1b[(size_t)t * 128 + ks * 16 + lh * 8];
    } else {
        #pragma unroll
        for (int ks = 0; ks < 8; ++ks) {
            float4 f0 = *(const float4*)&xT[(size_t)t * 128 + ks * 16 + lh * 8];
            float4 f1 = *(const float4*)&xT[(size_t)t * 128 + ks * 16 + lh * 8 + 4];
            float r0 = f0.x > 0.f ? 2.f * f0.x : f0.x;
            float r1 = f0.y > 0.f ? 2.f * f0.y : f0.y;
            float r2 = f0.z > 0.f ? 2.f * f0.z : f0.z;
            float r3 = f0.w > 0.f ? 2.f * f0.w : f0.w;
            float r4 = f1.x > 0.f ? 2.f * f1.x : f1.x;
            float r5 = f1.y > 0.f ? 2.f * f1.y : f1.y;
            float r6 = f1.z > 0.f ? 2.f * f1.z : f1.z;
            float r7 = f1.w > 0.f ? 2.f * f1.w : f1.w;
            uint4 w;
            w.x = cvtpk(r0, r1); w.y = cvtpk(r2, r3);
            w.z = cvtpk(r4, r5); w.w = cvtpk(r6, r7);
            bf[ks] = __builtin_bit_cast(short8, w);
        }
    }
    f32x16 xm[2];
    #pragma unroll
    for (int ta = 0; ta < 2; ++ta) {
        f32x16 acc = {};
        #pragma unroll
        for (int ks = 0; ks < 8; ++ks) {
            short8 af = *(const short8*)&encWTn[(size_t)(ta * 32 + l31) * 128 + ks * 16 + lh * 8];
            acc = __builtin_amdgcn_mfma_f32_32x32x16_bf16(af, bf[ks], acc, 0, 0, 0);
        }
        #pragma unroll
        for (int g = 0; g < 4; ++g) {
            int c0 = ta * 32 + g * 8 + lh * 4;
            float4 eb = *(const float4*)&encb[c0];
            float4 pv = *(const float4*)&pos[(size_t)n * 64 + c0];
            acc[g * 4 + 0] += eb.x + pv.x;
            acc[g * 4 + 1] += eb.y + pv.y;
            acc[g * 4 + 2] += eb.z + pv.z;
            acc[g * 4 + 3] += eb.w + pv.w;
        }
        xm[ta] = acc;
    }
    float sm = 0.f, sq = 0.f;
    #pragma unroll
    for (int ta = 0; ta < 2; ++ta)
        #pragma unroll
        for (int r = 0; r < 16; ++r) { float v = xm[ta][r]; sm += v; sq += v * v; }
    sm += __shfl_xor(sm, 32); sq += __shfl_xor(sq, 32);
    float mu = sm * (1.f / 64.f);
    float rs = rsqrtf(fmaxf(sq * (1.f / 64.f) - mu * mu, 0.f) + EPSF);
    unsigned short* dstb = s ? wyb : wxb;
    unsigned pku[2][8];
    #pragma unroll
    for (int ta = 0; ta < 2; ++ta)
        #pragma unroll
        for (int g = 0; g < 4; ++g) {
            int c0 = ta * 32 + g * 8 + lh * 4;
            float4 gg = *(const float4*)&lng[c0];
            float4 bb = *(const float4*)&lnb[c0];
            float u0 = (xm[ta][g * 4 + 0] - mu) * rs * gg.x + bb.x;
            float u1 = (xm[ta][g * 4 + 1] - mu) * rs * gg.y + bb.y;
            float u2 = (xm[ta][g * 4 + 2] - mu) * rs * gg.z + bb.z;
            float u3 = (xm[ta][g * 4 + 3] - mu) * rs * gg.w + bb.w;
            pku[ta][g * 2]     = cvtpk(u0, u1);
            pku[ta][g * 2 + 1] = cvtpk(u2, u3);
            uint2 o; o.x = pku[ta][g * 2]; o.y = pku[ta][g * 2 + 1];
            *(uint2*)&dstb[(size_t)t * 64 + c0] = o;
        }
    short8 Bu[4];
    bbuild(pku[0], lh, Bu[0], Bu[1]);
    bbuild(pku[1], lh, Bu[2], Bu[3]);
    // ---- qkv GEMM (A = qkvWT rows, B = Bu) + window-major epilogue ----
    int b = T0 >> 14;
    int row = (T0 & 16383) >> 7;
    int cp = wv * 32 + l31;
    int wid = ((row >> 4) << 3) + (cp >> 4);
    int p = ((row & 15) << 4) + (cp & 15);
    size_t cb = (size_t)(s * 2 + b) * 512 + wid;     // + head*64 = combo
    #pragma unroll
    for (int nt = 0; nt < 6; ++nt) {
        f32x16 acc = {};
        #pragma unroll
        for (int ks = 0; ks < 4; ++ks) {
            short8 afr = *(const short8*)&qkvWT[(size_t)(nt * 32 + l31) * 64 + ks * 16 + lh * 8];
            acc = __builtin_amdgcn_mfma_f32_32x32x16_bf16(afr, Bu[ks], acc, 0, 0, 0);
        }
        if (nt < 4) {
            const float scl = nt < 2 ? 1.f : KSCL;
            const int sec = nt < 2 ? 0 : 1;
            #pragma unroll
            for (int g = 0; g < 4; ++g) {
                int head = (nt & 1) * 4 + g;
                unsigned short* rec = qk + (cb + head * 64) * 4096;
                float f0 = acc[4 * g + 0] * scl, f1 = acc[4 * g + 1] * scl;
                float f2 = acc[4 * g + 2] * scl, f3 = acc[4 * g + 3] * scl;
                unsigned u01 = cvtpk(f0, f1), u23 = cvtpk(f2, f3);
                int off = p * 16 + sec * 8 + 4 * lh;
                *(unsigned*)(rec + off) = u01;
                *(unsigned*)(rec + off + 2) = u23;
            }
        } else {
            #pragma unroll
            for (int g = 0; g < 4; ++g) {
                int head = (nt - 4) * 4 + g;
                unsigned short* vrec = vT + (cb + head * 64) * 2048;
                int d0 = 4 * lh;
                vrec[(d0 + 0) * 256 + p] = (unsigned short)f2bf(acc[4 * g + 0]);
                vrec[(d0 + 1) * 256 + p] = (unsigned short)f2bf(acc[4 * g + 1]);
                vrec[(d0 + 2) * 256 + p] = (unsigned short)f2bf(acc[4 * g + 2]);
                vrec[(d0 + 3) * 256 + p] = (unsigned short)f2bf(acc[4 * g + 3]);
            }
        }
    }
}

// ---------------- K4: MFMA dual-stream windowed attention (bf16 out, r5-proven) ------
__global__ __launch_bounds__(256) void k_attn(
    const unsigned short* __restrict__ qk, const unsigned short* __restrict__ vT,
    unsigned short* __restrict__ obx, unsigned short* __restrict__ oby)
{
    int tid = threadIdx.x;
    int wave = tid >> 6, lane = tid & 63;
    int lh = lane >> 5, l31 = lane & 31;
    int bx = blockIdx.x;
    int s = bx >> 10;
    int r = bx & 1023;
    int head = (r >> 6) & 7, wid = r & 63, b = r >> 9;
    const unsigned short* qbase = qk + ((size_t)s * 1024 + r) * 4096;
    const unsigned short* vbase = vT + ((size_t)(s ^ 1) * 1024 + r) * 2048;  // cross v

    short8 qf[2];
    #pragma unroll
    for (int qt = 0; qt < 2; ++qt) {
        uint4 v = {0u, 0u, 0u, 0u};
        if (lh == 0) v = *(const uint4*)(qbase + (size_t)(wave * 64 + qt * 32 + l31) * 16);
        qf[qt] = __builtin_bit_cast(short8, v);
    }
    f32x16 acc[2];
    #pragma unroll
    for (int qt = 0; qt < 2; ++qt) acc[qt] = (f32x16){};
    const unsigned ONES = 0x3F803F80u;

    for (int jt = 0; jt < 8; ++jt) {
        uint4 kv = {0u, 0u, 0u, 0u};
        if (lh == 0) kv = *(const uint4*)(qbase + (size_t)(jt * 32 + l31) * 16 + 8);
        short8 kf = __builtin_bit_cast(short8, kv);
        uint2 a0 = {ONES, ONES}, a1 = {ONES, ONES}, a2 = {ONES, ONES}, a3 = {ONES, ONES};
        if (l31 < 8) {
            const unsigned short* vp = vbase + l31 * 256 + jt * 32 + lh * 4;
            a0 = *(const uint2*)vp;
            a1 = *(const uint2*)(vp + 8);
            a2 = *(const uint2*)(vp + 16);
            a3 = *(const uint2*)(vp + 24);
        }
        uint4 vaw = {a0.x, a0.y, a1.x, a1.y};
        uint4 vbw = {a2.x, a2.y, a3.x, a3.y};
        short8 vf0 = __builtin_bit_cast(short8, vaw);
        short8 vf1 = __builtin_bit_cast(short8, vbw);
        #pragma unroll
        for (int qt = 0; qt < 2; ++qt) {
            f32x16 c = __builtin_amdgcn_mfma_f32_32x32x16_bf16(kf, qf[qt], (f32x16){}, 0, 0, 0);
            float p[16];
            #pragma unroll
            for (int i = 0; i < 16; ++i) p[i] = EXP2(c[i]);
            unsigned pk[8];
            #pragma unroll
            for (int i = 0; i < 8; ++i) pk[i] = cvtpk(p[2 * i], p[2 * i + 1]);
            uint4 bw0 = {pk[0], pk[1], pk[2], pk[3]};
            uint4 bw1 = {pk[4], pk[5], pk[6], pk[7]};
            short8 B0 = __builtin_bit_cast(short8, bw0);
            short8 B1 = __builtin_bit_cast(short8, bw1);
            acc[qt] = __builtin_amdgcn_mfma_f32_32x32x16_bf16(vf0, B0, acc[qt], 0, 0, 0);
            acc[qt] = __builtin_amdgcn_mfma_f32_32x32x16_bf16(vf1, B1, acc[qt], 0, 0, 0);
        }
    }
    unsigned short* dst = s ? oby : obx;
    #pragma unroll
    for (int qt = 0; qt < 2; ++qt) {
        float inv = 1.f / acc[qt][4];
        int p = wave * 64 + qt * 32 + l31;
        int orow = (wid >> 3) * 16 + (p >> 4);
        int ocol = (wid & 7) * 16 + (p & 15);
        size_t t = (size_t)b * 16384 + orow * 128 + ocol;
        uint2 o;
        o.x = cvtpk(acc[qt][0] * inv, acc[qt][1] * inv);
        o.y = cvtpk(acc[qt][2] * inv, acc[qt][3] * inv);
        *(uint2*)&dst[t * 64 + head * 8 + lh * 4] = o;
    }
}

// ---------------- K5: proj + residual + LN + FFN + dec (bf16 o + bf16 residual) ------
__global__ __launch_bounds__(256) void k_fusedec(
    const unsigned short* __restrict__ obx, const unsigned short* __restrict__ oby,
    const unsigned short* __restrict__ wxb, const unsigned short* __restrict__ wyb,
    const unsigned short* __restrict__ projWTn, const float* __restrict__ projb,
    const unsigned short* __restrict__ W1Tn, const float* __restrict__ b1,
    const unsigned short* __restrict__ W2Tn, const float* __restrict__ b2,
    const unsigned short* __restrict__ decTn, const float* __restrict__ decb,
    const float* __restrict__ lng, const float* __restrict__ lnb,
    float* __restrict__ out)
{
    int tid = threadIdx.x;
    int wv = tid >> 6, l31 = tid & 31, lh = (tid >> 5) & 1;
    int t = blockIdx.x * 128 + wv * 32 + l31;
    f32x16 zacc[2];
    zacc[0] = (f32x16){}; zacc[1] = (f32x16){};
    #pragma unroll 1
    for (int s = 0; s < 2; ++s) {
        const unsigned short* osrc = s ? oby : obx;
        const unsigned short* wsrc = s ? wyb : wxb;
        // B for GEMM1: direct bf16 fragments, natural channel order
        short8 bo[4];
        #pragma unroll
        for (int kap = 0; kap < 4; ++kap)
            bo[kap] = *(const short8*)&osrc[(size_t)t * 64 + kap * 16 + lh * 8];
        // GEMM1: xm[m][tok] = projW^T @ o + projb + w
        f32x16 a1[2];
        #pragma unroll
        for (int ta = 0; ta < 2; ++ta) {
            f32x16 acc = {};
            #pragma unroll
            for (int kap = 0; kap < 4; ++kap) {
                short8 af = *(const short8*)&projWTn[(size_t)(ta * 32 + l31) * 64 + kap * 16 + lh * 8];
                acc = __builtin_amdgcn_mfma_f32_32x32x16_bf16(af, bo[kap], acc, 0, 0, 0);
            }
            #pragma unroll
            for (int g = 0; g < 4; ++g) {
                int c0 = ta * 32 + g * 8 + lh * 4;
                float4 pb = *(const float4*)&projb[c0];
                uint2 wr2 = *(const uint2*)&wsrc[(size_t)t * 64 + c0];
                acc[g * 4 + 0] += pb.x + bf2f((unsigned short)(wr2.x & 0xffffu));
                acc[g * 4 + 1] += pb.y + bf2f((unsigned short)(wr2.x >> 16));
                acc[g * 4 + 2] += pb.z + bf2f((unsigned short)(wr2.y & 0xffffu));
                acc[g * 4 + 3] += pb.w + bf2f((unsigned short)(wr2.y >> 16));
            }
            a1[ta] = acc;
        }
        // LN(xm)
        float sm = 0.f, sq = 0.f;
        #pragma unroll
        for (int ta = 0; ta < 2; ++ta)
            #pragma unroll
            for (int r = 0; r < 16; ++r) { float v = a1[ta][r]; sm += v; sq += v * v; }
        sm += __shfl_xor(sm, 32); sq += __shfl_xor(sq, 32);
        float mu = sm * (1.f / 64.f);
        float rs = rsqrtf(fmaxf(sq * (1.f / 64.f) - mu * mu, 0.f) + EPSF);
        unsigned pku[2][8];
        #pragma unroll
        for (int ta = 0; ta < 2; ++ta)
            #pragma unroll
            for (int g = 0; g < 4; ++g) {
                int c0 = ta * 32 + g * 8 + lh * 4;
                float4 gg = *(const float4*)&lng[c0];
                float4 bb = *(const float4*)&lnb[c0];
                float u0 = (a1[ta][g * 4 + 0] - mu) * rs * gg.x + bb.x;
                float u1 = (a1[ta][g * 4 + 1] - mu) * rs * gg.y + bb.y;
                float u2 = (a1[ta][g * 4 + 2] - mu) * rs * gg.z + bb.z;
                float u3 = (a1[ta][g * 4 + 3] - mu) * rs * gg.w + bb.w;
                pku[ta][g * 2]     = cvtpk(u0, u1);
                pku[ta][g * 2 + 1] = cvtpk(u2, u3);
            }
        short8 Bu[4];
        bbuild(pku[0], lh, Bu[0], Bu[1]);
        bbuild(pku[1], lh, Bu[2], Bu[3]);
        // GEMM2: h = relu(W1^T @ u + b1)
        unsigned pkh[2][8];
        #pragma unroll
        for (int th = 0; th < 2; ++th) {
            f32x16 acc = {};
            #pragma unroll
            for (int kap = 0; kap < 4; ++kap) {
                short8 af = *(const short8*)&W1Tn[(size_t)(th * 32 + l31) * 64 + kap * 16 + lh * 8];
                acc = __builtin_amdgcn_mfma_f32_32x32x16_bf16(af, Bu[kap], acc, 0, 0, 0);
            }
            #pragma unroll
            for (int g = 0; g < 4; ++g) {
                int c0 = th * 32 + g * 8 + lh * 4;
                float4 bb = *(const float4*)&b1[c0];
                float h0 = fmaxf(acc[g * 4 + 0] + bb.x, 0.f);
                float h1 = fmaxf(acc[g * 4 + 1] + bb.y, 0.f);
                float h2 = fmaxf(acc[g * 4 + 2] + bb.z, 0.f);
                float h3 = fmaxf(acc[g * 4 + 3] + bb.w, 0.f);
                pkh[th][g * 2]     = cvtpk(h0, h1);
                pkh[th][g * 2 + 1] = cvtpk(h2, h3);
            }
        }
        short8 Bh[4];
        bbuild(pkh[0], lh, Bh[0], Bh[1]);
        bbuild(pkh[1], lh, Bh[2], Bh[3]);
        // GEMM3: xf = xm + b2 + W2^T @ h ; z += xf
        #pragma unroll
        for (int ta = 0; ta < 2; ++ta) {
            f32x16 a3 = a1[ta];
            #pragma unroll
            for (int g = 0; g < 4; ++g) {
                int c0 = ta * 32 + g * 8 + lh * 4;
                float4 bb = *(const float4*)&b2[c0];
                a3[g * 4 + 0] += bb.x; a3[g * 4 + 1] += bb.y;
                a3[g * 4 + 2] += bb.z; a3[g * 4 + 3] += bb.w;
            }
            #pragma unroll
            for (int kap = 0; kap < 4; ++kap) {
                short8 af = *(const short8*)&W2Tn[(size_t)(ta * 32 + l31) * 64 + kap * 16 + lh * 8];
                a3 = __builtin_amdgcn_mfma_f32_32x32x16_bf16(af, Bh[kap], a3, 0, 0, 0);
            }
            zacc[ta] += a3;
        }
    }
    // dec: out[m][tok] = decW^T @ z + 2*decb
    unsigned pkz[2][8];
    #pragma unroll
    for (int ta = 0; ta < 2; ++ta)
        #pragma unroll
        for (int g = 0; g < 4; ++g) {
            pkz[ta][g * 2]     = cvtpk(zacc[ta][g * 4 + 0], zacc[ta][g * 4 + 1]);
            pkz[ta][g * 2 + 1] = cvtpk(zacc[ta][g * 4 + 2], zacc[ta][g * 4 + 3]);
        }
    short8 Bz[4];
    bbuild(pkz[0], lh, Bz[0], Bz[1]);
    bbuild(pkz[1], lh, Bz[2], Bz[3]);
    #pragma unroll
    for (int mu4 = 0; mu4 < 4; ++mu4) {
        f32x16 a4 = {};
        #pragma unroll
        for (int g = 0; g < 4; ++g) {
            int c0 = mu4 * 32 + g * 8 + lh * 4;
            float4 db = *(const float4*)&decb[c0];
            a4[g * 4 + 0] = 2.f * db.x; a4[g * 4 + 1] = 2.f * db.y;
            a4[g * 4 + 2] = 2.f * db.z; a4[g * 4 + 3] = 2.f * db.w;
        }
        #pragma unroll
        for (int kap = 0; kap < 4; ++kap) {
            short8 af = *(const short8*)&decTn[(size_t)(mu4 * 32 + l31) * 64 + kap * 16 + lh * 8];
            a4 = __builtin_amdgcn_mfma_f32_32x32x16_bf16(af, Bz[kap], a4, 0, 0, 0);
        }
        #pragma unroll
        for (int g = 0; g < 4; ++g) {
            int c0 = mu4 * 32 + g * 8 + lh * 4;
            float4 o;
            o.x = a4[g * 4 + 0]; o.y = a4[g * 4 + 1];
            o.z = a4[g * 4 + 2]; o.w = a4[g * 4 + 3];
            *(float4*)&out[(size_t)t * 128 + c0] = o;
        }
    }
}

extern "C" void kernel_launch(void* const* d_in, const int* in_sizes, int n_in,
                              void* d_out, int out_size, void* d_ws, size_t ws_size,
                              hipStream_t stream) {
    const float* x_C   = (const float*)d_in[0];
    const float* x_T   = (const float*)d_in[1];
    const float* dwW   = (const float*)d_in[2];
    const float* dwB   = (const float*)d_in[3];
    const float* pw    = (const float*)d_in[4];
    const float* pwb   = (const float*)d_in[5];
    const float* gam   = (const float*)d_in[6];
    const float* bet   = (const float*)d_in[7];
    const float* mean  = (const float*)d_in[8];
    const float* var   = (const float*)d_in[9];
    const float* encW  = (const float*)d_in[10];
    const float* encb  = (const float*)d_in[11];
    const float* pos   = (const float*)d_in[12];
    const float* lng   = (const float*)d_in[13];
    const float* lnb   = (const float*)d_in[14];
    const float* qkvW  = (const float*)d_in[15];
    const float* projW = (const float*)d_in[16];
    const float* projb = (const float*)d_in[17];
    const float* W1    = (const float*)d_in[18];
    const float* b1    = (const float*)d_in[19];
    const float* W2    = (const float*)d_in[20];
    const float* b2    = (const float*)d_in[21];
    const float* decW  = (const float*)d_in[22];
    const float* decb  = (const float*)d_in[23];
    float* out = (float*)d_out;

    float* ws = (float*)d_ws;
    unsigned short* xdwb = (unsigned short*)ws;                 // 4,194,304 bf16
    unsigned short* x1b  = (unsigned short*)(ws + 2097152);     // 4,194,304 bf16
    unsigned short* qkb  = (unsigned short*)(ws + 4194304);     // 8,388,608 bf16
    unsigned short* vTb  = (unsigned short*)(ws + 8388608);     // 4,194,304 bf16
    unsigned short* wxb  = (unsigned short*)(ws + 10485760);    // 2,097,152 bf16
    unsigned short* wyb  = (unsigned short*)(ws + 11534336);    // 2,097,152 bf16
    unsigned short* obx  = (unsigned short*)(ws + 12582912);    // 2,097,152 bf16
    unsigned short* oby  = (unsigned short*)(ws + 13631488);    // 2,097,152 bf16
    unsigned short* qkvWT   = (unsigned short*)(ws + 16777216); // 12,288 bf16
    unsigned short* weff    = (unsigned short*)(ws + 16783360); // 16,384 bf16
    float*          beff    = ws + 16791552;                    // 128 f
    unsigned short* projWTn = (unsigned short*)(ws + 16791680); // 4,096 bf16
    unsigned short* W1Tn    = (unsigned short*)(ws + 16793728); // 4,096 bf16
    unsigned short* W2Tn    = (unsigned short*)(ws + 16795776); // 4,096 bf16
    unsigned short* decTn   = (unsigned short*)(ws + 16797824); // 8,192 bf16
    unsigned short* encWTn  = (unsigned short*)(ws + 16801920); // 8,192 bf16

    k_dwconv<<<1249, 256, 0, stream>>>(x_C, dwW, dwB, xdwb, qkvW, pw, pwb,
                                       gam, bet, mean, var, projW, W1, W2, decW,
                                       encW, qkvWT, weff, beff, projWTn,
                                       W1Tn, W2Tn, decTn, encWTn);
    k_pw<<<512, 256, 0, stream>>>(xdwb, x_C, weff, beff, x1b);
    k_encqkv<<<dim3(256, 2), 256, 0, stream>>>(x1b, x_T, encWTn, encb, pos,
                                               lng, lnb, qkvWT, wxb, wyb, qkb, vTb);
    k_attn<<<2048, 256, 0, stream>>>(qkb, vTb, obx, oby);
    k_fusedec<<<256, 256, 0, stream>>>(obx, oby, wxb, wyb, projWTn, projb,
                                       W1Tn, b1, W2Tn, b2, decTn, decb,
                                       lng, lnb, out);
}

// Round 11
// 93.398 us; speedup vs baseline: 7.0016x; 1.0243x over previous
//
#include <hip/hip_runtime.h>
#include <hip/hip_bf16.h>
#include <math.h>

#define EPSF 1e-5f
// scale (1/sqrt(8)) * log2(e), folded into k at qkv time
#define KSCL 0.51010090329771713f

#if __has_builtin(__builtin_amdgcn_exp2f)
#define EXP2(x) __builtin_amdgcn_exp2f(x)
#else
#define EXP2(x) exp2f(x)
#endif

typedef __attribute__((ext_vector_type(8))) short short8;   // 8 bf16 = 4 VGPR
typedef __attribute__((ext_vector_type(16))) float f32x16;  // MFMA 32x32 acc

__device__ __forceinline__ float bf2f(unsigned short u) {
    union { unsigned int i; float f; } x; x.i = ((unsigned int)u) << 16; return x.f;
}
__device__ __forceinline__ unsigned int f2bf(float f) {
    union { float f; unsigned int i; } u; u.f = f;
    unsigned int r = u.i + 0x7FFFu + ((u.i >> 16) & 1u);
    return r >> 16;
}
__device__ __forceinline__ unsigned cvtpk(float a, float b) {
    unsigned r;
    asm("v_cvt_pk_bf16_f32 %0, %1, %2" : "=v"(r) : "v"(a), "v"(b));
    return r;
}
// Proven (r2/r8): build natural-k B fragments for a 32-row C block from 8
// pairwise-packed words (pk[i] = rows (2i,2i+1) in C reg order) + partner xchg.
__device__ __forceinline__ void bbuild(const unsigned pk[8], int lh,
                                       short8& B0, short8& B1) {
    unsigned xs[8];
    #pragma unroll
    for (int i = 0; i < 8; ++i) xs[i] = (unsigned)__shfl_xor((int)pk[i], 32);
    uint4 w0, w1;
    w0.x = lh ? xs[2] : pk[0]; w0.y = lh ? xs[3] : pk[1];
    w0.z = lh ? pk[2] : xs[0]; w0.w = lh ? pk[3] : xs[1];
    w1.x = lh ? xs[6] : pk[4]; w1.y = lh ? xs[7] : pk[5];
    w1.z = lh ? pk[6] : xs[4]; w1.w = lh ? pk[7] : xs[5];
    B0 = __builtin_bit_cast(short8, w0);
    B1 = __builtin_bit_cast(short8, w1);
}

// ---------------- K1: fused depthwise 3x3 + pointwise+BN+ReLU+residual -> x1b bf16 ---
// Block = 32 tokens x 128 ch. dwconv in regs -> bf16 LDS tile (XOR swizzled) ->
// MFMA pw (A = tokens from LDS, B = pw*scale built on the fly) -> x1b.
// Extra blocks: weight-prep transposes consumed by LATER launches only.
__global__ __launch_bounds__(256) void k_dwpw(
    const float* __restrict__ xC, const float* __restrict__ dwW,
    const float* __restrict__ dwB, const float* __restrict__ qkvW,
    const float* __restrict__ pw, const float* __restrict__ pwb,
    const float* __restrict__ gam, const float* __restrict__ bet,
    const float* __restrict__ mean, const float* __restrict__ var,
    const float* __restrict__ projW, const float* __restrict__ W1,
    const float* __restrict__ W2, const float* __restrict__ decW,
    const float* __restrict__ encW,
    unsigned short* __restrict__ x1b,
    unsigned short* __restrict__ qkvWT, unsigned short* __restrict__ projWTn,
    unsigned short* __restrict__ W1Tn, unsigned short* __restrict__ W2Tn,
    unsigned short* __restrict__ decTn, unsigned short* __restrict__ encWTn)
{
    int tid = threadIdx.x;
    int bid = blockIdx.x;
    if (bid >= 1024) {                  // -------- weight prep (plain transposes) -----
        int pid = (bid - 1024) * 256 + tid;       // 0..40959
        if (pid < 12288) {              // qkvWT[o*64+c] = qkvW[c*192+o]
            int o = pid >> 6, c = pid & 63;
            qkvWT[pid] = (unsigned short)f2bf(qkvW[c * 192 + o]);
        } else if (pid < 16384) {       // projWTn[m*64+c] = projW[c*64+m]
            int i = pid - 12288, m = i >> 6, c = i & 63;
            projWTn[i] = (unsigned short)f2bf(projW[c * 64 + m]);
        } else if (pid < 20480) {       // W1Tn[m*64+c] = W1[c*64+m]
            int i = pid - 16384, m = i >> 6, c = i & 63;
            W1Tn[i] = (unsigned short)f2bf(W1[c * 64 + m]);
        } else if (pid < 24576) {       // W2Tn[m*64+c] = W2[c*64+m]
            int i = pid - 20480, m = i >> 6, c = i & 63;
            W2Tn[i] = (unsigned short)f2bf(W2[c * 64 + m]);
        } else if (pid < 32768) {       // decTn[m*64+c] = decW[c*128+m], m<128
            int i = pid - 24576, m = i >> 6, c = i & 63;
            decTn[i] = (unsigned short)f2bf(decW[c * 128 + m]);
        } else {                        // encWTn[m*128+c] = encW[c*64+m], m<64
            int i = pid - 32768, m = i >> 7, c = i & 127;
            encWTn[i] = (unsigned short)f2bf(encW[c * 64 + m]);
        }
        return;
    }
    __shared__ float s_w[128 * 9];
    __shared__ float s_bias[128];
    __shared__ unsigned short s_t[32 * 128];      // bf16 dwconv tile, XOR swizzled
    for (int i = tid; i < 128 * 9; i += 256) s_w[i] = dwW[i];
    if (tid < 128) s_bias[tid] = dwB[tid];
    __syncthreads();
    // ---- depthwise conv: thread = 4 ch x 4 px (r10-proven) ----
    int c4 = (tid & 31) * 4;
    int T0 = bid * 32;
    int t0 = T0 + (tid >> 5) * 4;
    int b = t0 >> 14, n = t0 & 16383;
    int row = n >> 7, col0 = n & 127;
    float vb[3][6][4];
    #pragma unroll
    for (int ky = 0; ky < 3; ++ky) {
        int r = row + ky - 1;
        #pragma unroll
        for (int cx = 0; cx < 6; ++cx) {
            int cl = col0 + cx - 1;
            if ((unsigned)r < 128u && (unsigned)cl < 128u) {
                *(float4*)&vb[ky][cx][0] =
                    *(const float4*)&xC[((size_t)(b << 14) + (r << 7) + cl) * 128 + c4];
            } else {
                vb[ky][cx][0] = 0.f; vb[ky][cx][1] = 0.f; vb[ky][cx][2] = 0.f; vb[ky][cx][3] = 0.f;
            }
        }
    }
    float acc[4][4];
    #pragma unroll
    for (int p = 0; p < 4; ++p)
        #pragma unroll
        for (int j = 0; j < 4; ++j) acc[p][j] = s_bias[c4 + j];
    #pragma unroll
    for (int ky = 0; ky < 3; ++ky)
        #pragma unroll
        for (int kx = 0; kx < 3; ++kx)
            #pragma unroll
            for (int j = 0; j < 4; ++j) {
                float w = s_w[(c4 + j) * 9 + ky * 3 + kx];
                #pragma unroll
                for (int p = 0; p < 4; ++p)
                    acc[p][j] = fmaf(w, vb[ky][p + kx][j], acc[p][j]);
            }
    #pragma unroll
    for (int p = 0; p < 4; ++p) {
        int tok = (tid >> 5) * 4 + p;
        uint2 o;
        o.x = f2bf(acc[p][0]) | (f2bf(acc[p][1]) << 16);
        o.y = f2bf(acc[p][2]) | (f2bf(acc[p][3]) << 16);
        unsigned off = (tok << 8) + (c4 << 1);
        off ^= ((tok & 7) << 4);                   // G4 XOR swizzle (8B-aligned safe)
        *(uint2*)((char*)s_t + off) = o;
    }
    __syncthreads();
    // ---- pointwise MFMA: wave wv -> co tile wv*32 + l31, 32 tokens ----
    int wv = tid >> 6, lane = tid & 63, l31 = lane & 31, lh = lane >> 5;
    int co = wv * 32 + l31;
    float sc = gam[co] * rsqrtf(var[co] + EPSF);
    float be = (pwb[co] - mean[co]) * sc + bet[co];
    f32x16 acc2 = {};
    #pragma unroll
    for (int ks = 0; ks < 8; ++ks) {
        // B fragment: pw row co, k = ks*16 + lh*8 .. +7, scaled (== r10 weff)
        const float* pwp = &pw[(size_t)co * 128 + ks * 16 + lh * 8];
        float4 p0 = *(const float4*)pwp;
        float4 p1 = *(const float4*)(pwp + 4);
        uint4 w;
        w.x = cvtpk(p0.x * sc, p0.y * sc); w.y = cvtpk(p0.z * sc, p0.w * sc);
        w.z = cvtpk(p1.x * sc, p1.y * sc); w.w = cvtpk(p1.z * sc, p1.w * sc);
        short8 bfr = __builtin_bit_cast(short8, w);
        // A fragment: token l31 from swizzled LDS tile
        unsigned roff = (l31 << 8) + (ks << 5) + (lh << 4);
        roff ^= ((l31 & 7) << 4);
        short8 afr = *(const short8*)((const char*)s_t + roff);
        acc2 = __builtin_amdgcn_mfma_f32_32x32x16_bf16(afr, bfr, acc2, 0, 0, 0);
    }
    #pragma unroll
    for (int r = 0; r < 16; ++r) {
        int tt = T0 + (r & 3) + 8 * (r >> 2) + 4 * lh;
        float v = fmaxf(acc2[r] + be, 0.f) + xC[(size_t)tt * 128 + co];
        x1b[(size_t)tt * 128 + co] = (unsigned short)f2bf(v);
    }
}

// ---------------- K2: enc + pos + LN + qkv fused (no LDS, r10-proven) ---------------
__global__ __launch_bounds__(256) void k_encqkv(
    const unsigned short* __restrict__ x1b, const float* __restrict__ xT,
    const unsigned short* __restrict__ encWTn, const float* __restrict__ encb,
    const float* __restrict__ pos, const float* __restrict__ lng,
    const float* __restrict__ lnb, const unsigned short* __restrict__ qkvWT,
    unsigned short* __restrict__ wxb, unsigned short* __restrict__ wyb,
    unsigned short* __restrict__ qk, unsigned short* __restrict__ vT)
{
    int tid = threadIdx.x;
    int wv = tid >> 6, l31 = tid & 31, lh = (tid >> 5) & 1;
    int s = blockIdx.y;
    int T0 = blockIdx.x * 128;
    int t = T0 + wv * 32 + l31;
    int n = t & 16383;
    short8 bf[8];
    if (s == 0) {
        #pragma unroll
        for (int ks = 0; ks < 8; ++ks)
            bf[ks] = *(const short8*)&x1b[(size_t)t * 128 + ks * 16 + lh * 8];
    } else {
        #pragma unroll
        for (int ks = 0; ks < 8; ++ks) {
            float4 f0 = *(const float4*)&xT[(size_t)t * 128 + ks * 16 + lh * 8];
            float4 f1 = *(const float4*)&xT[(size_t)t * 128 + ks * 16 + lh * 8 + 4];
            float r0 = f0.x > 0.f ? 2.f * f0.x : f0.x;
            float r1 = f0.y > 0.f ? 2.f * f0.y : f0.y;
            float r2 = f0.z > 0.f ? 2.f * f0.z : f0.z;
            float r3 = f0.w > 0.f ? 2.f * f0.w : f0.w;
            float r4 = f1.x > 0.f ? 2.f * f1.x : f1.x;
            float r5 = f1.y > 0.f ? 2.f * f1.y : f1.y;
            float r6 = f1.z > 0.f ? 2.f * f1.z : f1.z;
            float r7 = f1.w > 0.f ? 2.f * f1.w : f1.w;
            uint4 w;
            w.x = cvtpk(r0, r1); w.y = cvtpk(r2, r3);
            w.z = cvtpk(r4, r5); w.w = cvtpk(r6, r7);
            bf[ks] = __builtin_bit_cast(short8, w);
        }
    }
    f32x16 xm[2];
    #pragma unroll
    for (int ta = 0; ta < 2; ++ta) {
        f32x16 acc = {};
        #pragma unroll
        for (int ks = 0; ks < 8; ++ks) {
            short8 af = *(const short8*)&encWTn[(size_t)(ta * 32 + l31) * 128 + ks * 16 + lh * 8];
            acc = __builtin_amdgcn_mfma_f32_32x32x16_bf16(af, bf[ks], acc, 0, 0, 0);
        }
        #pragma unroll
        for (int g = 0; g < 4; ++g) {
            int c0 = ta * 32 + g * 8 + lh * 4;
            float4 eb = *(const float4*)&encb[c0];
            float4 pv = *(const float4*)&pos[(size_t)n * 64 + c0];
            acc[g * 4 + 0] += eb.x + pv.x;
            acc[g * 4 + 1] += eb.y + pv.y;
            acc[g * 4 + 2] += eb.z + pv.z;
            acc[g * 4 + 3] += eb.w + pv.w;
        }
        xm[ta] = acc;
    }
    float sm = 0.f, sq = 0.f;
    #pragma unroll
    for (int ta = 0; ta < 2; ++ta)
        #pragma unroll
        for (int r = 0; r < 16; ++r) { float v = xm[ta][r]; sm += v; sq += v * v; }
    sm += __shfl_xor(sm, 32); sq += __shfl_xor(sq, 32);
    float mu = sm * (1.f / 64.f);
    float rs = rsqrtf(fmaxf(sq * (1.f / 64.f) - mu * mu, 0.f) + EPSF);
    unsigned short* dstb = s ? wyb : wxb;
    unsigned pku[2][8];
    #pragma unroll
    for (int ta = 0; ta < 2; ++ta)
        #pragma unroll
        for (int g = 0; g < 4; ++g) {
            int c0 = ta * 32 + g * 8 + lh * 4;
            float4 gg = *(const float4*)&lng[c0];
            float4 bb = *(const float4*)&lnb[c0];
            float u0 = (xm[ta][g * 4 + 0] - mu) * rs * gg.x + bb.x;
            float u1 = (xm[ta][g * 4 + 1] - mu) * rs * gg.y + bb.y;
            float u2 = (xm[ta][g * 4 + 2] - mu) * rs * gg.z + bb.z;
            float u3 = (xm[ta][g * 4 + 3] - mu) * rs * gg.w + bb.w;
            pku[ta][g * 2]     = cvtpk(u0, u1);
            pku[ta][g * 2 + 1] = cvtpk(u2, u3);
            uint2 o; o.x = pku[ta][g * 2]; o.y = pku[ta][g * 2 + 1];
            *(uint2*)&dstb[(size_t)t * 64 + c0] = o;
        }
    short8 Bu[4];
    bbuild(pku[0], lh, Bu[0], Bu[1]);
    bbuild(pku[1], lh, Bu[2], Bu[3]);
    // ---- qkv GEMM (A = qkvWT rows, B = Bu) + window-major epilogue ----
    int b = T0 >> 14;
    int row = (T0 & 16383) >> 7;
    int cp = wv * 32 + l31;
    int wid = ((row >> 4) << 3) + (cp >> 4);
    int p = ((row & 15) << 4) + (cp & 15);
    size_t cb = (size_t)(s * 2 + b) * 512 + wid;     // + head*64 = combo
    #pragma unroll
    for (int nt = 0; nt < 6; ++nt) {
        f32x16 acc = {};
        #pragma unroll
        for (int ks = 0; ks < 4; ++ks) {
            short8 afr = *(const short8*)&qkvWT[(size_t)(nt * 32 + l31) * 64 + ks * 16 + lh * 8];
            acc = __builtin_amdgcn_mfma_f32_32x32x16_bf16(afr, Bu[ks], acc, 0, 0, 0);
        }
        if (nt < 4) {
            const float scl = nt < 2 ? 1.f : KSCL;
            const int sec = nt < 2 ? 0 : 1;
            #pragma unroll
            for (int g = 0; g < 4; ++g) {
                int head = (nt & 1) * 4 + g;
                unsigned short* rec = qk + (cb + head * 64) * 4096;
                float f0 = acc[4 * g + 0] * scl, f1 = acc[4 * g + 1] * scl;
                float f2 = acc[4 * g + 2] * scl, f3 = acc[4 * g + 3] * scl;
                unsigned u01 = cvtpk(f0, f1), u23 = cvtpk(f2, f3);
                int off = p * 16 + sec * 8 + 4 * lh;
                *(unsigned*)(rec + off) = u01;
                *(unsigned*)(rec + off + 2) = u23;
            }
        } else {
            #pragma unroll
            for (int g = 0; g < 4; ++g) {
                int head = (nt - 4) * 4 + g;
                unsigned short* vrec = vT + (cb + head * 64) * 2048;
                int d0 = 4 * lh;
                vrec[(d0 + 0) * 256 + p] = (unsigned short)f2bf(acc[4 * g + 0]);
                vrec[(d0 + 1) * 256 + p] = (unsigned short)f2bf(acc[4 * g + 1]);
                vrec[(d0 + 2) * 256 + p] = (unsigned short)f2bf(acc[4 * g + 2]);
                vrec[(d0 + 3) * 256 + p] = (unsigned short)f2bf(acc[4 * g + 3]);
            }
        }
    }
}

// ---------------- K3: MFMA dual-stream windowed attention (bf16 out, proven) ---------
__global__ __launch_bounds__(256) void k_attn(
    const unsigned short* __restrict__ qk, const unsigned short* __restrict__ vT,
    unsigned short* __restrict__ obx, unsigned short* __restrict__ oby)
{
    int tid = threadIdx.x;
    int wave = tid >> 6, lane = tid & 63;
    int lh = lane >> 5, l31 = lane & 31;
    int bx = blockIdx.x;
    int s = bx >> 10;
    int r = bx & 1023;
    int head = (r >> 6) & 7, wid = r & 63, b = r >> 9;
    const unsigned short* qbase = qk + ((size_t)s * 1024 + r) * 4096;
    const unsigned short* vbase = vT + ((size_t)(s ^ 1) * 1024 + r) * 2048;  // cross v

    short8 qf[2];
    #pragma unroll
    for (int qt = 0; qt < 2; ++qt) {
        uint4 v = {0u, 0u, 0u, 0u};
        if (lh == 0) v = *(const uint4*)(qbase + (size_t)(wave * 64 + qt * 32 + l31) * 16);
        qf[qt] = __builtin_bit_cast(short8, v);
    }
    f32x16 acc[2];
    #pragma unroll
    for (int qt = 0; qt < 2; ++qt) acc[qt] = (f32x16){};
    const unsigned ONES = 0x3F803F80u;

    for (int jt = 0; jt < 8; ++jt) {
        uint4 kv = {0u, 0u, 0u, 0u};
        if (lh == 0) kv = *(const uint4*)(qbase + (size_t)(jt * 32 + l31) * 16 + 8);
        short8 kf = __builtin_bit_cast(short8, kv);
        uint2 a0 = {ONES, ONES}, a1 = {ONES, ONES}, a2 = {ONES, ONES}, a3 = {ONES, ONES};
        if (l31 < 8) {
            const unsigned short* vp = vbase + l31 * 256 + jt * 32 + lh * 4;
            a0 = *(const uint2*)vp;
            a1 = *(const uint2*)(vp + 8);
            a2 = *(const uint2*)(vp + 16);
            a3 = *(const uint2*)(vp + 24);
        }
        uint4 vaw = {a0.x, a0.y, a1.x, a1.y};
        uint4 vbw = {a2.x, a2.y, a3.x, a3.y};
        short8 vf0 = __builtin_bit_cast(short8, vaw);
        short8 vf1 = __builtin_bit_cast(short8, vbw);
        #pragma unroll
        for (int qt = 0; qt < 2; ++qt) {
            f32x16 c = __builtin_amdgcn_mfma_f32_32x32x16_bf16(kf, qf[qt], (f32x16){}, 0, 0, 0);
            float p[16];
            #pragma unroll
            for (int i = 0; i < 16; ++i) p[i] = EXP2(c[i]);
            unsigned pk[8];
            #pragma unroll
            for (int i = 0; i < 8; ++i) pk[i] = cvtpk(p[2 * i], p[2 * i + 1]);
            uint4 bw0 = {pk[0], pk[1], pk[2], pk[3]};
            uint4 bw1 = {pk[4], pk[5], pk[6], pk[7]};
            short8 B0 = __builtin_bit_cast(short8, bw0);
            short8 B1 = __builtin_bit_cast(short8, bw1);
            acc[qt] = __builtin_amdgcn_mfma_f32_32x32x16_bf16(vf0, B0, acc[qt], 0, 0, 0);
            acc[qt] = __builtin_amdgcn_mfma_f32_32x32x16_bf16(vf1, B1, acc[qt], 0, 0, 0);
        }
    }
    unsigned short* dst = s ? oby : obx;
    #pragma unroll
    for (int qt = 0; qt < 2; ++qt) {
        float inv = 1.f / acc[qt][4];
        int p = wave * 64 + qt * 32 + l31;
        int orow = (wid >> 3) * 16 + (p >> 4);
        int ocol = (wid & 7) * 16 + (p & 15);
        size_t t = (size_t)b * 16384 + orow * 128 + ocol;
        uint2 o;
        o.x = cvtpk(acc[qt][0] * inv, acc[qt][1] * inv);
        o.y = cvtpk(acc[qt][2] * inv, acc[qt][3] * inv);
        *(uint2*)&dst[t * 64 + head * 8 + lh * 4] = o;
    }
}

// ---------------- K4: proj + residual + LN + FFN + dec (bf16 in, proven) -------------
__global__ __launch_bounds__(256) void k_fusedec(
    const unsigned short* __restrict__ obx, const unsigned short* __restrict__ oby,
    const unsigned short* __restrict__ wxb, const unsigned short* __restrict__ wyb,
    const unsigned short* __restrict__ projWTn, const float* __restrict__ projb,
    const unsigned short* __restrict__ W1Tn, const float* __restrict__ b1,
    const unsigned short* __restrict__ W2Tn, const float* __restrict__ b2,
    const unsigned short* __restrict__ decTn, const float* __restrict__ decb,
    const float* __restrict__ lng, const float* __restrict__ lnb,
    float* __restrict__ out)
{
    int tid = threadIdx.x;
    int wv = tid >> 6, l31 = tid & 31, lh = (tid >> 5) & 1;
    int t = blockIdx.x * 128 + wv * 32 + l31;
    f32x16 zacc[2];
    zacc[0] = (f32x16){}; zacc[1] = (f32x16){};
    #pragma unroll 1
    for (int s = 0; s < 2; ++s) {
        const unsigned short* osrc = s ? oby : obx;
        const unsigned short* wsrc = s ? wyb : wxb;
        short8 bo[4];
        #pragma unroll
        for (int kap = 0; kap < 4; ++kap)
            bo[kap] = *(const short8*)&osrc[(size_t)t * 64 + kap * 16 + lh * 8];
        // GEMM1: xm[m][tok] = projW^T @ o + projb + w
        f32x16 a1[2];
        #pragma unroll
        for (int ta = 0; ta < 2; ++ta) {
            f32x16 acc = {};
            #pragma unroll
            for (int kap = 0; kap < 4; ++kap) {
                short8 af = *(const short8*)&projWTn[(size_t)(ta * 32 + l31) * 64 + kap * 16 + lh * 8];
                acc = __builtin_amdgcn_mfma_f32_32x32x16_bf16(af, bo[kap], acc, 0, 0, 0);
            }
            #pragma unroll
            for (int g = 0; g < 4; ++g) {
                int c0 = ta * 32 + g * 8 + lh * 4;
                float4 pb = *(const float4*)&projb[c0];
                uint2 wr2 = *(const uint2*)&wsrc[(size_t)t * 64 + c0];
                acc[g * 4 + 0] += pb.x + bf2f((unsigned short)(wr2.x & 0xffffu));
                acc[g * 4 + 1] += pb.y + bf2f((unsigned short)(wr2.x >> 16));
                acc[g * 4 + 2] += pb.z + bf2f((unsigned short)(wr2.y & 0xffffu));
                acc[g * 4 + 3] += pb.w + bf2f((unsigned short)(wr2.y >> 16));
            }
            a1[ta] = acc;
        }
        // LN(xm)
        float sm = 0.f, sq = 0.f;
        #pragma unroll
        for (int ta = 0; ta < 2; ++ta)
            #pragma unroll
            for (int r = 0; r < 16; ++r) { float v = a1[ta][r]; sm += v; sq += v * v; }
        sm += __shfl_xor(sm, 32); sq += __shfl_xor(sq, 32);
        float mu = sm * (1.f / 64.f);
        float rs = rsqrtf(fmaxf(sq * (1.f / 64.f) - mu * mu, 0.f) + EPSF);
        unsigned pku[2][8];
        #pragma unroll
        for (int ta = 0; ta < 2; ++ta)
            #pragma unroll
            for (int g = 0; g < 4; ++g) {
                int c0 = ta * 32 + g * 8 + lh * 4;
                float4 gg = *(const float4*)&lng[c0];
                float4 bb = *(const float4*)&lnb[c0];
                float u0 = (a1[ta][g * 4 + 0] - mu) * rs * gg.x + bb.x;
                float u1 = (a1[ta][g * 4 + 1] - mu) * rs * gg.y + bb.y;
                float u2 = (a1[ta][g * 4 + 2] - mu) * rs * gg.z + bb.z;
                float u3 = (a1[ta][g * 4 + 3] - mu) * rs * gg.w + bb.w;
                pku[ta][g * 2]     = cvtpk(u0, u1);
                pku[ta][g * 2 + 1] = cvtpk(u2, u3);
            }
        short8 Bu[4];
        bbuild(pku[0], lh, Bu[0], Bu[1]);
        bbuild(pku[1], lh, Bu[2], Bu[3]);
        // GEMM2: h = relu(W1^T @ u + b1)
        unsigned pkh[2][8];
        #pragma unroll
        for (int th = 0; th < 2; ++th) {
            f32x16 acc = {};
            #pragma unroll
            for (int kap = 0; kap < 4; ++kap) {
                short8 af = *(const short8*)&W1Tn[(size_t)(th * 32 + l31) * 64 + kap * 16 + lh * 8];
                acc = __builtin_amdgcn_mfma_f32_32x32x16_bf16(af, Bu[kap], acc, 0, 0, 0);
            }
            #pragma unroll
            for (int g = 0; g < 4; ++g) {
                int c0 = th * 32 + g * 8 + lh * 4;
                float4 bb = *(const float4*)&b1[c0];
                float h0 = fmaxf(acc[g * 4 + 0] + bb.x, 0.f);
                float h1 = fmaxf(acc[g * 4 + 1] + bb.y, 0.f);
                float h2 = fmaxf(acc[g * 4 + 2] + bb.z, 0.f);
                float h3 = fmaxf(acc[g * 4 + 3] + bb.w, 0.f);
                pkh[th][g * 2]     = cvtpk(h0, h1);
                pkh[th][g * 2 + 1] = cvtpk(h2, h3);
            }
        }
        short8 Bh[4];
        bbuild(pkh[0], lh, Bh[0], Bh[1]);
        bbuild(pkh[1], lh, Bh[2], Bh[3]);
        // GEMM3: xf = xm + b2 + W2^T @ h ; z += xf
        #pragma unroll
        for (int ta = 0; ta < 2; ++ta) {
            f32x16 a3 = a1[ta];
            #pragma unroll
            for (int g = 0; g < 4; ++g) {
                int c0 = ta * 32 + g * 8 + lh * 4;
                float4 bb = *(const float4*)&b2[c0];
                a3[g * 4 + 0] += bb.x; a3[g * 4 + 1] += bb.y;
                a3[g * 4 + 2] += bb.z; a3[g * 4 + 3] += bb.w;
            }
            #pragma unroll
            for (int kap = 0; kap < 4; ++kap) {
                short8 af = *(const short8*)&W2Tn[(size_t)(ta * 32 + l31) * 64 + kap * 16 + lh * 8];
                a3 = __builtin_amdgcn_mfma_f32_32x32x16_bf16(af, Bh[kap], a3, 0, 0, 0);
            }
            zacc[ta] += a3;
        }
    }
    // dec: out[m][tok] = decW^T @ z + 2*decb
    unsigned pkz[2][8];
    #pragma unroll
    for (int ta = 0; ta < 2; ++ta)
        #pragma unroll
        for (int g = 0; g < 4; ++g) {
            pkz[ta][g * 2]     = cvtpk(zacc[ta][g * 4 + 0], zacc[ta][g * 4 + 1]);
            pkz[ta][g * 2 + 1] = cvtpk(zacc[ta][g * 4 + 2], zacc[ta][g * 4 + 3]);
        }
    short8 Bz[4];
    bbuild(pkz[0], lh, Bz[0], Bz[1]);
    bbuild(pkz[1], lh, Bz[2], Bz[3]);
    #pragma unroll
    for (int mu4 = 0; mu4 < 4; ++mu4) {
        f32x16 a4 = {};
        #pragma unroll
        for (int g = 0; g < 4; ++g) {
            int c0 = mu4 * 32 + g * 8 + lh * 4;
            float4 db = *(const float4*)&decb[c0];
            a4[g * 4 + 0] = 2.f * db.x; a4[g * 4 + 1] = 2.f * db.y;
            a4[g * 4 + 2] = 2.f * db.z; a4[g * 4 + 3] = 2.f * db.w;
        }
        #pragma unroll
        for (int kap = 0; kap < 4; ++kap) {
            short8 af = *(const short8*)&decTn[(size_t)(mu4 * 32 + l31) * 64 + kap * 16 + lh * 8];
            a4 = __builtin_amdgcn_mfma_f32_32x32x16_bf16(af, Bz[kap], a4, 0, 0, 0);
        }
        #pragma unroll
        for (int g = 0; g < 4; ++g) {
            int c0 = mu4 * 32 + g * 8 + lh * 4;
            float4 o;
            o.x = a4[g * 4 + 0]; o.y = a4[g * 4 + 1];
            o.z = a4[g * 4 + 2]; o.w = a4[g * 4 + 3];
            *(float4*)&out[(size_t)t * 128 + c0] = o;
        }
    }
}

extern "C" void kernel_launch(void* const* d_in, const int* in_sizes, int n_in,
                              void* d_out, int out_size, void* d_ws, size_t ws_size,
                              hipStream_t stream) {
    const float* x_C   = (const float*)d_in[0];
    const float* x_T   = (const float*)d_in[1];
    const float* dwW   = (const float*)d_in[2];
    const float* dwB   = (const float*)d_in[3];
    const float* pw    = (const float*)d_in[4];
    const float* pwb   = (const float*)d_in[5];
    const float* gam   = (const float*)d_in[6];
    const float* bet   = (const float*)d_in[7];
    const float* mean  = (const float*)d_in[8];
    const float* var   = (const float*)d_in[9];
    const float* encW  = (const float*)d_in[10];
    const float* encb  = (const float*)d_in[11];
    const float* pos   = (const float*)d_in[12];
    const float* lng   = (const float*)d_in[13];
    const float* lnb   = (const float*)d_in[14];
    const float* qkvW  = (const float*)d_in[15];
    const float* projW = (const float*)d_in[16];
    const float* projb = (const float*)d_in[17];
    const float* W1    = (const float*)d_in[18];
    const float* b1    = (const float*)d_in[19];
    const float* W2    = (const float*)d_in[20];
    const float* b2    = (const float*)d_in[21];
    const float* decW  = (const float*)d_in[22];
    const float* decb  = (const float*)d_in[23];
    float* out = (float*)d_out;

    float* ws = (float*)d_ws;
    unsigned short* x1b  = (unsigned short*)(ws + 2097152);     // 4,194,304 bf16
    unsigned short* qkb  = (unsigned short*)(ws + 4194304);     // 8,388,608 bf16
    unsigned short* vTb  = (unsigned short*)(ws + 8388608);     // 4,194,304 bf16
    unsigned short* wxb  = (unsigned short*)(ws + 10485760);    // 2,097,152 bf16
    unsigned short* wyb  = (unsigned short*)(ws + 11534336);    // 2,097,152 bf16
    unsigned short* obx  = (unsigned short*)(ws + 12582912);    // 2,097,152 bf16
    unsigned short* oby  = (unsigned short*)(ws + 13631488);    // 2,097,152 bf16
    unsigned short* qkvWT   = (unsigned short*)(ws + 16777216); // 12,288 bf16
    unsigned short* projWTn = (unsigned short*)(ws + 16791680); // 4,096 bf16
    unsigned short* W1Tn    = (unsigned short*)(ws + 16793728); // 4,096 bf16
    unsigned short* W2Tn    = (unsigned short*)(ws + 16795776); // 4,096 bf16
    unsigned short* decTn   = (unsigned short*)(ws + 16797824); // 8,192 bf16
    unsigned short* encWTn  = (unsigned short*)(ws + 16801920); // 8,192 bf16

    k_dwpw<<<1184, 256, 0, stream>>>(x_C, dwW, dwB, qkvW, pw, pwb,
                                     gam, bet, mean, var, projW, W1, W2, decW,
                                     encW, x1b, qkvWT, projWTn,
                                     W1Tn, W2Tn, decTn, encWTn);
    k_encqkv<<<dim3(256, 2), 256, 0, stream>>>(x1b, x_T, encWTn, encb, pos,
                                               lng, lnb, qkvWT, wxb, wyb, qkb, vTb);
    k_attn<<<2048, 256, 0, stream>>>(qkb, vTb, obx, oby);
    k_fusedec<<<256, 256, 0, stream>>>(obx, oby, wxb, wyb, projWTn, projb,
                                       W1Tn, b1, W2Tn, b2, decTn, decb,
                                       lng, lnb, out);
}

// Round 13
// 93.238 us; speedup vs baseline: 7.0136x; 1.0017x over previous
//
#include <hip/hip_runtime.h>
#include <hip/hip_bf16.h>
#include <math.h>

#define EPSF 1e-5f
// scale (1/sqrt(8)) * log2(e), folded into k at qkv time
#define KSCL 0.51010090329771713f

#if __has_builtin(__builtin_amdgcn_exp2f)
#define EXP2(x) __builtin_amdgcn_exp2f(x)
#else
#define EXP2(x) exp2f(x)
#endif

typedef __attribute__((ext_vector_type(8))) short short8;   // 8 bf16 = 4 VGPR
typedef __attribute__((ext_vector_type(16))) float f32x16;  // MFMA 32x32 acc

__device__ __forceinline__ float bf2f(unsigned short u) {
    union { unsigned int i; float f; } x; x.i = ((unsigned int)u) << 16; return x.f;
}
__device__ __forceinline__ unsigned int f2bf(float f) {
    union { float f; unsigned int i; } u; u.f = f;
    unsigned int r = u.i + 0x7FFFu + ((u.i >> 16) & 1u);
    return r >> 16;
}
__device__ __forceinline__ unsigned cvtpk(float a, float b) {
    unsigned r;
    asm("v_cvt_pk_bf16_f32 %0, %1, %2" : "=v"(r) : "v"(a), "v"(b));
    return r;
}
// Proven (r2/r8): build natural-k B fragments for a 32-row C block from 8
// pairwise-packed words (pk[i] = rows (2i,2i+1) in C reg order) + partner xchg.
__device__ __forceinline__ void bbuild(const unsigned pk[8], int lh,
                                       short8& B0, short8& B1) {
    unsigned xs[8];
    #pragma unroll
    for (int i = 0; i < 8; ++i) xs[i] = (unsigned)__shfl_xor((int)pk[i], 32);
    uint4 w0, w1;
    w0.x = lh ? xs[2] : pk[0]; w0.y = lh ? xs[3] : pk[1];
    w0.z = lh ? pk[2] : xs[0]; w0.w = lh ? pk[3] : xs[1];
    w1.x = lh ? xs[6] : pk[4]; w1.y = lh ? xs[7] : pk[5];
    w1.z = lh ? pk[6] : xs[4]; w1.w = lh ? pk[7] : xs[5];
    B0 = __builtin_bit_cast(short8, w0);
    B1 = __builtin_bit_cast(short8, w1);
}

// ---------------- K1: fused depthwise 3x3 + pointwise+BN+ReLU+residual -> x1b bf16 ---
// Block = 32 tokens x 128 ch. dwconv in regs -> bf16 LDS tile (XOR swizzled) ->
// MFMA pw (A = tokens from LDS, B = pw*scale built on the fly) -> x1b.
// Extra blocks: weight-prep transposes consumed by LATER launches only.
__global__ __launch_bounds__(256) void k_dwpw(
    const float* __restrict__ xC, const float* __restrict__ dwW,
    const float* __restrict__ dwB, const float* __restrict__ qkvW,
    const float* __restrict__ pw, const float* __restrict__ pwb,
    const float* __restrict__ gam, const float* __restrict__ bet,
    const float* __restrict__ mean, const float* __restrict__ var,
    const float* __restrict__ projW, const float* __restrict__ W1,
    const float* __restrict__ W2, const float* __restrict__ decW,
    const float* __restrict__ encW,
    unsigned short* __restrict__ x1b,
    unsigned short* __restrict__ qkvWT, unsigned short* __restrict__ projWTn,
    unsigned short* __restrict__ W1Tn, unsigned short* __restrict__ W2Tn,
    unsigned short* __restrict__ decTn, unsigned short* __restrict__ encWTn)
{
    int tid = threadIdx.x;
    int bid = blockIdx.x;
    if (bid >= 1024) {                  // -------- weight prep (plain transposes) -----
        int pid = (bid - 1024) * 256 + tid;       // 0..40959
        if (pid < 12288) {              // qkvWT[o*64+c] = qkvW[c*192+o]
            int o = pid >> 6, c = pid & 63;
            qkvWT[pid] = (unsigned short)f2bf(qkvW[c * 192 + o]);
        } else if (pid < 16384) {       // projWTn[m*64+c] = projW[c*64+m]
            int i = pid - 12288, m = i >> 6, c = i & 63;
            projWTn[i] = (unsigned short)f2bf(projW[c * 64 + m]);
        } else if (pid < 20480) {       // W1Tn[m*64+c] = W1[c*64+m]
            int i = pid - 16384, m = i >> 6, c = i & 63;
            W1Tn[i] = (unsigned short)f2bf(W1[c * 64 + m]);
        } else if (pid < 24576) {       // W2Tn[m*64+c] = W2[c*64+m]
            int i = pid - 20480, m = i >> 6, c = i & 63;
            W2Tn[i] = (unsigned short)f2bf(W2[c * 64 + m]);
        } else if (pid < 32768) {       // decTn[m*64+c] = decW[c*128+m], m<128
            int i = pid - 24576, m = i >> 6, c = i & 63;
            decTn[i] = (unsigned short)f2bf(decW[c * 128 + m]);
        } else {                        // encWTn[m*128+c] = encW[c*64+m], m<64
            int i = pid - 32768, m = i >> 7, c = i & 127;
            encWTn[i] = (unsigned short)f2bf(encW[c * 64 + m]);
        }
        return;
    }
    __shared__ float s_w[128 * 9];
    __shared__ float s_bias[128];
    __shared__ unsigned short s_t[32 * 128];      // bf16 dwconv tile, XOR swizzled
    for (int i = tid; i < 128 * 9; i += 256) s_w[i] = dwW[i];
    if (tid < 128) s_bias[tid] = dwB[tid];
    __syncthreads();
    // ---- depthwise conv: thread = 4 ch x 4 px (r10-proven) ----
    int c4 = (tid & 31) * 4;
    int T0 = bid * 32;
    int t0 = T0 + (tid >> 5) * 4;
    int b = t0 >> 14, n = t0 & 16383;
    int row = n >> 7, col0 = n & 127;
    float vb[3][6][4];
    #pragma unroll
    for (int ky = 0; ky < 3; ++ky) {
        int r = row + ky - 1;
        #pragma unroll
        for (int cx = 0; cx < 6; ++cx) {
            int cl = col0 + cx - 1;
            if ((unsigned)r < 128u && (unsigned)cl < 128u) {
                *(float4*)&vb[ky][cx][0] =
                    *(const float4*)&xC[((size_t)(b << 14) + (r << 7) + cl) * 128 + c4];
            } else {
                vb[ky][cx][0] = 0.f; vb[ky][cx][1] = 0.f; vb[ky][cx][2] = 0.f; vb[ky][cx][3] = 0.f;
            }
        }
    }
    float acc[4][4];
    #pragma unroll
    for (int p = 0; p < 4; ++p)
        #pragma unroll
        for (int j = 0; j < 4; ++j) acc[p][j] = s_bias[c4 + j];
    #pragma unroll
    for (int ky = 0; ky < 3; ++ky)
        #pragma unroll
        for (int kx = 0; kx < 3; ++kx)
            #pragma unroll
            for (int j = 0; j < 4; ++j) {
                float w = s_w[(c4 + j) * 9 + ky * 3 + kx];
                #pragma unroll
                for (int p = 0; p < 4; ++p)
                    acc[p][j] = fmaf(w, vb[ky][p + kx][j], acc[p][j]);
            }
    #pragma unroll
    for (int p = 0; p < 4; ++p) {
        int tok = (tid >> 5) * 4 + p;
        uint2 o;
        o.x = f2bf(acc[p][0]) | (f2bf(acc[p][1]) << 16);
        o.y = f2bf(acc[p][2]) | (f2bf(acc[p][3]) << 16);
        unsigned off = (tok << 8) + (c4 << 1);
        off ^= ((tok & 7) << 4);                   // G4 XOR swizzle (8B-aligned safe)
        *(uint2*)((char*)s_t + off) = o;
    }
    __syncthreads();
    // ---- pointwise MFMA: wave wv -> co tile wv*32 + l31, 32 tokens ----
    int wv = tid >> 6, lane = tid & 63, l31 = lane & 31, lh = lane >> 5;
    int co = wv * 32 + l31;
    float sc = gam[co] * rsqrtf(var[co] + EPSF);
    float be = (pwb[co] - mean[co]) * sc + bet[co];
    f32x16 acc2 = {};
    #pragma unroll
    for (int ks = 0; ks < 8; ++ks) {
        // B fragment: pw row co, k = ks*16 + lh*8 .. +7, scaled (== r10 weff)
        const float* pwp = &pw[(size_t)co * 128 + ks * 16 + lh * 8];
        float4 p0 = *(const float4*)pwp;
        float4 p1 = *(const float4*)(pwp + 4);
        uint4 w;
        w.x = cvtpk(p0.x * sc, p0.y * sc); w.y = cvtpk(p0.z * sc, p0.w * sc);
        w.z = cvtpk(p1.x * sc, p1.y * sc); w.w = cvtpk(p1.z * sc, p1.w * sc);
        short8 bfr = __builtin_bit_cast(short8, w);
        // A fragment: token l31 from swizzled LDS tile
        unsigned roff = (l31 << 8) + (ks << 5) + (lh << 4);
        roff ^= ((l31 & 7) << 4);
        short8 afr = *(const short8*)((const char*)s_t + roff);
        acc2 = __builtin_amdgcn_mfma_f32_32x32x16_bf16(afr, bfr, acc2, 0, 0, 0);
    }
    #pragma unroll
    for (int r = 0; r < 16; ++r) {
        int tt = T0 + (r & 3) + 8 * (r >> 2) + 4 * lh;
        float v = fmaxf(acc2[r] + be, 0.f) + xC[(size_t)tt * 128 + co];
        x1b[(size_t)tt * 128 + co] = (unsigned short)f2bf(v);
    }
}

// ---------------- K2: enc + pos + LN + qkv fused (no LDS, r10-proven) ---------------
__global__ __launch_bounds__(256) void k_encqkv(
    const unsigned short* __restrict__ x1b, const float* __restrict__ xT,
    const unsigned short* __restrict__ encWTn, const float* __restrict__ encb,
    const float* __restrict__ pos, const float* __restrict__ lng,
    const float* __restrict__ lnb, const unsigned short* __restrict__ qkvWT,
    unsigned short* __restrict__ wxb, unsigned short* __restrict__ wyb,
    unsigned short* __restrict__ qk, unsigned short* __restrict__ vT)
{
    int tid = threadIdx.x;
    int wv = tid >> 6, l31 = tid & 31, lh = (tid >> 5) & 1;
    int s = blockIdx.y;
    int T0 = blockIdx.x * 128;
    int t = T0 + wv * 32 + l31;
    int n = t & 16383;
    short8 bf[8];
    if (s == 0) {
        #pragma unroll
        for (int ks = 0; ks < 8; ++ks)
            bf[ks] = *(const short8*)&x1b[(size_t)t * 128 + ks * 16 + lh * 8];
    } else {
        #pragma unroll
        for (int ks = 0; ks < 8; ++ks) {
            float4 f0 = *(const float4*)&xT[(size_t)t * 128 + ks * 16 + lh * 8];
            float4 f1 = *(const float4*)&xT[(size_t)t * 128 + ks * 16 + lh * 8 + 4];
            float r0 = f0.x > 0.f ? 2.f * f0.x : f0.x;
            float r1 = f0.y > 0.f ? 2.f * f0.y : f0.y;
            float r2 = f0.z > 0.f ? 2.f * f0.z : f0.z;
            float r3 = f0.w > 0.f ? 2.f * f0.w : f0.w;
            float r4 = f1.x > 0.f ? 2.f * f1.x : f1.x;
            float r5 = f1.y > 0.f ? 2.f * f1.y : f1.y;
            float r6 = f1.z > 0.f ? 2.f * f1.z : f1.z;
            float r7 = f1.w > 0.f ? 2.f * f1.w : f1.w;
            uint4 w;
            w.x = cvtpk(r0, r1); w.y = cvtpk(r2, r3);
            w.z = cvtpk(r4, r5); w.w = cvtpk(r6, r7);
            bf[ks] = __builtin_bit_cast(short8, w);
        }
    }
    f32x16 xm[2];
    #pragma unroll
    for (int ta = 0; ta < 2; ++ta) {
        f32x16 acc = {};
        #pragma unroll
        for (int ks = 0; ks < 8; ++ks) {
            short8 af = *(const short8*)&encWTn[(size_t)(ta * 32 + l31) * 128 + ks * 16 + lh * 8];
            acc = __builtin_amdgcn_mfma_f32_32x32x16_bf16(af, bf[ks], acc, 0, 0, 0);
        }
        #pragma unroll
        for (int g = 0; g < 4; ++g) {
            int c0 = ta * 32 + g * 8 + lh * 4;
            float4 eb = *(const float4*)&encb[c0];
            float4 pv = *(const float4*)&pos[(size_t)n * 64 + c0];
            acc[g * 4 + 0] += eb.x + pv.x;
            acc[g * 4 + 1] += eb.y + pv.y;
            acc[g * 4 + 2] += eb.z + pv.z;
            acc[g * 4 + 3] += eb.w + pv.w;
        }
        xm[ta] = acc;
    }
    float sm = 0.f, sq = 0.f;
    #pragma unroll
    for (int ta = 0; ta < 2; ++ta)
        #pragma unroll
        for (int r = 0; r < 16; ++r) { float v = xm[ta][r]; sm += v; sq += v * v; }
    sm += __shfl_xor(sm, 32); sq += __shfl_xor(sq, 32);
    float mu = sm * (1.f / 64.f);
    float rs = rsqrtf(fmaxf(sq * (1.f / 64.f) - mu * mu, 0.f) + EPSF);
    unsigned short* dstb = s ? wyb : wxb;
    unsigned pku[2][8];
    #pragma unroll
    for (int ta = 0; ta < 2; ++ta)
        #pragma unroll
        for (int g = 0; g < 4; ++g) {
            int c0 = ta * 32 + g * 8 + lh * 4;
            float4 gg = *(const float4*)&lng[c0];
            float4 bb = *(const float4*)&lnb[c0];
            float u0 = (xm[ta][g * 4 + 0] - mu) * rs * gg.x + bb.x;
            float u1 = (xm[ta][g * 4 + 1] - mu) * rs * gg.y + bb.y;
            float u2 = (xm[ta][g * 4 + 2] - mu) * rs * gg.z + bb.z;
            float u3 = (xm[ta][g * 4 + 3] - mu) * rs * gg.w + bb.w;
            pku[ta][g * 2]     = cvtpk(u0, u1);
            pku[ta][g * 2 + 1] = cvtpk(u2, u3);
            uint2 o; o.x = pku[ta][g * 2]; o.y = pku[ta][g * 2 + 1];
            *(uint2*)&dstb[(size_t)t * 64 + c0] = o;
        }
    short8 Bu[4];
    bbuild(pku[0], lh, Bu[0], Bu[1]);
    bbuild(pku[1], lh, Bu[2], Bu[3]);
    // ---- qkv GEMM (A = qkvWT rows, B = Bu) + window-major epilogue ----
    int b = T0 >> 14;
    int row = (T0 & 16383) >> 7;
    int cp = wv * 32 + l31;
    int wid = ((row >> 4) << 3) + (cp >> 4);
    int p = ((row & 15) << 4) + (cp & 15);
    size_t cb = (size_t)(s * 2 + b) * 512 + wid;     // + head*64 = combo
    #pragma unroll
    for (int nt = 0; nt < 6; ++nt) {
        f32x16 acc = {};
        #pragma unroll
        for (int ks = 0; ks < 4; ++ks) {
            short8 afr = *(const short8*)&qkvWT[(size_t)(nt * 32 + l31) * 64 + ks * 16 + lh * 8];
            acc = __builtin_amdgcn_mfma_f32_32x32x16_bf16(afr, Bu[ks], acc, 0, 0, 0);
        }
        if (nt < 4) {
            const float scl = nt < 2 ? 1.f : KSCL;
            const int sec = nt < 2 ? 0 : 1;
            #pragma unroll
            for (int g = 0; g < 4; ++g) {
                int head = (nt & 1) * 4 + g;
                unsigned short* rec = qk + (cb + head * 64) * 4096;
                float f0 = acc[4 * g + 0] * scl, f1 = acc[4 * g + 1] * scl;
                float f2 = acc[4 * g + 2] * scl, f3 = acc[4 * g + 3] * scl;
                unsigned u01 = cvtpk(f0, f1), u23 = cvtpk(f2, f3);
                int off = p * 16 + sec * 8 + 4 * lh;
                *(unsigned*)(rec + off) = u01;
                *(unsigned*)(rec + off + 2) = u23;
            }
        } else {
            #pragma unroll
            for (int g = 0; g < 4; ++g) {
                int head = (nt - 4) * 4 + g;
                unsigned short* vrec = vT + (cb + head * 64) * 2048;
                int d0 = 4 * lh;
                vrec[(d0 + 0) * 256 + p] = (unsigned short)f2bf(acc[4 * g + 0]);
                vrec[(d0 + 1) * 256 + p] = (unsigned short)f2bf(acc[4 * g + 1]);
                vrec[(d0 + 2) * 256 + p] = (unsigned short)f2bf(acc[4 * g + 2]);
                vrec[(d0 + 3) * 256 + p] = (unsigned short)f2bf(acc[4 * g + 3]);
            }
        }
    }
}

// ---------------- K3: MFMA dual-stream windowed attention (bf16 out, proven) ---------
__global__ __launch_bounds__(256) void k_attn(
    const unsigned short* __restrict__ qk, const unsigned short* __restrict__ vT,
    unsigned short* __restrict__ obx, unsigned short* __restrict__ oby)
{
    int tid = threadIdx.x;
    int wave = tid >> 6, lane = tid & 63;
    int lh = lane >> 5, l31 = lane & 31;
    int bx = blockIdx.x;
    int s = bx >> 10;
    int r = bx & 1023;
    int head = (r >> 6) & 7, wid = r & 63, b = r >> 9;
    const unsigned short* qbase = qk + ((size_t)s * 1024 + r) * 4096;
    const unsigned short* vbase = vT + ((size_t)(s ^ 1) * 1024 + r) * 2048;  // cross v

    short8 qf[2];
    #pragma unroll
    for (int qt = 0; qt < 2; ++qt) {
        uint4 v = {0u, 0u, 0u, 0u};
        if (lh == 0) v = *(const uint4*)(qbase + (size_t)(wave * 64 + qt * 32 + l31) * 16);
        qf[qt] = __builtin_bit_cast(short8, v);
    }
    f32x16 acc[2];
    #pragma unroll
    for (int qt = 0; qt < 2; ++qt) acc[qt] = (f32x16){};
    const unsigned ONES = 0x3F803F80u;

    for (int jt = 0; jt < 8; ++jt) {
        uint4 kv = {0u, 0u, 0u, 0u};
        if (lh == 0) kv = *(const uint4*)(qbase + (size_t)(jt * 32 + l31) * 16 + 8);
        short8 kf = __builtin_bit_cast(short8, kv);
        uint2 a0 = {ONES, ONES}, a1 = {ONES, ONES}, a2 = {ONES, ONES}, a3 = {ONES, ONES};
        if (l31 < 8) {
            const unsigned short* vp = vbase + l31 * 256 + jt * 32 + lh * 4;
            a0 = *(const uint2*)vp;
            a1 = *(const uint2*)(vp + 8);
            a2 = *(const uint2*)(vp + 16);
            a3 = *(const uint2*)(vp + 24);
        }
        uint4 vaw = {a0.x, a0.y, a1.x, a1.y};
        uint4 vbw = {a2.x, a2.y, a3.x, a3.y};
        short8 vf0 = __builtin_bit_cast(short8, vaw);
        short8 vf1 = __builtin_bit_cast(short8, vbw);
        #pragma unroll
        for (int qt = 0; qt < 2; ++qt) {
            f32x16 c = __builtin_amdgcn_mfma_f32_32x32x16_bf16(kf, qf[qt], (f32x16){}, 0, 0, 0);
            float p[16];
            #pragma unroll
            for (int i = 0; i < 16; ++i) p[i] = EXP2(c[i]);
            unsigned pk[8];
            #pragma unroll
            for (int i = 0; i < 8; ++i) pk[i] = cvtpk(p[2 * i], p[2 * i + 1]);
            uint4 bw0 = {pk[0], pk[1], pk[2], pk[3]};
            uint4 bw1 = {pk[4], pk[5], pk[6], pk[7]};
            short8 B0 = __builtin_bit_cast(short8, bw0);
            short8 B1 = __builtin_bit_cast(short8, bw1);
            acc[qt] = __builtin_amdgcn_mfma_f32_32x32x16_bf16(vf0, B0, acc[qt], 0, 0, 0);
            acc[qt] = __builtin_amdgcn_mfma_f32_32x32x16_bf16(vf1, B1, acc[qt], 0, 0, 0);
        }
    }
    unsigned short* dst = s ? oby : obx;
    #pragma unroll
    for (int qt = 0; qt < 2; ++qt) {
        float inv = 1.f / acc[qt][4];
        int p = wave * 64 + qt * 32 + l31;
        int orow = (wid >> 3) * 16 + (p >> 4);
        int ocol = (wid & 7) * 16 + (p & 15);
        size_t t = (size_t)b * 16384 + orow * 128 + ocol;
        uint2 o;
        o.x = cvtpk(acc[qt][0] * inv, acc[qt][1] * inv);
        o.y = cvtpk(acc[qt][2] * inv, acc[qt][3] * inv);
        *(uint2*)&dst[t * 64 + head * 8 + lh * 4] = o;
    }
}

// ---------------- K4: proj + residual + LN + FFN + dec (bf16 in, proven) -------------
__global__ __launch_bounds__(256) void k_fusedec(
    const unsigned short* __restrict__ obx, const unsigned short* __restrict__ oby,
    const unsigned short* __restrict__ wxb, const unsigned short* __restrict__ wyb,
    const unsigned short* __restrict__ projWTn, const float* __restrict__ projb,
    const unsigned short* __restrict__ W1Tn, const float* __restrict__ b1,
    const unsigned short* __restrict__ W2Tn, const float* __restrict__ b2,
    const unsigned short* __restrict__ decTn, const float* __restrict__ decb,
    const float* __restrict__ lng, const float* __restrict__ lnb,
    float* __restrict__ out)
{
    int tid = threadIdx.x;
    int wv = tid >> 6, l31 = tid & 31, lh = (tid >> 5) & 1;
    int t = blockIdx.x * 128 + wv * 32 + l31;
    f32x16 zacc[2];
    zacc[0] = (f32x16){}; zacc[1] = (f32x16){};
    #pragma unroll 1
    for (int s = 0; s < 2; ++s) {
        const unsigned short* osrc = s ? oby : obx;
        const unsigned short* wsrc = s ? wyb : wxb;
        short8 bo[4];
        #pragma unroll
        for (int kap = 0; kap < 4; ++kap)
            bo[kap] = *(const short8*)&osrc[(size_t)t * 64 + kap * 16 + lh * 8];
        // GEMM1: xm[m][tok] = projW^T @ o + projb + w
        f32x16 a1[2];
        #pragma unroll
        for (int ta = 0; ta < 2; ++ta) {
            f32x16 acc = {};
            #pragma unroll
            for (int kap = 0; kap < 4; ++kap) {
                short8 af = *(const short8*)&projWTn[(size_t)(ta * 32 + l31) * 64 + kap * 16 + lh * 8];
                acc = __builtin_amdgcn_mfma_f32_32x32x16_bf16(af, bo[kap], acc, 0, 0, 0);
            }
            #pragma unroll
            for (int g = 0; g < 4; ++g) {
                int c0 = ta * 32 + g * 8 + lh * 4;
                float4 pb = *(const float4*)&projb[c0];
                uint2 wr2 = *(const uint2*)&wsrc[(size_t)t * 64 + c0];
                acc[g * 4 + 0] += pb.x + bf2f((unsigned short)(wr2.x & 0xffffu));
                acc[g * 4 + 1] += pb.y + bf2f((unsigned short)(wr2.x >> 16));
                acc[g * 4 + 2] += pb.z + bf2f((unsigned short)(wr2.y & 0xffffu));
                acc[g * 4 + 3] += pb.w + bf2f((unsigned short)(wr2.y >> 16));
            }
            a1[ta] = acc;
        }
        // LN(xm)
        float sm = 0.f, sq = 0.f;
        #pragma unroll
        for (int ta = 0; ta < 2; ++ta)
            #pragma unroll
            for (int r = 0; r < 16; ++r) { float v = a1[ta][r]; sm += v; sq += v * v; }
        sm += __shfl_xor(sm, 32); sq += __shfl_xor(sq, 32);
        float mu = sm * (1.f / 64.f);
        float rs = rsqrtf(fmaxf(sq * (1.f / 64.f) - mu * mu, 0.f) + EPSF);
        unsigned pku[2][8];
        #pragma unroll
        for (int ta = 0; ta < 2; ++ta)
            #pragma unroll
            for (int g = 0; g < 4; ++g) {
                int c0 = ta * 32 + g * 8 + lh * 4;
                float4 gg = *(const float4*)&lng[c0];
                float4 bb = *(const float4*)&lnb[c0];
                float u0 = (a1[ta][g * 4 + 0] - mu) * rs * gg.x + bb.x;
                float u1 = (a1[ta][g * 4 + 1] - mu) * rs * gg.y + bb.y;
                float u2 = (a1[ta][g * 4 + 2] - mu) * rs * gg.z + bb.z;
                float u3 = (a1[ta][g * 4 + 3] - mu) * rs * gg.w + bb.w;
                pku[ta][g * 2]     = cvtpk(u0, u1);
                pku[ta][g * 2 + 1] = cvtpk(u2, u3);
            }
        short8 Bu[4];
        bbuild(pku[0], lh, Bu[0], Bu[1]);
        bbuild(pku[1], lh, Bu[2], Bu[3]);
        // GEMM2: h = relu(W1^T @ u + b1)
        unsigned pkh[2][8];
        #pragma unroll
        for (int th = 0; th < 2; ++th) {
            f32x16 acc = {};
            #pragma unroll
            for (int kap = 0; kap < 4; ++kap) {
                short8 af = *(const short8*)&W1Tn[(size_t)(th * 32 + l31) * 64 + kap * 16 + lh * 8];
                acc = __builtin_amdgcn_mfma_f32_32x32x16_bf16(af, Bu[kap], acc, 0, 0, 0);
            }
            #pragma unroll
            for (int g = 0; g < 4; ++g) {
                int c0 = th * 32 + g * 8 + lh * 4;
                float4 bb = *(const float4*)&b1[c0];
                float h0 = fmaxf(acc[g * 4 + 0] + bb.x, 0.f);
                float h1 = fmaxf(acc[g * 4 + 1] + bb.y, 0.f);
                float h2 = fmaxf(acc[g * 4 + 2] + bb.z, 0.f);
                float h3 = fmaxf(acc[g * 4 + 3] + bb.w, 0.f);
                pkh[th][g * 2]     = cvtpk(h0, h1);
                pkh[th][g * 2 + 1] = cvtpk(h2, h3);
            }
        }
        short8 Bh[4];
        bbuild(pkh[0], lh, Bh[0], Bh[1]);
        bbuild(pkh[1], lh, Bh[2], Bh[3]);
        // GEMM3: xf = xm + b2 + W2^T @ h ; z += xf
        #pragma unroll
        for (int ta = 0; ta < 2; ++ta) {
            f32x16 a3 = a1[ta];
            #pragma unroll
            for (int g = 0; g < 4; ++g) {
                int c0 = ta * 32 + g * 8 + lh * 4;
                float4 bb = *(const float4*)&b2[c0];
                a3[g * 4 + 0] += bb.x; a3[g * 4 + 1] += bb.y;
                a3[g * 4 + 2] += bb.z; a3[g * 4 + 3] += bb.w;
            }
            #pragma unroll
            for (int kap = 0; kap < 4; ++kap) {
                short8 af = *(const short8*)&W2Tn[(size_t)(ta * 32 + l31) * 64 + kap * 16 + lh * 8];
                a3 = __builtin_amdgcn_mfma_f32_32x32x16_bf16(af, Bh[kap], a3, 0, 0, 0);
            }
            zacc[ta] += a3;
        }
    }
    // dec: out[m][tok] = decW^T @ z + 2*decb
    unsigned pkz[2][8];
    #pragma unroll
    for (int ta = 0; ta < 2; ++ta)
        #pragma unroll
        for (int g = 0; g < 4; ++g) {
            pkz[ta][g * 2]     = cvtpk(zacc[ta][g * 4 + 0], zacc[ta][g * 4 + 1]);
            pkz[ta][g * 2 + 1] = cvtpk(zacc[ta][g * 4 + 2], zacc[ta][g * 4 + 3]);
        }
    short8 Bz[4];
    bbuild(pkz[0], lh, Bz[0], Bz[1]);
    bbuild(pkz[1], lh, Bz[2], Bz[3]);
    #pragma unroll
    for (int mu4 = 0; mu4 < 4; ++mu4) {
        f32x16 a4 = {};
        #pragma unroll
        for (int g = 0; g < 4; ++g) {
            int c0 = mu4 * 32 + g * 8 + lh * 4;
            float4 db = *(const float4*)&decb[c0];
            a4[g * 4 + 0] = 2.f * db.x; a4[g * 4 + 1] = 2.f * db.y;
            a4[g * 4 + 2] = 2.f * db.z; a4[g * 4 + 3] = 2.f * db.w;
        }
        #pragma unroll
        for (int kap = 0; kap < 4; ++kap) {
            short8 af = *(const short8*)&decTn[(size_t)(mu4 * 32 + l31) * 64 + kap * 16 + lh * 8];
            a4 = __builtin_amdgcn_mfma_f32_32x32x16_bf16(af, Bz[kap], a4, 0, 0, 0);
        }
        #pragma unroll
        for (int g = 0; g < 4; ++g) {
            int c0 = mu4 * 32 + g * 8 + lh * 4;
            float4 o;
            o.x = a4[g * 4 + 0]; o.y = a4[g * 4 + 1];
            o.z = a4[g * 4 + 2]; o.w = a4[g * 4 + 3];
            *(float4*)&out[(size_t)t * 128 + c0] = o;
        }
    }
}

extern "C" void kernel_launch(void* const* d_in, const int* in_sizes, int n_in,
                              void* d_out, int out_size, void* d_ws, size_t ws_size,
                              hipStream_t stream) {
    const float* x_C   = (const float*)d_in[0];
    const float* x_T   = (const float*)d_in[1];
    const float* dwW   = (const float*)d_in[2];
    const float* dwB   = (const float*)d_in[3];
    const float* pw    = (const float*)d_in[4];
    const float* pwb   = (const float*)d_in[5];
    const float* gam   = (const float*)d_in[6];
    const float* bet   = (const float*)d_in[7];
    const float* mean  = (const float*)d_in[8];
    const float* var   = (const float*)d_in[9];
    const float* encW  = (const float*)d_in[10];
    const float* encb  = (const float*)d_in[11];
    const float* pos   = (const float*)d_in[12];
    const float* lng   = (const float*)d_in[13];
    const float* lnb   = (const float*)d_in[14];
    const float* qkvW  = (const float*)d_in[15];
    const float* projW = (const float*)d_in[16];
    const float* projb = (const float*)d_in[17];
    const float* W1    = (const float*)d_in[18];
    const float* b1    = (const float*)d_in[19];
    const float* W2    = (const float*)d_in[20];
    const float* b2    = (const float*)d_in[21];
    const float* decW  = (const float*)d_in[22];
    const float* decb  = (const float*)d_in[23];
    float* out = (float*)d_out;

    float* ws = (float*)d_ws;
    unsigned short* x1b  = (unsigned short*)(ws + 2097152);     // 4,194,304 bf16
    unsigned short* qkb  = (unsigned short*)(ws + 4194304);     // 8,388,608 bf16
    unsigned short* vTb  = (unsigned short*)(ws + 8388608);     // 4,194,304 bf16
    unsigned short* wxb  = (unsigned short*)(ws + 10485760);    // 2,097,152 bf16
    unsigned short* wyb  = (unsigned short*)(ws + 11534336);    // 2,097,152 bf16
    unsigned short* obx  = (unsigned short*)(ws + 12582912);    // 2,097,152 bf16
    unsigned short* oby  = (unsigned short*)(ws + 13631488);    // 2,097,152 bf16
    unsigned short* qkvWT   = (unsigned short*)(ws + 16777216); // 12,288 bf16
    unsigned short* projWTn = (unsigned short*)(ws + 16791680); // 4,096 bf16
    unsigned short* W1Tn    = (unsigned short*)(ws + 16793728); // 4,096 bf16
    unsigned short* W2Tn    = (unsigned short*)(ws + 16795776); // 4,096 bf16
    unsigned short* decTn   = (unsigned short*)(ws + 16797824); // 8,192 bf16
    unsigned short* encWTn  = (unsigned short*)(ws + 16801920); // 8,192 bf16

    k_dwpw<<<1184, 256, 0, stream>>>(x_C, dwW, dwB, qkvW, pw, pwb,
                                     gam, bet, mean, var, projW, W1, W2, decW,
                                     encW, x1b, qkvWT, projWTn,
                                     W1Tn, W2Tn, decTn, encWTn);
    k_encqkv<<<dim3(256, 2), 256, 0, stream>>>(x1b, x_T, encWTn, encb, pos,
                                               lng, lnb, qkvWT, wxb, wyb, qkb, vTb);
    k_attn<<<2048, 256, 0, stream>>>(qkb, vTb, obx, oby);
    k_fusedec<<<256, 256, 0, stream>>>(obx, oby, wxb, wyb, projWTn, projb,
                                       W1Tn, b1, W2Tn, b2, decTn, decb,
                                       lng, lnb, out);
}